// Round 3
// baseline (1014.572 us; speedup 1.0000x reference)
//
#include <hip/hip_runtime.h>
#include <math.h>

#define DM 512
#define NTOK_V 62

typedef _Float16 h16;
typedef __attribute__((ext_vector_type(8))) _Float16 h16x8;
typedef __attribute__((ext_vector_type(4))) float f32x4;

__device__ __forceinline__ void ldsload16(const void* g, void* l) {
    __builtin_amdgcn_global_load_lds(
        (const __attribute__((address_space(1))) unsigned int*)g,
        (__attribute__((address_space(3))) unsigned int*)l, 16, 0, 0);
}

// ---------------------------------------------------------------- fp32 -> fp16 convert
__global__ __launch_bounds__(256) void k_cvt(const float* __restrict__ in,
                                             h16* __restrict__ outp, int n8) {
    int i = blockIdx.x * 256 + threadIdx.x;
    if (i >= n8) return;
    float4 a = ((const float4*)in)[i * 2];
    float4 b = ((const float4*)in)[i * 2 + 1];
    h16x8 h;
    h[0] = (h16)a.x; h[1] = (h16)a.y; h[2] = (h16)a.z; h[3] = (h16)a.w;
    h[4] = (h16)b.x; h[5] = (h16)b.y; h[6] = (h16)b.z; h[7] = (h16)b.w;
    ((h16x8*)outp)[i] = h;
}

// ---------------------------------------------------------------- concat -> fp16 X
__global__ __launch_bounds__(256) void k_concat_h(const float* __restrict__ frames,
                                                  const float* __restrict__ expt,
                                                  h16* __restrict__ X) {
    int row = blockIdx.x;
    int b = row >> 5, s = row & 31;
    int t = threadIdx.x;
    const float* src = (s < 30) ? (frames + ((size_t)(b * 30 + s)) * DM)
                                : (expt + (size_t)(s - 30) * DM);
    X[(size_t)row * DM + t]       = (h16)src[t];
    X[(size_t)row * DM + t + 256] = (h16)src[t + 256];
}

// ---------------------------------------------------------------- 256x256 MFMA GEMM, C = A @ B^T
// A [M,K] h16 (row stride lda), B [N,K] h16 (row stride ldb), C h16 (row stride ldc).
// 512 thr = 8 waves (2M x 4N), wave outputs 128x64. BK=32. A staged via 4-slot LDS ring
// (prefetch distance 3); B fragments loaded straight global->VGPR one step ahead.
// MODE: 0 = +bias, 1 = +bias+relu, 2 = plain, 3 = split-K partial (out += z*M*N)
template<int MODE>
__global__ __launch_bounds__(512, 2) void k_gemm256(
        const h16* __restrict__ A, int lda,
        const h16* __restrict__ B, int ldb,
        const float* __restrict__ bias,
        h16* __restrict__ C, int ldc,
        int M, int N, int Keff) {
    __shared__ h16 lds[32768];                    // 64KB: 4 slots x 16KB (A tiles)
    const int t = threadIdx.x;
    const int w = t >> 6, lane = t & 63;
    const int wr = w >> 2, wc = w & 3;
    const int rr = lane & 15, kq = lane >> 4;     // kq in 0..3
    const size_t row0 = (size_t)blockIdx.y * 256;
    const size_t col0 = (size_t)blockIdx.x * 256;
    const int z = blockIdx.z;

    const h16* Ab = A + (size_t)z * Keff;
    const h16* Bb = B + (size_t)z * Keff;
    // staging: thread stages A rows r = ld*128 + w*16 + rr at k-offset kq*8
    const h16* gA0 = Ab + (row0 + w * 16 + rr) * (size_t)lda + kq * 8;
    const h16* gA1 = gA0 + (size_t)128 * lda;
    // B fragment source: lane holds B[col0 + wc*64 + n*16 + rr][kq*8 .. +7]
    const h16* gB = Bb + (col0 + wc * 64 + rr) * (size_t)ldb + kq * 8;

    h16* Cz = C + (MODE == 3 ? (size_t)z * M * N : (size_t)0);

    f32x4 acc[8][4];
#pragma unroll
    for (int m = 0; m < 8; ++m)
#pragma unroll
        for (int n = 0; n < 4; ++n) acc[m][n] = (f32x4){0.f, 0.f, 0.f, 0.f};

    const int nt = Keff >> 5;                     // #K-steps (even, >= 8)
    h16x8 bA[4], bB[4];

#define LDBX(dst, step) { _Pragma("unroll") for (int n = 0; n < 4; ++n) \
        dst[n] = *(const h16x8*)(gB + (size_t)(n * 16) * ldb + (size_t)(step) * 32); }
#define STGX(step) { char* sA_ = (char*)lds + (((step) & 3) << 14) + (w << 10); \
        ldsload16(gA0 + (size_t)(step) * 32, sA_); \
        ldsload16(gA1 + (size_t)(step) * 32, sA_ + 8192); }
#define SB0 __builtin_amdgcn_sched_barrier(0);
#define CMP(it, bX) { \
        const char* sl_ = (const char*)lds + (((it) & 3) << 14) + ((wr * 8) << 10) + (kq << 8) + (rr << 4); \
        h16x8 a_[8]; \
        _Pragma("unroll") for (int m = 0; m < 8; ++m) a_[m] = *(const h16x8*)(sl_ + (m << 10)); \
        __builtin_amdgcn_s_setprio(1); \
        _Pragma("unroll") for (int m = 0; m < 8; ++m) \
        _Pragma("unroll") for (int n = 0; n < 4; ++n) \
            acc[m][n] = __builtin_amdgcn_mfma_f32_16x16x32_f16(a_[m], bX[n], acc[m][n], 0, 0, 0); \
        __builtin_amdgcn_s_setprio(0); }

    // prologue: issue B(0) then A-stages 0,1,2; retire B0+A0, keep A1,A2 in flight
    LDBX(bA, 0)
    SB0
    STGX(0) STGX(1) STGX(2)
    asm volatile("s_waitcnt vmcnt(2)" ::: "memory");
    __builtin_amdgcn_s_barrier();

    int it = 0;
    for (; it + 4 < nt; it += 2) {                // steady state: no guards -> tight waitcnts
        LDBX(bB, it + 1)
        SB0
        STGX(it + 3)
        CMP(it, bA)
        __builtin_amdgcn_s_barrier();
        LDBX(bA, it + 2)
        SB0
        STGX(it + 4)
        CMP(it + 1, bB)
        __builtin_amdgcn_s_barrier();
    }
    for (; it < nt; it += 2) {                    // tail
        if (it + 1 < nt) LDBX(bB, it + 1)
        SB0
        if (it + 3 < nt) STGX(it + 3)
        CMP(it, bA)
        __builtin_amdgcn_s_barrier();
        if (it + 2 < nt) LDBX(bA, it + 2)
        SB0
        if (it + 4 < nt) STGX(it + 4)
        CMP(it + 1, bB)
        __builtin_amdgcn_s_barrier();
    }
#undef LDBX
#undef STGX
#undef SB0
#undef CMP

    // epilogue: bias preload (4 cols/thread), LDS-staged coalesced store, 2 chunks of 128 rows
    float bv[4] = {0.f, 0.f, 0.f, 0.f};
    if (MODE == 0 || MODE == 1) {
#pragma unroll
        for (int n = 0; n < 4; ++n) bv[n] = bias[col0 + wc * 64 + n * 16 + rr];
    }
    h16* cl = lds;                                 // [128][256] h16 = 64KB
#pragma unroll
    for (int half = 0; half < 2; ++half) {
        if (wr == half) {
#pragma unroll
            for (int m = 0; m < 8; ++m)
#pragma unroll
                for (int n = 0; n < 4; ++n)
#pragma unroll
                    for (int j = 0; j < 4; ++j) {
                        int r = m * 16 + kq * 4 + j;
                        int c = wc * 64 + n * 16 + rr;
                        float v = acc[m][n][j] + bv[n];
                        if (MODE == 1) v = fmaxf(v, 0.f);
                        cl[r * 256 + c] = (h16)v;
                    }
        }
        __builtin_amdgcn_s_barrier();
        {
            int r = t >> 2, seg = t & 3;
            size_t grow = row0 + half * 128 + r;
            h16* gp = Cz + grow * (size_t)ldc + col0 + seg * 64;
            const h16* lp = cl + r * 256 + seg * 64;
#pragma unroll
            for (int i = 0; i < 8; ++i)
                *(h16x8*)(gp + i * 8) = *(const h16x8*)(lp + i * 8);
        }
        __builtin_amdgcn_s_barrier();
    }
}

// ---------------------------------------------------------------- attention, one block per (b,h)
__global__ __launch_bounds__(256) void k_attn_h(const h16* __restrict__ qkv,
                                                h16* __restrict__ att) {
    __shared__ float q[32][65], k[32][65], v[32][65];
    __shared__ float sc[32][33];
    int b = blockIdx.x >> 3, h = blockIdx.x & 7;
    int t = threadIdx.x;
    const h16* base = qkv + (size_t)b * 32 * 1536 + h * 64;
    for (int i = t; i < 2048; i += 256) {
        int s = i >> 6, d = i & 63;
        size_t ro = (size_t)s * 1536 + d;
        q[s][d] = (float)base[ro];
        k[s][d] = (float)base[ro + 512];
        v[s][d] = (float)base[ro + 1024];
    }
    __syncthreads();
    {
        int r = t >> 3, c0 = (t & 7) << 2;
        float s0 = 0.f, s1 = 0.f, s2 = 0.f, s3 = 0.f;
#pragma unroll 8
        for (int d = 0; d < 64; ++d) {
            float qv = q[r][d];
            s0 += qv * k[c0 + 0][d];
            s1 += qv * k[c0 + 1][d];
            s2 += qv * k[c0 + 2][d];
            s3 += qv * k[c0 + 3][d];
        }
        sc[r][c0 + 0] = s0 * 0.125f;
        sc[r][c0 + 1] = s1 * 0.125f;
        sc[r][c0 + 2] = s2 * 0.125f;
        sc[r][c0 + 3] = s3 * 0.125f;
    }
    __syncthreads();
    {   // wave-parallel softmax: 8 lanes per row
        int r = t >> 3, c0 = (t & 7) << 2;
        float a0 = sc[r][c0], a1 = sc[r][c0 + 1], a2 = sc[r][c0 + 2], a3 = sc[r][c0 + 3];
        float mx = fmaxf(fmaxf(a0, a1), fmaxf(a2, a3));
        mx = fmaxf(mx, __shfl_xor(mx, 1));
        mx = fmaxf(mx, __shfl_xor(mx, 2));
        mx = fmaxf(mx, __shfl_xor(mx, 4));
        float e0 = expf(a0 - mx), e1 = expf(a1 - mx), e2 = expf(a2 - mx), e3 = expf(a3 - mx);
        float sm = e0 + e1 + e2 + e3;
        sm += __shfl_xor(sm, 1);
        sm += __shfl_xor(sm, 2);
        sm += __shfl_xor(sm, 4);
        float inv = 1.f / sm;
        sc[r][c0] = e0 * inv; sc[r][c0 + 1] = e1 * inv; sc[r][c0 + 2] = e2 * inv; sc[r][c0 + 3] = e3 * inv;
    }
    __syncthreads();
    for (int i = t; i < 2048; i += 256) {
        int s = i >> 6, d = i & 63;
        float acc = 0.f;
#pragma unroll 8
        for (int c = 0; c < 32; ++c) acc += sc[s][c] * v[c][d];
        att[((size_t)b * 32 + s) * DM + h * 64 + d] = (h16)acc;
    }
}

// ---------------------------------------------------------------- x = LN(x + p0 + p1 + bias)*w + b
__global__ __launch_bounds__(256) void k_addln_red(h16* __restrict__ x,
                                                   const h16* __restrict__ p0,
                                                   const h16* __restrict__ p1,
                                                   const float* __restrict__ bias,
                                                   const float* __restrict__ w,
                                                   const float* __restrict__ b) {
    size_t row = blockIdx.x;
    int t = threadIdx.x;
    size_t o0 = row * DM + t, o1 = o0 + 256;
    float v0 = (float)x[o0] + (float)p0[o0] + (float)p1[o0] + bias[t];
    float v1 = (float)x[o1] + (float)p0[o1] + (float)p1[o1] + bias[t + 256];
    float s = v0 + v1;
#pragma unroll
    for (int o = 32; o; o >>= 1) s += __shfl_xor(s, o);
    __shared__ float ss[4], qs[4];
    if ((t & 63) == 0) ss[t >> 6] = s;
    __syncthreads();
    float mean = (ss[0] + ss[1] + ss[2] + ss[3]) * (1.f / 512.f);
    float d0 = v0 - mean, d1 = v1 - mean;
    float qv = d0 * d0 + d1 * d1;
#pragma unroll
    for (int o = 32; o; o >>= 1) qv += __shfl_xor(qv, o);
    if ((t & 63) == 0) qs[t >> 6] = qv;
    __syncthreads();
    float var = (qs[0] + qs[1] + qs[2] + qs[3]) * (1.f / 512.f);
    float inv = 1.f / sqrtf(var + 1e-5f);
    x[o0] = (h16)(d0 * inv * w[t] + b[t]);
    x[o1] = (h16)(d1 * inv * w[t + 256] + b[t + 256]);
}

// ---------------------------------------------------------------- l2 rows: f32 in -> f16 out
__global__ __launch_bounds__(256) void k_l2rows_h(const float* __restrict__ in,
                                                  h16* __restrict__ outp) {
    size_t row = blockIdx.x;
    int t = threadIdx.x;
    float v0 = in[row * DM + t], v1 = in[row * DM + t + 256];
    float q = v0 * v0 + v1 * v1;
#pragma unroll
    for (int o = 32; o; o >>= 1) q += __shfl_xor(q, o);
    __shared__ float qs[4];
    if ((t & 63) == 0) qs[t >> 6] = q;
    __syncthreads();
    float n = sqrtf(qs[0] + qs[1] + qs[2] + qs[3]);
    float sc = 1.f / fmaxf(n, 1e-12f);
    outp[row * DM + t]       = (h16)(v0 * sc);
    outp[row * DM + t + 256] = (h16)(v1 * sc);
}

// ---------------------------------------------------------------- TOK rows (l2'd frames + video tokens)
__global__ __launch_bounds__(256) void k_build_tok_h(const float* __restrict__ frames,
                                                     const h16* __restrict__ X,
                                                     h16* __restrict__ TOK) {
    int rid = blockIdx.x;
    int j = rid / NTOK_V, tt = rid % NTOK_V;
    int t = threadIdx.x;
    float v0, v1;
    if (tt < 30) {
        const float* src = frames + ((size_t)j * 30 + tt) * DM;
        v0 = src[t]; v1 = src[t + 256];
    } else {
        const h16* src = X + ((size_t)j * 32 + (tt - 30)) * DM;
        v0 = (float)src[t]; v1 = (float)src[t + 256];
    }
    float q = v0 * v0 + v1 * v1;
#pragma unroll
    for (int o = 32; o; o >>= 1) q += __shfl_xor(q, o);
    __shared__ float qs[4];
    if ((t & 63) == 0) qs[t >> 6] = q;
    __syncthreads();
    float n = sqrtf(qs[0] + qs[1] + qs[2] + qs[3]);
    float sc = 1.f / fmaxf(n, 1e-12f);
    TOK[(size_t)rid * DM + t]       = (h16)(v0 * sc);
    TOK[(size_t)rid * DM + t + 256] = (h16)(v1 * sc);
}

// ---------------------------------------------------------------- max-reduce dots -> sims
__global__ __launch_bounds__(256) void k_sim_h(const h16* __restrict__ dots,
                                               float* __restrict__ out) {
    int i = blockIdx.x;
    int j = threadIdx.x;
    const h16* p = dots + (size_t)i * 15872 + (size_t)j * NTOK_V;
    float mf = -1e30f, mv = -1e30f;
#pragma unroll
    for (int tt = 0; tt < 30; ++tt) mf = fmaxf(mf, (float)p[tt]);
#pragma unroll
    for (int tt = 30; tt < 62; ++tt) mv = fmaxf(mv, (float)p[tt]);
    int o = i * 256 + j;
    out[o]          = mf + mv;
    out[65536 + o]  = mf;
    out[131072 + o] = mv;
}

// ---------------------------------------------------------------- launcher
extern "C" void kernel_launch(void* const* d_in, const int* in_sizes, int n_in,
                              void* d_out, int out_size, void* d_ws, size_t ws_size,
                              hipStream_t stream) {
    const float* text   = (const float*)d_in[0];
    const float* frames = (const float*)d_in[1];
    const float* expt   = (const float*)d_in[2];
    const float* Wqkv   = (const float*)d_in[3];
    const float* bqkv   = (const float*)d_in[4];
    const float* Wo     = (const float*)d_in[5];
    const float* bo     = (const float*)d_in[6];
    const float* ln1w   = (const float*)d_in[7];
    const float* ln1b   = (const float*)d_in[8];
    const float* W1     = (const float*)d_in[9];
    const float* b1     = (const float*)d_in[10];
    const float* W2     = (const float*)d_in[11];
    const float* b2     = (const float*)d_in[12];
    const float* ln2w   = (const float*)d_in[13];
    const float* ln2b   = (const float*)d_in[14];
    float* out = (float*)d_out;

    char* wsb = (char*)d_ws;
    const size_t MB = 1024 * 1024;
    h16* Xh    = (h16*)(wsb);              // 8 MB   [8192,512]
    h16* P0    = (h16*)(wsb + 8 * MB);     // 8 MB   split-K partial 0
    h16* P1    = (h16*)(wsb + 16 * MB);    // 8 MB   split-K partial 1 (= P0 + 8192*512)
    h16* ATTh  = (h16*)(wsb + 24 * MB);    // 8 MB   [8192,512]
    h16* FFh   = (h16*)(wsb + 32 * MB);    // 32 MB  [8192,2048] (also QKV [8192,1536])
    h16* TOKh  = (h16*)(wsb + 32 * MB);    // alias FF: 15.5 MB [15872,512] (post-transformer)
    h16* DOTSh = (h16*)(wsb + 48 * MB);    // alias FF tail: 7.75 MB [256,15872]
    h16* Wh    = (h16*)(wsb + 64 * MB);    // 25 MB  all weights fp16
    h16* QHATh = (h16*)(wsb + 90 * MB);    // 0.25 MB [256,512]

    h16* Whqkv = Wh;                       // 4*1536*512
    h16* Who   = Whqkv + 3145728;          // 4*512*512
    h16* Wh1   = Who + 1048576;            // 4*2048*512
    h16* Wh2   = Wh1 + 4194304;            // 4*2048*512

    k_cvt<<<1536, 256, 0, stream>>>(Wqkv, Whqkv, 393216);
    k_cvt<<<512,  256, 0, stream>>>(Wo,   Who,   131072);
    k_cvt<<<2048, 256, 0, stream>>>(W1,   Wh1,   524288);
    k_cvt<<<2048, 256, 0, stream>>>(W2,   Wh2,   524288);
    k_concat_h<<<8192, 256, 0, stream>>>(frames, expt, Xh);

    for (int l = 0; l < 4; ++l) {
        const h16* Wqkv_l = Whqkv + (size_t)l * 786432;
        const h16* Wo_l   = Who   + (size_t)l * 262144;
        const h16* W1_l   = Wh1   + (size_t)l * 1048576;
        const h16* W2_l   = Wh2   + (size_t)l * 1048576;

        k_gemm256<0><<<dim3(6, 32, 1), 512, 0, stream>>>(
            Xh, 512, Wqkv_l, 512, bqkv + (size_t)l * 1536, FFh, 1536, 8192, 1536, 512);
        k_attn_h<<<2048, 256, 0, stream>>>(FFh, ATTh);
        k_gemm256<3><<<dim3(2, 32, 2), 512, 0, stream>>>(
            ATTh, 512, Wo_l, 512, nullptr, P0, 512, 8192, 512, 256);
        k_addln_red<<<8192, 256, 0, stream>>>(Xh, P0, P1, bo + (size_t)l * 512,
                                              ln1w + (size_t)l * 512, ln1b + (size_t)l * 512);
        k_gemm256<1><<<dim3(8, 32, 1), 512, 0, stream>>>(
            Xh, 512, W1_l, 512, b1 + (size_t)l * 2048, FFh, 2048, 8192, 2048, 512);
        k_gemm256<3><<<dim3(2, 32, 2), 512, 0, stream>>>(
            FFh, 2048, W2_l, 2048, nullptr, P0, 512, 8192, 512, 1024);
        k_addln_red<<<8192, 256, 0, stream>>>(Xh, P0, P1, b2 + (size_t)l * 512,
                                              ln2w + (size_t)l * 512, ln2b + (size_t)l * 512);
    }

    k_l2rows_h<<<256, 256, 0, stream>>>(text, QHATh);
    k_build_tok_h<<<256 * NTOK_V, 256, 0, stream>>>(frames, Xh, TOKh);
    k_gemm256<2><<<dim3(62, 1, 1), 512, 0, stream>>>(
        QHATh, 512, TOKh, 512, nullptr, DOTSh, 15872, 256, 15872, 512);
    k_sim_h<<<256, 256, 0, stream>>>(DOTSh, out);
}

// Round 5
// 695.049 us; speedup vs baseline: 1.4597x; 1.4597x over previous
//
#include <hip/hip_runtime.h>
#include <math.h>

#define DM 512
#define NTOK_V 62

typedef _Float16 h16;
typedef __attribute__((ext_vector_type(8))) _Float16 h16x8;
typedef __attribute__((ext_vector_type(4))) float f32x4;

__device__ __forceinline__ void ldsload16(const void* g, void* l) {
    __builtin_amdgcn_global_load_lds(
        (const __attribute__((address_space(1))) unsigned int*)g,
        (__attribute__((address_space(3))) unsigned int*)l, 16, 0, 0);
}

// ---------------------------------------------------------------- fp32 -> fp16 convert
__global__ __launch_bounds__(256) void k_cvt(const float* __restrict__ in,
                                             h16* __restrict__ outp, int n8) {
    int i = blockIdx.x * 256 + threadIdx.x;
    if (i >= n8) return;
    float4 a = ((const float4*)in)[i * 2];
    float4 b = ((const float4*)in)[i * 2 + 1];
    h16x8 h;
    h[0] = (h16)a.x; h[1] = (h16)a.y; h[2] = (h16)a.z; h[3] = (h16)a.w;
    h[4] = (h16)b.x; h[5] = (h16)b.y; h[6] = (h16)b.z; h[7] = (h16)b.w;
    ((h16x8*)outp)[i] = h;
}

// ---------------------------------------------------------------- concat -> fp16 X
__global__ __launch_bounds__(256) void k_concat_h(const float* __restrict__ frames,
                                                  const float* __restrict__ expt,
                                                  h16* __restrict__ X) {
    int row = blockIdx.x;
    int b = row >> 5, s = row & 31;
    int t = threadIdx.x;
    const float* src = (s < 30) ? (frames + ((size_t)(b * 30 + s)) * DM)
                                : (expt + (size_t)(s - 30) * DM);
    X[(size_t)row * DM + t]       = (h16)src[t];
    X[(size_t)row * DM + t + 256] = (h16)src[t + 256];
}

// ---------------------------------------------------------------- MFMA fp16 GEMM  C = A @ B^T
// 128x128 tile, 4 waves 2x2, coalesced global_load_lds staging, 4-slot LDS ring.
// Counted-vmcnt pipeline: steady state vmcnt(8) (2 stages in flight across barriers);
// tail peeled with vmcnt(4)/vmcnt(0) — at iter it the required wait is
// 4*(stages_issued-(it+1)) which collapses to 8,...,8,4,0 (R4's bug: it kept 8).
// MODE: 0 = +bias, 1 = +bias+relu, 2 = plain, 3 = split-K partial (out at z*M*N)
template<int MODE>
__global__ __launch_bounds__(256, 2) void k_hgemm(
        const h16* __restrict__ A, int lda,
        const h16* __restrict__ B, int ldb,
        const float* __restrict__ bias,
        h16* __restrict__ C, int ldc,
        int M, int N, int Keff) {
    __shared__ char smem[65536];               // 4 slots x (A 8KB + B 8KB)
    const int t = threadIdx.x;
    const int w = t >> 6, lane = t & 63;
    const int wr = w >> 1, wc = w & 1;
    const int kc = lane >> 4, rr = lane & 15;
    const size_t row0 = (size_t)blockIdx.y * 128;
    const size_t col0 = (size_t)blockIdx.x * 128;
    const int z = blockIdx.z;

    const h16* gA = A + (size_t)z * Keff + (row0 + (w << 5) + rr) * (size_t)lda + (kc << 3);
    const h16* gB = B + (size_t)z * Keff + (col0 + (w << 5) + rr) * (size_t)ldb + (kc << 3);
    h16* Cz = C + (MODE == 3 ? (size_t)z * (size_t)M * N : (size_t)0);

    f32x4 acc[4][4];
#pragma unroll
    for (int m = 0; m < 4; ++m)
#pragma unroll
        for (int n = 0; n < 4; ++n) acc[m][n] = (f32x4){0.f, 0.f, 0.f, 0.f};

    const int nt = Keff >> 5;                  // K-steps (>= 8 for all call sites)

#define SB0 __builtin_amdgcn_sched_barrier(0);
#define STAGE(step) { char* sA_ = smem + (((step) & 3) << 14) + (w << 11); \
        ldsload16(gA + (size_t)(step) * 32, sA_); \
        ldsload16(gA + (size_t)(step) * 32 + (size_t)16 * lda, sA_ + 1024); \
        ldsload16(gB + (size_t)(step) * 32, sA_ + 8192); \
        ldsload16(gB + (size_t)(step) * 32 + (size_t)16 * ldb, sA_ + 9216); }
#define KSTEP(WAITLIT, it, DOSTAGE) { \
        asm volatile("s_waitcnt vmcnt(" WAITLIT ")" ::: "memory"); \
        SB0 \
        __builtin_amdgcn_s_barrier(); \
        SB0 \
        const char* bA = smem + (((it) & 3) << 14); \
        const char* bB = bA + 8192; \
        h16x8 af[4], bf[4]; \
        _Pragma("unroll") for (int m = 0; m < 4; ++m) \
            af[m] = *(const h16x8*)(bA + (wr * 4 + m) * 1024 + lane * 16); \
        _Pragma("unroll") for (int n = 0; n < 4; ++n) \
            bf[n] = *(const h16x8*)(bB + (wc * 4 + n) * 1024 + lane * 16); \
        asm volatile("s_waitcnt lgkmcnt(0)" ::: "memory"); \
        SB0 \
        __builtin_amdgcn_s_barrier(); \
        SB0 \
        if (DOSTAGE) STAGE((it) + 3) \
        __builtin_amdgcn_s_setprio(1); \
        _Pragma("unroll") for (int m = 0; m < 4; ++m) \
        _Pragma("unroll") for (int n = 0; n < 4; ++n) \
            acc[m][n] = __builtin_amdgcn_mfma_f32_16x16x32_f16(af[m], bf[n], acc[m][n], 0, 0, 0); \
        __builtin_amdgcn_s_setprio(0); \
        SB0 }

    STAGE(0) STAGE(1) STAGE(2)
    int it = 0;
    for (; it < nt - 2; ++it) KSTEP("8", it, (it + 3 < nt))
    KSTEP("4", nt - 2, 0)
    KSTEP("0", nt - 1, 0)
#undef KSTEP
#undef STAGE
#undef SB0

    // epilogue (R2-proven): direct stores, 16-lane groups write 32B segments
#pragma unroll
    for (int n = 0; n < 4; ++n) {
        size_t col = col0 + wc * 64 + n * 16 + rr;
        float bv = (MODE == 0 || MODE == 1) ? bias[col] : 0.f;
#pragma unroll
        for (int m = 0; m < 4; ++m) {
            size_t rbase = row0 + wr * 64 + m * 16 + (kc << 2);
#pragma unroll
            for (int j = 0; j < 4; ++j) {
                float v = acc[m][n][j] + bv;
                if (MODE == 1) v = fmaxf(v, 0.f);
                Cz[(rbase + j) * (size_t)ldc + col] = (h16)v;
            }
        }
    }
}

// ---------------------------------------------------------------- attention, one block per (b,h)
__global__ __launch_bounds__(256) void k_attn_h(const h16* __restrict__ qkv,
                                                h16* __restrict__ att) {
    __shared__ float q[32][65], k[32][65], v[32][65];
    __shared__ float sc[32][33];
    int b = blockIdx.x >> 3, h = blockIdx.x & 7;
    int t = threadIdx.x;
    const h16* base = qkv + (size_t)b * 32 * 1536 + h * 64;
    for (int i = t; i < 2048; i += 256) {
        int s = i >> 6, d = i & 63;
        size_t ro = (size_t)s * 1536 + d;
        q[s][d] = (float)base[ro];
        k[s][d] = (float)base[ro + 512];
        v[s][d] = (float)base[ro + 1024];
    }
    __syncthreads();
    {
        int r = t >> 3, c0 = (t & 7) << 2;
        float s0 = 0.f, s1 = 0.f, s2 = 0.f, s3 = 0.f;
#pragma unroll 8
        for (int d = 0; d < 64; ++d) {
            float qv = q[r][d];
            s0 += qv * k[c0 + 0][d];
            s1 += qv * k[c0 + 1][d];
            s2 += qv * k[c0 + 2][d];
            s3 += qv * k[c0 + 3][d];
        }
        sc[r][c0 + 0] = s0 * 0.125f;
        sc[r][c0 + 1] = s1 * 0.125f;
        sc[r][c0 + 2] = s2 * 0.125f;
        sc[r][c0 + 3] = s3 * 0.125f;
    }
    __syncthreads();
    {   // wave-parallel softmax: 8 lanes per row
        int r = t >> 3, c0 = (t & 7) << 2;
        float a0 = sc[r][c0], a1 = sc[r][c0 + 1], a2 = sc[r][c0 + 2], a3 = sc[r][c0 + 3];
        float mx = fmaxf(fmaxf(a0, a1), fmaxf(a2, a3));
        mx = fmaxf(mx, __shfl_xor(mx, 1));
        mx = fmaxf(mx, __shfl_xor(mx, 2));
        mx = fmaxf(mx, __shfl_xor(mx, 4));
        float e0 = expf(a0 - mx), e1 = expf(a1 - mx), e2 = expf(a2 - mx), e3 = expf(a3 - mx);
        float sm = e0 + e1 + e2 + e3;
        sm += __shfl_xor(sm, 1);
        sm += __shfl_xor(sm, 2);
        sm += __shfl_xor(sm, 4);
        float inv = 1.f / sm;
        sc[r][c0] = e0 * inv; sc[r][c0 + 1] = e1 * inv; sc[r][c0 + 2] = e2 * inv; sc[r][c0 + 3] = e3 * inv;
    }
    __syncthreads();
    for (int i = t; i < 2048; i += 256) {
        int s = i >> 6, d = i & 63;
        float acc = 0.f;
#pragma unroll 8
        for (int c = 0; c < 32; ++c) acc += sc[s][c] * v[c][d];
        att[((size_t)b * 32 + s) * DM + h * 64 + d] = (h16)acc;
    }
}

// ---------------------------------------------------------------- x = LN(x + p0 + p1 + bias)*w + b
__global__ __launch_bounds__(256) void k_addln_red(h16* __restrict__ x,
                                                   const h16* __restrict__ p0,
                                                   const h16* __restrict__ p1,
                                                   const float* __restrict__ bias,
                                                   const float* __restrict__ w,
                                                   const float* __restrict__ b) {
    size_t row = blockIdx.x;
    int t = threadIdx.x;
    size_t o0 = row * DM + t, o1 = o0 + 256;
    float v0 = (float)x[o0] + (float)p0[o0] + (float)p1[o0] + bias[t];
    float v1 = (float)x[o1] + (float)p0[o1] + (float)p1[o1] + bias[t + 256];
    float s = v0 + v1;
#pragma unroll
    for (int o = 32; o; o >>= 1) s += __shfl_xor(s, o);
    __shared__ float ss[4], qs[4];
    if ((t & 63) == 0) ss[t >> 6] = s;
    __syncthreads();
    float mean = (ss[0] + ss[1] + ss[2] + ss[3]) * (1.f / 512.f);
    float d0 = v0 - mean, d1 = v1 - mean;
    float qv = d0 * d0 + d1 * d1;
#pragma unroll
    for (int o = 32; o; o >>= 1) qv += __shfl_xor(qv, o);
    if ((t & 63) == 0) qs[t >> 6] = qv;
    __syncthreads();
    float var = (qs[0] + qs[1] + qs[2] + qs[3]) * (1.f / 512.f);
    float inv = 1.f / sqrtf(var + 1e-5f);
    x[o0] = (h16)(d0 * inv * w[t] + b[t]);
    x[o1] = (h16)(d1 * inv * w[t + 256] + b[t + 256]);
}

// ---------------------------------------------------------------- l2 rows: f32 in -> f16 out
__global__ __launch_bounds__(256) void k_l2rows_h(const float* __restrict__ in,
                                                  h16* __restrict__ outp) {
    size_t row = blockIdx.x;
    int t = threadIdx.x;
    float v0 = in[row * DM + t], v1 = in[row * DM + t + 256];
    float q = v0 * v0 + v1 * v1;
#pragma unroll
    for (int o = 32; o; o >>= 1) q += __shfl_xor(q, o);
    __shared__ float qs[4];
    if ((t & 63) == 0) qs[t >> 6] = q;
    __syncthreads();
    float n = sqrtf(qs[0] + qs[1] + qs[2] + qs[3]);
    float sc = 1.f / fmaxf(n, 1e-12f);
    outp[row * DM + t]       = (h16)(v0 * sc);
    outp[row * DM + t + 256] = (h16)(v1 * sc);
}

// ---------------------------------------------------------------- TOK rows (l2'd frames + video tokens)
__global__ __launch_bounds__(256) void k_build_tok_h(const float* __restrict__ frames,
                                                     const h16* __restrict__ X,
                                                     h16* __restrict__ TOK) {
    int rid = blockIdx.x;
    int j = rid / NTOK_V, tt = rid % NTOK_V;
    int t = threadIdx.x;
    float v0, v1;
    if (tt < 30) {
        const float* src = frames + ((size_t)j * 30 + tt) * DM;
        v0 = src[t]; v1 = src[t + 256];
    } else {
        const h16* src = X + ((size_t)j * 32 + (tt - 30)) * DM;
        v0 = (float)src[t]; v1 = (float)src[t + 256];
    }
    float q = v0 * v0 + v1 * v1;
#pragma unroll
    for (int o = 32; o; o >>= 1) q += __shfl_xor(q, o);
    __shared__ float qs[4];
    if ((t & 63) == 0) qs[t >> 6] = q;
    __syncthreads();
    float n = sqrtf(qs[0] + qs[1] + qs[2] + qs[3]);
    float sc = 1.f / fmaxf(n, 1e-12f);
    TOK[(size_t)rid * DM + t]       = (h16)(v0 * sc);
    TOK[(size_t)rid * DM + t + 256] = (h16)(v1 * sc);
}

// ---------------------------------------------------------------- max-reduce dots -> sims
__global__ __launch_bounds__(256) void k_sim_h(const h16* __restrict__ dots,
                                               float* __restrict__ out) {
    int i = blockIdx.x;
    int j = threadIdx.x;
    const h16* p = dots + (size_t)i * 15872 + (size_t)j * NTOK_V;
    float mf = -1e30f, mv = -1e30f;
#pragma unroll
    for (int tt = 0; tt < 30; ++tt) mf = fmaxf(mf, (float)p[tt]);
#pragma unroll
    for (int tt = 30; tt < 62; ++tt) mv = fmaxf(mv, (float)p[tt]);
    int o = i * 256 + j;
    out[o]          = mf + mv;
    out[65536 + o]  = mf;
    out[131072 + o] = mv;
}

// ---------------------------------------------------------------- launcher
extern "C" void kernel_launch(void* const* d_in, const int* in_sizes, int n_in,
                              void* d_out, int out_size, void* d_ws, size_t ws_size,
                              hipStream_t stream) {
    const float* text   = (const float*)d_in[0];
    const float* frames = (const float*)d_in[1];
    const float* expt   = (const float*)d_in[2];
    const float* Wqkv   = (const float*)d_in[3];
    const float* bqkv   = (const float*)d_in[4];
    const float* Wo     = (const float*)d_in[5];
    const float* bo     = (const float*)d_in[6];
    const float* ln1w   = (const float*)d_in[7];
    const float* ln1b   = (const float*)d_in[8];
    const float* W1     = (const float*)d_in[9];
    const float* b1     = (const float*)d_in[10];
    const float* W2     = (const float*)d_in[11];
    const float* b2     = (const float*)d_in[12];
    const float* ln2w   = (const float*)d_in[13];
    const float* ln2b   = (const float*)d_in[14];
    float* out = (float*)d_out;

    char* wsb = (char*)d_ws;
    const size_t MB = 1024 * 1024;
    h16* Xh    = (h16*)(wsb);              // 8 MB   [8192,512]
    h16* P0    = (h16*)(wsb + 8 * MB);     // 8 MB   split-K partial 0
    h16* P1    = (h16*)(wsb + 16 * MB);    // 8 MB   split-K partial 1 (= P0 + 8192*512)
    h16* ATTh  = (h16*)(wsb + 24 * MB);    // 8 MB   [8192,512]
    h16* FFh   = (h16*)(wsb + 32 * MB);    // 32 MB  [8192,2048] (also QKV [8192,1536])
    h16* TOKh  = (h16*)(wsb + 32 * MB);    // alias FF: 15.5 MB [15872,512] (post-transformer)
    h16* DOTSh = (h16*)(wsb + 48 * MB);    // alias FF tail: 7.75 MB [256,15872]
    h16* Wh    = (h16*)(wsb + 64 * MB);    // 25 MB  all weights fp16
    h16* QHATh = (h16*)(wsb + 90 * MB);    // 0.25 MB [256,512]

    h16* Whqkv = Wh;                       // 4*1536*512
    h16* Who   = Whqkv + 3145728;          // 4*512*512
    h16* Wh1   = Who + 1048576;            // 4*2048*512
    h16* Wh2   = Wh1 + 4194304;            // 4*2048*512

    k_cvt<<<1536, 256, 0, stream>>>(Wqkv, Whqkv, 393216);
    k_cvt<<<512,  256, 0, stream>>>(Wo,   Who,   131072);
    k_cvt<<<2048, 256, 0, stream>>>(W1,   Wh1,   524288);
    k_cvt<<<2048, 256, 0, stream>>>(W2,   Wh2,   524288);
    k_concat_h<<<8192, 256, 0, stream>>>(frames, expt, Xh);

    for (int l = 0; l < 4; ++l) {
        const h16* Wqkv_l = Whqkv + (size_t)l * 786432;
        const h16* Wo_l   = Who   + (size_t)l * 262144;
        const h16* W1_l   = Wh1   + (size_t)l * 1048576;
        const h16* W2_l   = Wh2   + (size_t)l * 1048576;

        k_hgemm<0><<<dim3(12, 64, 1), 256, 0, stream>>>(
            Xh, 512, Wqkv_l, 512, bqkv + (size_t)l * 1536, FFh, 1536, 8192, 1536, 512);
        k_attn_h<<<2048, 256, 0, stream>>>(FFh, ATTh);
        k_hgemm<3><<<dim3(4, 64, 2), 256, 0, stream>>>(
            ATTh, 512, Wo_l, 512, nullptr, P0, 512, 8192, 512, 256);
        k_addln_red<<<8192, 256, 0, stream>>>(Xh, P0, P1, bo + (size_t)l * 512,
                                              ln1w + (size_t)l * 512, ln1b + (size_t)l * 512);
        k_hgemm<1><<<dim3(16, 64, 1), 256, 0, stream>>>(
            Xh, 512, W1_l, 512, b1 + (size_t)l * 2048, FFh, 2048, 8192, 2048, 512);
        k_hgemm<3><<<dim3(4, 64, 2), 256, 0, stream>>>(
            FFh, 2048, W2_l, 2048, nullptr, P0, 512, 8192, 512, 1024);
        k_addln_red<<<8192, 256, 0, stream>>>(Xh, P0, P1, b2 + (size_t)l * 512,
                                              ln2w + (size_t)l * 512, ln2b + (size_t)l * 512);
    }

    k_l2rows_h<<<256, 256, 0, stream>>>(text, QHATh);
    k_build_tok_h<<<256 * NTOK_V, 256, 0, stream>>>(frames, Xh, TOKh);
    k_hgemm<2><<<dim3(124, 2, 1), 256, 0, stream>>>(
        QHATh, 512, TOKh, 512, nullptr, DOTSh, 15872, 256, 15872, 512);
    k_sim_h<<<256, 256, 0, stream>>>(DOTSh, out);
}

// Round 6
// 695.036 us; speedup vs baseline: 1.4597x; 1.0000x over previous
//
#include <hip/hip_runtime.h>
#include <math.h>

#define DM 512
#define NTOK_V 62

typedef _Float16 h16;
typedef __attribute__((ext_vector_type(8))) _Float16 h16x8;
typedef __attribute__((ext_vector_type(4))) float f32x4;

__device__ __forceinline__ void ldsload16(const void* g, void* l) {
    __builtin_amdgcn_global_load_lds(
        (const __attribute__((address_space(1))) unsigned int*)g,
        (__attribute__((address_space(3))) unsigned int*)l, 16, 0, 0);
}

// ---------------------------------------------------------------- fp32 -> fp16 convert
__global__ __launch_bounds__(256) void k_cvt(const float* __restrict__ in,
                                             h16* __restrict__ outp, int n8) {
    int i = blockIdx.x * 256 + threadIdx.x;
    if (i >= n8) return;
    float4 a = ((const float4*)in)[i * 2];
    float4 b = ((const float4*)in)[i * 2 + 1];
    h16x8 h;
    h[0] = (h16)a.x; h[1] = (h16)a.y; h[2] = (h16)a.z; h[3] = (h16)a.w;
    h[4] = (h16)b.x; h[5] = (h16)b.y; h[6] = (h16)b.z; h[7] = (h16)b.w;
    ((h16x8*)outp)[i] = h;
}

// ---------------------------------------------------------------- concat -> fp16 X
__global__ __launch_bounds__(256) void k_concat_h(const float* __restrict__ frames,
                                                  const float* __restrict__ expt,
                                                  h16* __restrict__ X) {
    int row = blockIdx.x;
    int b = row >> 5, s = row & 31;
    int t = threadIdx.x;
    const float* src = (s < 30) ? (frames + ((size_t)(b * 30 + s)) * DM)
                                : (expt + (size_t)(s - 30) * DM);
    X[(size_t)row * DM + t]       = (h16)src[t];
    X[(size_t)row * DM + t + 256] = (h16)src[t + 256];
}

// ---------------------------------------------------------------- MFMA fp16 GEMM  C = A @ B^T
// 128x128 tile, 4 waves 2x2, coalesced global_load_lds staging, 4-slot LDS ring,
// distance-3 prefetch, counted vmcnt (8,...,8,8,4,0) and ONE barrier per K-step:
// STAGE(it+3) overwrites slot (it-1)&3, whose reads every wave drained (lgkmcnt(0))
// before reaching barrier(it) -> WAR-safe without the second barrier.
// MODE: 0 = +bias, 1 = +bias+relu, 2 = plain, 3 = split-K partial (out at z*M*N)
template<int MODE>
__global__ __launch_bounds__(256, 2) void k_hgemm(
        const h16* __restrict__ A, int lda,
        const h16* __restrict__ B, int ldb,
        const float* __restrict__ bias,
        h16* __restrict__ C, int ldc,
        int M, int N, int Keff) {
    __shared__ char smem[65536];               // 4 slots x (A 8KB + B 8KB)
    const int t = threadIdx.x;
    const int w = t >> 6, lane = t & 63;
    const int wr = w >> 1, wc = w & 1;
    const int kc = lane >> 4, rr = lane & 15;
    const size_t row0 = (size_t)blockIdx.y * 128;
    const size_t col0 = (size_t)blockIdx.x * 128;
    const int z = blockIdx.z;

    const h16* gA = A + (size_t)z * Keff + (row0 + (w << 5) + rr) * (size_t)lda + (kc << 3);
    const h16* gB = B + (size_t)z * Keff + (col0 + (w << 5) + rr) * (size_t)ldb + (kc << 3);
    h16* Cz = C + (MODE == 3 ? (size_t)z * (size_t)M * N : (size_t)0);

    f32x4 acc[4][4];
#pragma unroll
    for (int m = 0; m < 4; ++m)
#pragma unroll
        for (int n = 0; n < 4; ++n) acc[m][n] = (f32x4){0.f, 0.f, 0.f, 0.f};

    const int nt = Keff >> 5;                  // K-steps (>= 8 for all call sites)

#define SB0 __builtin_amdgcn_sched_barrier(0);
#define STAGE(step) { char* sA_ = smem + (((step) & 3) << 14) + (w << 11); \
        ldsload16(gA + (size_t)(step) * 32, sA_); \
        ldsload16(gA + (size_t)(step) * 32 + (size_t)16 * lda, sA_ + 1024); \
        ldsload16(gB + (size_t)(step) * 32, sA_ + 8192); \
        ldsload16(gB + (size_t)(step) * 32 + (size_t)16 * ldb, sA_ + 9216); }
#define KSTEP(WAITLIT, it, DOSTAGE) { \
        asm volatile("s_waitcnt vmcnt(" WAITLIT ")" ::: "memory"); \
        SB0 \
        __builtin_amdgcn_s_barrier(); \
        SB0 \
        const char* bA = smem + (((it) & 3) << 14); \
        const char* bB = bA + 8192; \
        h16x8 af[4], bf[4]; \
        _Pragma("unroll") for (int m = 0; m < 4; ++m) \
            af[m] = *(const h16x8*)(bA + (wr * 4 + m) * 1024 + lane * 16); \
        _Pragma("unroll") for (int n = 0; n < 4; ++n) \
            bf[n] = *(const h16x8*)(bB + (wc * 4 + n) * 1024 + lane * 16); \
        asm volatile("s_waitcnt lgkmcnt(0)" ::: "memory"); \
        SB0 \
        if (DOSTAGE) STAGE((it) + 3) \
        __builtin_amdgcn_s_setprio(1); \
        _Pragma("unroll") for (int m = 0; m < 4; ++m) \
        _Pragma("unroll") for (int n = 0; n < 4; ++n) \
            acc[m][n] = __builtin_amdgcn_mfma_f32_16x16x32_f16(af[m], bf[n], acc[m][n], 0, 0, 0); \
        __builtin_amdgcn_s_setprio(0); \
        SB0 }

    STAGE(0) STAGE(1) STAGE(2)
    int it = 0;
    for (; it < nt - 3; ++it) KSTEP("8", it, 1)
    KSTEP("8", it, 0) ++it;                    // it = nt-3: all stages issued, 2 in flight
    KSTEP("4", it, 0) ++it;                    // it = nt-2: 1 in flight
    KSTEP("0", it, 0)                          // it = nt-1: drain
#undef KSTEP
#undef STAGE
#undef SB0

    // epilogue: direct stores, 16-lane groups write 32B segments
#pragma unroll
    for (int n = 0; n < 4; ++n) {
        size_t col = col0 + wc * 64 + n * 16 + rr;
        float bv = (MODE == 0 || MODE == 1) ? bias[col] : 0.f;
#pragma unroll
        for (int m = 0; m < 4; ++m) {
            size_t rbase = row0 + wr * 64 + m * 16 + (kc << 2);
#pragma unroll
            for (int j = 0; j < 4; ++j) {
                float v = acc[m][n][j] + bv;
                if (MODE == 1) v = fmaxf(v, 0.f);
                Cz[(rbase + j) * (size_t)ldc + col] = (h16)v;
            }
        }
    }
}

// ---------------------------------------------------------------- attention, one block per (b,h)
__global__ __launch_bounds__(256) void k_attn_h(const h16* __restrict__ qkv,
                                                h16* __restrict__ att) {
    __shared__ float q[32][65], k[32][65], v[32][65];
    __shared__ float sc[32][33];
    int b = blockIdx.x >> 3, h = blockIdx.x & 7;
    int t = threadIdx.x;
    const h16* base = qkv + (size_t)b * 32 * 1536 + h * 64;
    for (int i = t; i < 2048; i += 256) {
        int s = i >> 6, d = i & 63;
        size_t ro = (size_t)s * 1536 + d;
        q[s][d] = (float)base[ro];
        k[s][d] = (float)base[ro + 512];
        v[s][d] = (float)base[ro + 1024];
    }
    __syncthreads();
    {
        int r = t >> 3, c0 = (t & 7) << 2;
        float s0 = 0.f, s1 = 0.f, s2 = 0.f, s3 = 0.f;
#pragma unroll 8
        for (int d = 0; d < 64; ++d) {
            float qv = q[r][d];
            s0 += qv * k[c0 + 0][d];
            s1 += qv * k[c0 + 1][d];
            s2 += qv * k[c0 + 2][d];
            s3 += qv * k[c0 + 3][d];
        }
        sc[r][c0 + 0] = s0 * 0.125f;
        sc[r][c0 + 1] = s1 * 0.125f;
        sc[r][c0 + 2] = s2 * 0.125f;
        sc[r][c0 + 3] = s3 * 0.125f;
    }
    __syncthreads();
    {   // wave-parallel softmax: 8 lanes per row
        int r = t >> 3, c0 = (t & 7) << 2;
        float a0 = sc[r][c0], a1 = sc[r][c0 + 1], a2 = sc[r][c0 + 2], a3 = sc[r][c0 + 3];
        float mx = fmaxf(fmaxf(a0, a1), fmaxf(a2, a3));
        mx = fmaxf(mx, __shfl_xor(mx, 1));
        mx = fmaxf(mx, __shfl_xor(mx, 2));
        mx = fmaxf(mx, __shfl_xor(mx, 4));
        float e0 = expf(a0 - mx), e1 = expf(a1 - mx), e2 = expf(a2 - mx), e3 = expf(a3 - mx);
        float sm = e0 + e1 + e2 + e3;
        sm += __shfl_xor(sm, 1);
        sm += __shfl_xor(sm, 2);
        sm += __shfl_xor(sm, 4);
        float inv = 1.f / sm;
        sc[r][c0] = e0 * inv; sc[r][c0 + 1] = e1 * inv; sc[r][c0 + 2] = e2 * inv; sc[r][c0 + 3] = e3 * inv;
    }
    __syncthreads();
    for (int i = t; i < 2048; i += 256) {
        int s = i >> 6, d = i & 63;
        float acc = 0.f;
#pragma unroll 8
        for (int c = 0; c < 32; ++c) acc += sc[s][c] * v[c][d];
        att[((size_t)b * 32 + s) * DM + h * 64 + d] = (h16)acc;
    }
}

// ---------------------------------------------------------------- x = LN(x + p0 + p1 + bias)*w + b
__global__ __launch_bounds__(256) void k_addln_red(h16* __restrict__ x,
                                                   const h16* __restrict__ p0,
                                                   const h16* __restrict__ p1,
                                                   const float* __restrict__ bias,
                                                   const float* __restrict__ w,
                                                   const float* __restrict__ b) {
    size_t row = blockIdx.x;
    int t = threadIdx.x;
    size_t o0 = row * DM + t, o1 = o0 + 256;
    float v0 = (float)x[o0] + (float)p0[o0] + (float)p1[o0] + bias[t];
    float v1 = (float)x[o1] + (float)p0[o1] + (float)p1[o1] + bias[t + 256];
    float s = v0 + v1;
#pragma unroll
    for (int o = 32; o; o >>= 1) s += __shfl_xor(s, o);
    __shared__ float ss[4], qs[4];
    if ((t & 63) == 0) ss[t >> 6] = s;
    __syncthreads();
    float mean = (ss[0] + ss[1] + ss[2] + ss[3]) * (1.f / 512.f);
    float d0 = v0 - mean, d1 = v1 - mean;
    float qv = d0 * d0 + d1 * d1;
#pragma unroll
    for (int o = 32; o; o >>= 1) qv += __shfl_xor(qv, o);
    if ((t & 63) == 0) qs[t >> 6] = qv;
    __syncthreads();
    float var = (qs[0] + qs[1] + qs[2] + qs[3]) * (1.f / 512.f);
    float inv = 1.f / sqrtf(var + 1e-5f);
    x[o0] = (h16)(d0 * inv * w[t] + b[t]);
    x[o1] = (h16)(d1 * inv * w[t + 256] + b[t + 256]);
}

// ---------------------------------------------------------------- l2 rows: f32 in -> f16 out
__global__ __launch_bounds__(256) void k_l2rows_h(const float* __restrict__ in,
                                                  h16* __restrict__ outp) {
    size_t row = blockIdx.x;
    int t = threadIdx.x;
    float v0 = in[row * DM + t], v1 = in[row * DM + t + 256];
    float q = v0 * v0 + v1 * v1;
#pragma unroll
    for (int o = 32; o; o >>= 1) q += __shfl_xor(q, o);
    __shared__ float qs[4];
    if ((t & 63) == 0) qs[t >> 6] = q;
    __syncthreads();
    float n = sqrtf(qs[0] + qs[1] + qs[2] + qs[3]);
    float sc = 1.f / fmaxf(n, 1e-12f);
    outp[row * DM + t]       = (h16)(v0 * sc);
    outp[row * DM + t + 256] = (h16)(v1 * sc);
}

// ---------------------------------------------------------------- TOK rows (l2'd frames + video tokens)
__global__ __launch_bounds__(256) void k_build_tok_h(const float* __restrict__ frames,
                                                     const h16* __restrict__ X,
                                                     h16* __restrict__ TOK) {
    int rid = blockIdx.x;
    int j = rid / NTOK_V, tt = rid % NTOK_V;
    int t = threadIdx.x;
    float v0, v1;
    if (tt < 30) {
        const float* src = frames + ((size_t)j * 30 + tt) * DM;
        v0 = src[t]; v1 = src[t + 256];
    } else {
        const h16* src = X + ((size_t)j * 32 + (tt - 30)) * DM;
        v0 = (float)src[t]; v1 = (float)src[t + 256];
    }
    float q = v0 * v0 + v1 * v1;
#pragma unroll
    for (int o = 32; o; o >>= 1) q += __shfl_xor(q, o);
    __shared__ float qs[4];
    if ((t & 63) == 0) qs[t >> 6] = q;
    __syncthreads();
    float n = sqrtf(qs[0] + qs[1] + qs[2] + qs[3]);
    float sc = 1.f / fmaxf(n, 1e-12f);
    TOK[(size_t)rid * DM + t]       = (h16)(v0 * sc);
    TOK[(size_t)rid * DM + t + 256] = (h16)(v1 * sc);
}

// ---------------------------------------------------------------- max-reduce dots -> sims
__global__ __launch_bounds__(256) void k_sim_h(const h16* __restrict__ dots,
                                               float* __restrict__ out) {
    int i = blockIdx.x;
    int j = threadIdx.x;
    const h16* p = dots + (size_t)i * 15872 + (size_t)j * NTOK_V;
    float mf = -1e30f, mv = -1e30f;
#pragma unroll
    for (int tt = 0; tt < 30; ++tt) mf = fmaxf(mf, (float)p[tt]);
#pragma unroll
    for (int tt = 30; tt < 62; ++tt) mv = fmaxf(mv, (float)p[tt]);
    int o = i * 256 + j;
    out[o]          = mf + mv;
    out[65536 + o]  = mf;
    out[131072 + o] = mv;
}

// ---------------------------------------------------------------- launcher
extern "C" void kernel_launch(void* const* d_in, const int* in_sizes, int n_in,
                              void* d_out, int out_size, void* d_ws, size_t ws_size,
                              hipStream_t stream) {
    const float* text   = (const float*)d_in[0];
    const float* frames = (const float*)d_in[1];
    const float* expt   = (const float*)d_in[2];
    const float* Wqkv   = (const float*)d_in[3];
    const float* bqkv   = (const float*)d_in[4];
    const float* Wo     = (const float*)d_in[5];
    const float* bo     = (const float*)d_in[6];
    const float* ln1w   = (const float*)d_in[7];
    const float* ln1b   = (const float*)d_in[8];
    const float* W1     = (const float*)d_in[9];
    const float* b1     = (const float*)d_in[10];
    const float* W2     = (const float*)d_in[11];
    const float* b2     = (const float*)d_in[12];
    const float* ln2w   = (const float*)d_in[13];
    const float* ln2b   = (const float*)d_in[14];
    float* out = (float*)d_out;

    char* wsb = (char*)d_ws;
    const size_t MB = 1024 * 1024;
    h16* Xh    = (h16*)(wsb);              // 8 MB   [8192,512]
    h16* P0    = (h16*)(wsb + 8 * MB);     // 8 MB   split-K partial 0
    h16* P1    = (h16*)(wsb + 16 * MB);    // 8 MB   split-K partial 1 (= P0 + 8192*512)
    h16* ATTh  = (h16*)(wsb + 24 * MB);    // 8 MB   [8192,512]
    h16* FFh   = (h16*)(wsb + 32 * MB);    // 32 MB  [8192,2048] (also QKV [8192,1536])
    h16* TOKh  = (h16*)(wsb + 32 * MB);    // alias FF: 15.5 MB [15872,512] (post-transformer)
    h16* DOTSh = (h16*)(wsb + 48 * MB);    // alias FF tail: 7.75 MB [256,15872]
    h16* Wh    = (h16*)(wsb + 64 * MB);    // 25 MB  all weights fp16
    h16* QHATh = (h16*)(wsb + 90 * MB);    // 0.25 MB [256,512]

    h16* Whqkv = Wh;                       // 4*1536*512
    h16* Who   = Whqkv + 3145728;          // 4*512*512
    h16* Wh1   = Who + 1048576;            // 4*2048*512
    h16* Wh2   = Wh1 + 4194304;            // 4*2048*512

    k_cvt<<<1536, 256, 0, stream>>>(Wqkv, Whqkv, 393216);
    k_cvt<<<512,  256, 0, stream>>>(Wo,   Who,   131072);
    k_cvt<<<2048, 256, 0, stream>>>(W1,   Wh1,   524288);
    k_cvt<<<2048, 256, 0, stream>>>(W2,   Wh2,   524288);
    k_concat_h<<<8192, 256, 0, stream>>>(frames, expt, Xh);

    for (int l = 0; l < 4; ++l) {
        const h16* Wqkv_l = Whqkv + (size_t)l * 786432;
        const h16* Wo_l   = Who   + (size_t)l * 262144;
        const h16* W1_l   = Wh1   + (size_t)l * 1048576;
        const h16* W2_l   = Wh2   + (size_t)l * 1048576;

        k_hgemm<0><<<dim3(12, 64, 1), 256, 0, stream>>>(
            Xh, 512, Wqkv_l, 512, bqkv + (size_t)l * 1536, FFh, 1536, 8192, 1536, 512);
        k_attn_h<<<2048, 256, 0, stream>>>(FFh, ATTh);
        k_hgemm<3><<<dim3(4, 64, 2), 256, 0, stream>>>(
            ATTh, 512, Wo_l, 512, nullptr, P0, 512, 8192, 512, 256);
        k_addln_red<<<8192, 256, 0, stream>>>(Xh, P0, P1, bo + (size_t)l * 512,
                                              ln1w + (size_t)l * 512, ln1b + (size_t)l * 512);
        k_hgemm<1><<<dim3(16, 64, 1), 256, 0, stream>>>(
            Xh, 512, W1_l, 512, b1 + (size_t)l * 2048, FFh, 2048, 8192, 2048, 512);
        k_hgemm<3><<<dim3(4, 64, 2), 256, 0, stream>>>(
            FFh, 2048, W2_l, 2048, nullptr, P0, 512, 8192, 512, 1024);
        k_addln_red<<<8192, 256, 0, stream>>>(Xh, P0, P1, b2 + (size_t)l * 512,
                                              ln2w + (size_t)l * 512, ln2b + (size_t)l * 512);
    }

    k_l2rows_h<<<256, 256, 0, stream>>>(text, QHATh);
    k_build_tok_h<<<256 * NTOK_V, 256, 0, stream>>>(frames, Xh, TOKh);
    k_hgemm<2><<<dim3(124, 2, 1), 256, 0, stream>>>(
        QHATh, 512, TOKh, 512, nullptr, DOTSh, 15872, 256, 15872, 512);
    k_sim_h<<<256, 256, 0, stream>>>(DOTSh, out);
}

// Round 7
// 692.744 us; speedup vs baseline: 1.4646x; 1.0033x over previous
//
#include <hip/hip_runtime.h>
#include <math.h>

#define DM 512
#define NTOK_V 62

typedef _Float16 h16;
typedef __attribute__((ext_vector_type(8))) _Float16 h16x8;
typedef __attribute__((ext_vector_type(4))) float f32x4;

__device__ __forceinline__ void ldsload16(const void* g, void* l) {
    __builtin_amdgcn_global_load_lds(
        (const __attribute__((address_space(1))) unsigned int*)g,
        (__attribute__((address_space(3))) unsigned int*)l, 16, 0, 0);
}

// ---------------------------------------------------------------- fp32 -> fp16 convert
__global__ __launch_bounds__(256) void k_cvt(const float* __restrict__ in,
                                             h16* __restrict__ outp, int n8) {
    int i = blockIdx.x * 256 + threadIdx.x;
    if (i >= n8) return;
    float4 a = ((const float4*)in)[i * 2];
    float4 b = ((const float4*)in)[i * 2 + 1];
    h16x8 h;
    h[0] = (h16)a.x; h[1] = (h16)a.y; h[2] = (h16)a.z; h[3] = (h16)a.w;
    h[4] = (h16)b.x; h[5] = (h16)b.y; h[6] = (h16)b.z; h[7] = (h16)b.w;
    ((h16x8*)outp)[i] = h;
}

// ---------------------------------------------------------------- concat -> fp16 X
__global__ __launch_bounds__(256) void k_concat_h(const float* __restrict__ frames,
                                                  const float* __restrict__ expt,
                                                  h16* __restrict__ X) {
    int row = blockIdx.x;
    int b = row >> 5, s = row & 31;
    int t = threadIdx.x;
    const float* src = (s < 30) ? (frames + ((size_t)(b * 30 + s)) * DM)
                                : (expt + (size_t)(s - 30) * DM);
    X[(size_t)row * DM + t]       = (h16)src[t];
    X[(size_t)row * DM + t + 256] = (h16)src[t + 256];
}

// ---------------------------------------------------------------- MFMA fp16 GEMM  C = A @ B^T
// 128x128 tile, 512 threads = 8 waves (2 row x 4 col), wave outputs 64x32 (acc 4x2).
// 3-slot LDS ring (48KB -> 3 blocks/CU = 24 waves/CU), distance-2 prefetch,
// counted vmcnt: steady "2" (one 2-load stage in flight past the waited one),
// tail 2,0. One barrier per K-step (R6-validated WAR-safe). Slot ids tracked
// incrementally (no % in hot loop).
// MODE: 0 = +bias, 1 = +bias+relu, 2 = plain, 3 = split-K partial (out at z*M*N)
template<int MODE>
__global__ __launch_bounds__(512, 4) void k_hgemm(
        const h16* __restrict__ A, int lda,
        const h16* __restrict__ B, int ldb,
        const float* __restrict__ bias,
        h16* __restrict__ C, int ldc,
        int M, int N, int Keff) {
    __shared__ char smem[49152];               // 3 slots x (A 8KB + B 8KB)
    const int t = threadIdx.x;
    const int w = t >> 6, lane = t & 63;
    const int wr = w >> 2, wc = w & 3;         // wave grid 2 x 4
    const int kc = lane >> 4, rr = lane & 15;
    const size_t row0 = (size_t)blockIdx.y * 128;
    const size_t col0 = (size_t)blockIdx.x * 128;
    const int z = blockIdx.z;

    // staging: wave w stages A rows w*16+rr and B rows w*16+rr (one 16B load each)
    const h16* gA = A + (size_t)z * Keff + (row0 + (w << 4) + rr) * (size_t)lda + (kc << 3);
    const h16* gB = B + (size_t)z * Keff + (col0 + (w << 4) + rr) * (size_t)ldb + (kc << 3);
    h16* Cz = C + (MODE == 3 ? (size_t)z * (size_t)M * N : (size_t)0);

    f32x4 acc[4][2];
#pragma unroll
    for (int m = 0; m < 4; ++m)
#pragma unroll
        for (int n = 0; n < 2; ++n) acc[m][n] = (f32x4){0.f, 0.f, 0.f, 0.f};

    const int nt = Keff >> 5;                  // K-steps (>= 8 for all call sites)

#define SB0 __builtin_amdgcn_sched_barrier(0);
#define STAGE(step, slot) { char* sA_ = smem + ((slot) << 14) + (w << 10); \
        ldsload16(gA + (size_t)(step) * 32, sA_); \
        ldsload16(gB + (size_t)(step) * 32, sA_ + 8192); }
#define KSTEP(WAITLIT, slotR, DOSTAGE, stepW, slotW) { \
        asm volatile("s_waitcnt vmcnt(" WAITLIT ")" ::: "memory"); \
        SB0 \
        __builtin_amdgcn_s_barrier(); \
        SB0 \
        const char* bA = smem + ((slotR) << 14); \
        const char* bB = bA + 8192; \
        h16x8 af[4], bf[2]; \
        _Pragma("unroll") for (int m = 0; m < 4; ++m) \
            af[m] = *(const h16x8*)(bA + ((wr << 2) + m) * 1024 + lane * 16); \
        _Pragma("unroll") for (int n = 0; n < 2; ++n) \
            bf[n] = *(const h16x8*)(bB + ((wc << 1) + n) * 1024 + lane * 16); \
        asm volatile("s_waitcnt lgkmcnt(0)" ::: "memory"); \
        SB0 \
        if (DOSTAGE) STAGE(stepW, slotW) \
        __builtin_amdgcn_s_setprio(1); \
        _Pragma("unroll") for (int m = 0; m < 4; ++m) \
        _Pragma("unroll") for (int n = 0; n < 2; ++n) \
            acc[m][n] = __builtin_amdgcn_mfma_f32_16x16x32_f16(af[m], bf[n], acc[m][n], 0, 0, 0); \
        __builtin_amdgcn_s_setprio(0); \
        SB0 }

    STAGE(0, 0) STAGE(1, 1)
    int slotR = 0, slotW = 2;
    int it = 0;
    for (; it < nt - 2; ++it) {
        KSTEP("2", slotR, 1, it + 2, slotW)
        slotR = (slotR == 2) ? 0 : slotR + 1;
        slotW = (slotW == 2) ? 0 : slotW + 1;
    }
    KSTEP("2", slotR, 0, 0, 0)
    slotR = (slotR == 2) ? 0 : slotR + 1;
    KSTEP("0", slotR, 0, 0, 0)
#undef KSTEP
#undef STAGE
#undef SB0

    // epilogue: direct stores, 16-lane groups write 32B segments
#pragma unroll
    for (int n = 0; n < 2; ++n) {
        size_t col = col0 + (wc << 5) + n * 16 + rr;
        float bv = (MODE == 0 || MODE == 1) ? bias[col] : 0.f;
#pragma unroll
        for (int m = 0; m < 4; ++m) {
            size_t rbase = row0 + (wr << 6) + m * 16 + (kc << 2);
#pragma unroll
            for (int j = 0; j < 4; ++j) {
                float v = acc[m][n][j] + bv;
                if (MODE == 1) v = fmaxf(v, 0.f);
                Cz[(rbase + j) * (size_t)ldc + col] = (h16)v;
            }
        }
    }
}

// ---------------------------------------------------------------- attention, one block per (b,h)
__global__ __launch_bounds__(256) void k_attn_h(const h16* __restrict__ qkv,
                                                h16* __restrict__ att) {
    __shared__ float q[32][65], k[32][65], v[32][65];
    __shared__ float sc[32][33];
    int b = blockIdx.x >> 3, h = blockIdx.x & 7;
    int t = threadIdx.x;
    const h16* base = qkv + (size_t)b * 32 * 1536 + h * 64;
    for (int i = t; i < 2048; i += 256) {
        int s = i >> 6, d = i & 63;
        size_t ro = (size_t)s * 1536 + d;
        q[s][d] = (float)base[ro];
        k[s][d] = (float)base[ro + 512];
        v[s][d] = (float)base[ro + 1024];
    }
    __syncthreads();
    {
        int r = t >> 3, c0 = (t & 7) << 2;
        float s0 = 0.f, s1 = 0.f, s2 = 0.f, s3 = 0.f;
#pragma unroll 8
        for (int d = 0; d < 64; ++d) {
            float qv = q[r][d];
            s0 += qv * k[c0 + 0][d];
            s1 += qv * k[c0 + 1][d];
            s2 += qv * k[c0 + 2][d];
            s3 += qv * k[c0 + 3][d];
        }
        sc[r][c0 + 0] = s0 * 0.125f;
        sc[r][c0 + 1] = s1 * 0.125f;
        sc[r][c0 + 2] = s2 * 0.125f;
        sc[r][c0 + 3] = s3 * 0.125f;
    }
    __syncthreads();
    {   // wave-parallel softmax: 8 lanes per row
        int r = t >> 3, c0 = (t & 7) << 2;
        float a0 = sc[r][c0], a1 = sc[r][c0 + 1], a2 = sc[r][c0 + 2], a3 = sc[r][c0 + 3];
        float mx = fmaxf(fmaxf(a0, a1), fmaxf(a2, a3));
        mx = fmaxf(mx, __shfl_xor(mx, 1));
        mx = fmaxf(mx, __shfl_xor(mx, 2));
        mx = fmaxf(mx, __shfl_xor(mx, 4));
        float e0 = expf(a0 - mx), e1 = expf(a1 - mx), e2 = expf(a2 - mx), e3 = expf(a3 - mx);
        float sm = e0 + e1 + e2 + e3;
        sm += __shfl_xor(sm, 1);
        sm += __shfl_xor(sm, 2);
        sm += __shfl_xor(sm, 4);
        float inv = 1.f / sm;
        sc[r][c0] = e0 * inv; sc[r][c0 + 1] = e1 * inv; sc[r][c0 + 2] = e2 * inv; sc[r][c0 + 3] = e3 * inv;
    }
    __syncthreads();
    for (int i = t; i < 2048; i += 256) {
        int s = i >> 6, d = i & 63;
        float acc = 0.f;
#pragma unroll 8
        for (int c = 0; c < 32; ++c) acc += sc[s][c] * v[c][d];
        att[((size_t)b * 32 + s) * DM + h * 64 + d] = (h16)acc;
    }
}

// ---------------------------------------------------------------- x = LN(x + p0 + p1 + bias)*w + b
__global__ __launch_bounds__(256) void k_addln_red(h16* __restrict__ x,
                                                   const h16* __restrict__ p0,
                                                   const h16* __restrict__ p1,
                                                   const float* __restrict__ bias,
                                                   const float* __restrict__ w,
                                                   const float* __restrict__ b) {
    size_t row = blockIdx.x;
    int t = threadIdx.x;
    size_t o0 = row * DM + t, o1 = o0 + 256;
    float v0 = (float)x[o0] + (float)p0[o0] + (float)p1[o0] + bias[t];
    float v1 = (float)x[o1] + (float)p0[o1] + (float)p1[o1] + bias[t + 256];
    float s = v0 + v1;
#pragma unroll
    for (int o = 32; o; o >>= 1) s += __shfl_xor(s, o);
    __shared__ float ss[4], qs[4];
    if ((t & 63) == 0) ss[t >> 6] = s;
    __syncthreads();
    float mean = (ss[0] + ss[1] + ss[2] + ss[3]) * (1.f / 512.f);
    float d0 = v0 - mean, d1 = v1 - mean;
    float qv = d0 * d0 + d1 * d1;
#pragma unroll
    for (int o = 32; o; o >>= 1) qv += __shfl_xor(qv, o);
    if ((t & 63) == 0) qs[t >> 6] = qv;
    __syncthreads();
    float var = (qs[0] + qs[1] + qs[2] + qs[3]) * (1.f / 512.f);
    float inv = 1.f / sqrtf(var + 1e-5f);
    x[o0] = (h16)(d0 * inv * w[t] + b[t]);
    x[o1] = (h16)(d1 * inv * w[t + 256] + b[t + 256]);
}

// ---------------------------------------------------------------- l2 rows: f32 in -> f16 out
__global__ __launch_bounds__(256) void k_l2rows_h(const float* __restrict__ in,
                                                  h16* __restrict__ outp) {
    size_t row = blockIdx.x;
    int t = threadIdx.x;
    float v0 = in[row * DM + t], v1 = in[row * DM + t + 256];
    float q = v0 * v0 + v1 * v1;
#pragma unroll
    for (int o = 32; o; o >>= 1) q += __shfl_xor(q, o);
    __shared__ float qs[4];
    if ((t & 63) == 0) qs[t >> 6] = q;
    __syncthreads();
    float n = sqrtf(qs[0] + qs[1] + qs[2] + qs[3]);
    float sc = 1.f / fmaxf(n, 1e-12f);
    outp[row * DM + t]       = (h16)(v0 * sc);
    outp[row * DM + t + 256] = (h16)(v1 * sc);
}

// ---------------------------------------------------------------- TOK rows (l2'd frames + video tokens)
__global__ __launch_bounds__(256) void k_build_tok_h(const float* __restrict__ frames,
                                                     const h16* __restrict__ X,
                                                     h16* __restrict__ TOK) {
    int rid = blockIdx.x;
    int j = rid / NTOK_V, tt = rid % NTOK_V;
    int t = threadIdx.x;
    float v0, v1;
    if (tt < 30) {
        const float* src = frames + ((size_t)j * 30 + tt) * DM;
        v0 = src[t]; v1 = src[t + 256];
    } else {
        const h16* src = X + ((size_t)j * 32 + (tt - 30)) * DM;
        v0 = (float)src[t]; v1 = (float)src[t + 256];
    }
    float q = v0 * v0 + v1 * v1;
#pragma unroll
    for (int o = 32; o; o >>= 1) q += __shfl_xor(q, o);
    __shared__ float qs[4];
    if ((t & 63) == 0) qs[t >> 6] = q;
    __syncthreads();
    float n = sqrtf(qs[0] + qs[1] + qs[2] + qs[3]);
    float sc = 1.f / fmaxf(n, 1e-12f);
    TOK[(size_t)rid * DM + t]       = (h16)(v0 * sc);
    TOK[(size_t)rid * DM + t + 256] = (h16)(v1 * sc);
}

// ---------------------------------------------------------------- max-reduce dots -> sims
__global__ __launch_bounds__(256) void k_sim_h(const h16* __restrict__ dots,
                                               float* __restrict__ out) {
    int i = blockIdx.x;
    int j = threadIdx.x;
    const h16* p = dots + (size_t)i * 15872 + (size_t)j * NTOK_V;
    float mf = -1e30f, mv = -1e30f;
#pragma unroll
    for (int tt = 0; tt < 30; ++tt) mf = fmaxf(mf, (float)p[tt]);
#pragma unroll
    for (int tt = 30; tt < 62; ++tt) mv = fmaxf(mv, (float)p[tt]);
    int o = i * 256 + j;
    out[o]          = mf + mv;
    out[65536 + o]  = mf;
    out[131072 + o] = mv;
}

// ---------------------------------------------------------------- launcher
extern "C" void kernel_launch(void* const* d_in, const int* in_sizes, int n_in,
                              void* d_out, int out_size, void* d_ws, size_t ws_size,
                              hipStream_t stream) {
    const float* text   = (const float*)d_in[0];
    const float* frames = (const float*)d_in[1];
    const float* expt   = (const float*)d_in[2];
    const float* Wqkv   = (const float*)d_in[3];
    const float* bqkv   = (const float*)d_in[4];
    const float* Wo     = (const float*)d_in[5];
    const float* bo     = (const float*)d_in[6];
    const float* ln1w   = (const float*)d_in[7];
    const float* ln1b   = (const float*)d_in[8];
    const float* W1     = (const float*)d_in[9];
    const float* b1     = (const float*)d_in[10];
    const float* W2     = (const float*)d_in[11];
    const float* b2     = (const float*)d_in[12];
    const float* ln2w   = (const float*)d_in[13];
    const float* ln2b   = (const float*)d_in[14];
    float* out = (float*)d_out;

    char* wsb = (char*)d_ws;
    const size_t MB = 1024 * 1024;
    h16* Xh    = (h16*)(wsb);              // 8 MB   [8192,512]
    h16* P0    = (h16*)(wsb + 8 * MB);     // 8 MB   split-K partial 0
    h16* P1    = (h16*)(wsb + 16 * MB);    // 8 MB   split-K partial 1 (= P0 + 8192*512)
    h16* ATTh  = (h16*)(wsb + 24 * MB);    // 8 MB   [8192,512]
    h16* FFh   = (h16*)(wsb + 32 * MB);    // 32 MB  [8192,2048] (also QKV [8192,1536])
    h16* TOKh  = (h16*)(wsb + 32 * MB);    // alias FF: 15.5 MB [15872,512] (post-transformer)
    h16* DOTSh = (h16*)(wsb + 48 * MB);    // alias FF tail: 7.75 MB [256,15872]
    h16* Wh    = (h16*)(wsb + 64 * MB);    // 25 MB  all weights fp16
    h16* QHATh = (h16*)(wsb + 90 * MB);    // 0.25 MB [256,512]

    h16* Whqkv = Wh;                       // 4*1536*512
    h16* Who   = Whqkv + 3145728;          // 4*512*512
    h16* Wh1   = Who + 1048576;            // 4*2048*512
    h16* Wh2   = Wh1 + 4194304;            // 4*2048*512

    k_cvt<<<1536, 256, 0, stream>>>(Wqkv, Whqkv, 393216);
    k_cvt<<<512,  256, 0, stream>>>(Wo,   Who,   131072);
    k_cvt<<<2048, 256, 0, stream>>>(W1,   Wh1,   524288);
    k_cvt<<<2048, 256, 0, stream>>>(W2,   Wh2,   524288);
    k_concat_h<<<8192, 256, 0, stream>>>(frames, expt, Xh);

    for (int l = 0; l < 4; ++l) {
        const h16* Wqkv_l = Whqkv + (size_t)l * 786432;
        const h16* Wo_l   = Who   + (size_t)l * 262144;
        const h16* W1_l   = Wh1   + (size_t)l * 1048576;
        const h16* W2_l   = Wh2   + (size_t)l * 1048576;

        k_hgemm<0><<<dim3(12, 64, 1), 512, 0, stream>>>(
            Xh, 512, Wqkv_l, 512, bqkv + (size_t)l * 1536, FFh, 1536, 8192, 1536, 512);
        k_attn_h<<<2048, 256, 0, stream>>>(FFh, ATTh);
        k_hgemm<3><<<dim3(4, 64, 2), 512, 0, stream>>>(
            ATTh, 512, Wo_l, 512, nullptr, P0, 512, 8192, 512, 256);
        k_addln_red<<<8192, 256, 0, stream>>>(Xh, P0, P1, bo + (size_t)l * 512,
                                              ln1w + (size_t)l * 512, ln1b + (size_t)l * 512);
        k_hgemm<1><<<dim3(16, 64, 1), 512, 0, stream>>>(
            Xh, 512, W1_l, 512, b1 + (size_t)l * 2048, FFh, 2048, 8192, 2048, 512);
        k_hgemm<3><<<dim3(4, 64, 2), 512, 0, stream>>>(
            FFh, 2048, W2_l, 2048, nullptr, P0, 512, 8192, 512, 1024);
        k_addln_red<<<8192, 256, 0, stream>>>(Xh, P0, P1, b2 + (size_t)l * 512,
                                              ln2w + (size_t)l * 512, ln2b + (size_t)l * 512);
    }

    k_l2rows_h<<<256, 256, 0, stream>>>(text, QHATh);
    k_build_tok_h<<<256 * NTOK_V, 256, 0, stream>>>(frames, Xh, TOKh);
    k_hgemm<2><<<dim3(124, 2, 1), 512, 0, stream>>>(
        QHATh, 512, TOKh, 512, nullptr, DOTSh, 15872, 256, 15872, 512);
    k_sim_h<<<256, 256, 0, stream>>>(DOTSh, out);
}

// Round 8
// 675.187 us; speedup vs baseline: 1.5027x; 1.0260x over previous
//
#include <hip/hip_runtime.h>
#include <math.h>

#define DM 512
#define NTOK_V 62

typedef _Float16 h16;
typedef __attribute__((ext_vector_type(8))) _Float16 h16x8;
typedef __attribute__((ext_vector_type(4))) float f32x4;

__device__ __forceinline__ void ldsload16(const void* g, void* l) {
    __builtin_amdgcn_global_load_lds(
        (const __attribute__((address_space(1))) unsigned int*)g,
        (__attribute__((address_space(3))) unsigned int*)l, 16, 0, 0);
}

// ---------------------------------------------------------------- fp32 -> fp16 convert
__global__ __launch_bounds__(256) void k_cvt(const float* __restrict__ in,
                                             h16* __restrict__ outp, int n8) {
    int i = blockIdx.x * 256 + threadIdx.x;
    if (i >= n8) return;
    float4 a = ((const float4*)in)[i * 2];
    float4 b = ((const float4*)in)[i * 2 + 1];
    h16x8 h;
    h[0] = (h16)a.x; h[1] = (h16)a.y; h[2] = (h16)a.z; h[3] = (h16)a.w;
    h[4] = (h16)b.x; h[5] = (h16)b.y; h[6] = (h16)b.z; h[7] = (h16)b.w;
    ((h16x8*)outp)[i] = h;
}

// ---------------------------------------------------------------- concat -> fp16 X
__global__ __launch_bounds__(256) void k_concat_h(const float* __restrict__ frames,
                                                  const float* __restrict__ expt,
                                                  h16* __restrict__ X) {
    int row = blockIdx.x;
    int b = row >> 5, s = row & 31;
    int t = threadIdx.x;
    const float* src = (s < 30) ? (frames + ((size_t)(b * 30 + s)) * DM)
                                : (expt + (size_t)(s - 30) * DM);
    X[(size_t)row * DM + t]       = (h16)src[t];
    X[(size_t)row * DM + t + 256] = (h16)src[t + 256];
}

// ---------------------------------------------------------------- 8-phase 256x256 MFMA GEMM (m201-style)
// C = A @ B^T. 512 thr = 8 waves (2M x 4N), wave = 128x64 out (acc 8x4).
// BK=64 K-tiles, 2x64KB LDS double-buffer. Per tile: 4 phases, each
// {ds_reads || stage 1 half-tile (2 gloads) -> lgkmcnt(0) -> barrier -> 16 MFMA}.
// vmcnt(2) only at tile boundary (boundary stage pushes outstanding to 10 -> the
// next tile's 8 loads retire). lgkmcnt(0) BEFORE each barrier closes the WAR race
// on the old buffer. Fragment-native LDS: 1KB block = 16 rows x 32 k, lane*16B
// IS the MFMA fragment -> conflict-free gload dest AND ds_read, no swizzle.
// MODE: 0 = +bias, 1 = +bias+relu
template<int MODE>
__global__ __launch_bounds__(512, 2) void k_g8(
        const h16* __restrict__ A, int lda,
        const h16* __restrict__ B, int ldb,
        const float* __restrict__ bias,
        h16* __restrict__ C, int ldc,
        int M, int N, int Keff) {
    __shared__ char smem[131072];              // 2 bufs x (A 2x16KB + B 2x16KB)
    const int t = threadIdx.x;
    const int w = t >> 6, lane = t & 63;
    const int wr = w >> 2, wc = w & 3;         // wave grid 2 x 4
    const int kc = lane >> 4, rr = lane & 15;
    const size_t row0 = (size_t)blockIdx.y * 256;
    const size_t col0 = (size_t)blockIdx.x * 256;

    // staging base: thread covers (row/col = h*128 + w*16 + rr, k = q*32 + kc*8)
    const h16* gA = A + (row0 + (w << 4) + rr) * (size_t)lda + (kc << 3);
    const h16* gB = B + (col0 + (w << 4) + rr) * (size_t)ldb + (kc << 3);

    f32x4 acc[8][4];
#pragma unroll
    for (int m = 0; m < 8; ++m)
#pragma unroll
        for (int n = 0; n < 4; ++n) acc[m][n] = (f32x4){0.f, 0.f, 0.f, 0.f};

    const int nt = Keff >> 6;                  // K-tiles (8 for K=512)

#define SB0 __builtin_amdgcn_sched_barrier(0);
#define STG_A(bs, h, jt) { char* d_ = smem + (bs)*65536 + (h)*16384 + (w << 10) + (lane << 4); \
        const h16* s_ = gA + (size_t)((h)*128) * lda + (size_t)(jt)*64; \
        ldsload16(s_, d_); ldsload16(s_ + 32, d_ + 8192); }
#define STG_B(bs, h, jt) { char* d_ = smem + (bs)*65536 + 32768 + (h)*16384 + (w << 10) + (lane << 4); \
        const h16* s_ = gB + (size_t)((h)*128) * ldb + (size_t)(jt)*64; \
        ldsload16(s_, d_); ldsload16(s_ + 32, d_ + 8192); }
#define MFMA16(mp, AF) { \
        __builtin_amdgcn_s_setprio(1); \
        _Pragma("unroll") for (int i = 0; i < 2; ++i) \
        _Pragma("unroll") for (int n = 0; n < 4; ++n) \
        _Pragma("unroll") for (int kk = 0; kk < 2; ++kk) \
            acc[(mp)*2 + i][n] = __builtin_amdgcn_mfma_f32_16x16x32_f16(AF[i][kk], bf[n][kk], acc[(mp)*2 + i][n], 0, 0, 0); \
        __builtin_amdgcn_s_setprio(0); SB0 }

    // prologue: stage tile 0 into buf 0 (8 loads)
    STG_A(0, 0, 0) STG_A(0, 1, 0) STG_B(0, 0, 0) STG_B(0, 1, 0)

    int cur = 0;
    for (int j = 0; j < nt; ++j) {
        const int nxt = cur ^ 1;
        // ---- phase 0 (tile boundary)
        if (j + 1 < nt) {
            STG_A(nxt, 0, j + 1)
            asm volatile("s_waitcnt vmcnt(2)" ::: "memory");
        } else {
            asm volatile("s_waitcnt vmcnt(0)" ::: "memory");
        }
        SB0
        __builtin_amdgcn_s_barrier();
        SB0
        const char* Ab = smem + cur * 65536 + wr * 16384;
        const char* Bb = smem + cur * 65536 + 32768 + (wc >> 1) * 16384;
        h16x8 bf[4][2];
#pragma unroll
        for (int n = 0; n < 4; ++n)
#pragma unroll
            for (int kk = 0; kk < 2; ++kk)
                bf[n][kk] = *(const h16x8*)(Bb + kk * 8192 + (((wc & 1) << 2) + n) * 1024 + (lane << 4));
        h16x8 a0[2][2];
#pragma unroll
        for (int i = 0; i < 2; ++i)
#pragma unroll
            for (int kk = 0; kk < 2; ++kk)
                a0[i][kk] = *(const h16x8*)(Ab + kk * 8192 + (0 + i) * 1024 + (lane << 4));
        asm volatile("s_waitcnt lgkmcnt(0)" ::: "memory");
        SB0
        MFMA16(0, a0)
        // ---- phase 1
        h16x8 a1[2][2];
#pragma unroll
        for (int i = 0; i < 2; ++i)
#pragma unroll
            for (int kk = 0; kk < 2; ++kk)
                a1[i][kk] = *(const h16x8*)(Ab + kk * 8192 + (2 + i) * 1024 + (lane << 4));
        if (j + 1 < nt) STG_A(nxt, 1, j + 1)
        asm volatile("s_waitcnt lgkmcnt(0)" ::: "memory");
        SB0
        __builtin_amdgcn_s_barrier();
        SB0
        MFMA16(1, a1)
        // ---- phase 2
        h16x8 a2[2][2];
#pragma unroll
        for (int i = 0; i < 2; ++i)
#pragma unroll
            for (int kk = 0; kk < 2; ++kk)
                a2[i][kk] = *(const h16x8*)(Ab + kk * 8192 + (4 + i) * 1024 + (lane << 4));
        if (j + 1 < nt) STG_B(nxt, 0, j + 1)
        asm volatile("s_waitcnt lgkmcnt(0)" ::: "memory");
        SB0
        __builtin_amdgcn_s_barrier();
        SB0
        MFMA16(2, a2)
        // ---- phase 3
        h16x8 a3[2][2];
#pragma unroll
        for (int i = 0; i < 2; ++i)
#pragma unroll
            for (int kk = 0; kk < 2; ++kk)
                a3[i][kk] = *(const h16x8*)(Ab + kk * 8192 + (6 + i) * 1024 + (lane << 4));
        if (j + 1 < nt) STG_B(nxt, 1, j + 1)
        asm volatile("s_waitcnt lgkmcnt(0)" ::: "memory");
        SB0
        __builtin_amdgcn_s_barrier();
        SB0
        MFMA16(3, a3)
        cur = nxt;
    }
#undef MFMA16
#undef STG_A
#undef STG_B
#undef SB0

    // epilogue: direct stores (R7-proven indexing)
#pragma unroll
    for (int n = 0; n < 4; ++n) {
        size_t col = col0 + (wc << 6) + n * 16 + rr;
        float bv = bias ? bias[col] : 0.f;
#pragma unroll
        for (int m = 0; m < 8; ++m) {
            size_t rbase = row0 + (wr << 7) + m * 16 + (kc << 2);
#pragma unroll
            for (int jj = 0; jj < 4; ++jj) {
                float v = acc[m][n][jj] + bv;
                if (MODE == 1) v = fmaxf(v, 0.f);
                C[(rbase + jj) * (size_t)ldc + col] = (h16)v;
            }
        }
    }
}

// ---------------------------------------------------------------- 128x128 2-phase GEMM (R7, proven)
// MODE: 0 = +bias, 1 = +bias+relu, 2 = plain, 3 = split-K partial (out at z*M*N)
template<int MODE>
__global__ __launch_bounds__(512, 4) void k_hgemm(
        const h16* __restrict__ A, int lda,
        const h16* __restrict__ B, int ldb,
        const float* __restrict__ bias,
        h16* __restrict__ C, int ldc,
        int M, int N, int Keff) {
    __shared__ char smem[49152];               // 3 slots x (A 8KB + B 8KB)
    const int t = threadIdx.x;
    const int w = t >> 6, lane = t & 63;
    const int wr = w >> 2, wc = w & 3;         // wave grid 2 x 4
    const int kc = lane >> 4, rr = lane & 15;
    const size_t row0 = (size_t)blockIdx.y * 128;
    const size_t col0 = (size_t)blockIdx.x * 128;
    const int z = blockIdx.z;

    const h16* gA = A + (size_t)z * Keff + (row0 + (w << 4) + rr) * (size_t)lda + (kc << 3);
    const h16* gB = B + (size_t)z * Keff + (col0 + (w << 4) + rr) * (size_t)ldb + (kc << 3);
    h16* Cz = C + (MODE == 3 ? (size_t)z * (size_t)M * N : (size_t)0);

    f32x4 acc[4][2];
#pragma unroll
    for (int m = 0; m < 4; ++m)
#pragma unroll
        for (int n = 0; n < 2; ++n) acc[m][n] = (f32x4){0.f, 0.f, 0.f, 0.f};

    const int nt = Keff >> 5;

#define SB0 __builtin_amdgcn_sched_barrier(0);
#define STAGE(step, slot) { char* sA_ = smem + ((slot) << 14) + (w << 10); \
        ldsload16(gA + (size_t)(step) * 32, sA_); \
        ldsload16(gB + (size_t)(step) * 32, sA_ + 8192); }
#define KSTEP(WAITLIT, slotR, DOSTAGE, stepW, slotW) { \
        asm volatile("s_waitcnt vmcnt(" WAITLIT ")" ::: "memory"); \
        SB0 \
        __builtin_amdgcn_s_barrier(); \
        SB0 \
        const char* bA = smem + ((slotR) << 14); \
        const char* bB = bA + 8192; \
        h16x8 af[4], bf[2]; \
        _Pragma("unroll") for (int m = 0; m < 4; ++m) \
            af[m] = *(const h16x8*)(bA + ((wr << 2) + m) * 1024 + lane * 16); \
        _Pragma("unroll") for (int n = 0; n < 2; ++n) \
            bf[n] = *(const h16x8*)(bB + ((wc << 1) + n) * 1024 + lane * 16); \
        asm volatile("s_waitcnt lgkmcnt(0)" ::: "memory"); \
        SB0 \
        if (DOSTAGE) STAGE(stepW, slotW) \
        __builtin_amdgcn_s_setprio(1); \
        _Pragma("unroll") for (int m = 0; m < 4; ++m) \
        _Pragma("unroll") for (int n = 0; n < 2; ++n) \
            acc[m][n] = __builtin_amdgcn_mfma_f32_16x16x32_f16(af[m], bf[n], acc[m][n], 0, 0, 0); \
        __builtin_amdgcn_s_setprio(0); \
        SB0 }

    STAGE(0, 0) STAGE(1, 1)
    int slotR = 0, slotW = 2;
    int it = 0;
    for (; it < nt - 2; ++it) {
        KSTEP("2", slotR, 1, it + 2, slotW)
        slotR = (slotR == 2) ? 0 : slotR + 1;
        slotW = (slotW == 2) ? 0 : slotW + 1;
    }
    KSTEP("2", slotR, 0, 0, 0)
    slotR = (slotR == 2) ? 0 : slotR + 1;
    KSTEP("0", slotR, 0, 0, 0)
#undef KSTEP
#undef STAGE
#undef SB0

#pragma unroll
    for (int n = 0; n < 2; ++n) {
        size_t col = col0 + (wc << 5) + n * 16 + rr;
        float bv = (MODE == 0 || MODE == 1) ? bias[col] : 0.f;
#pragma unroll
        for (int m = 0; m < 4; ++m) {
            size_t rbase = row0 + (wr << 6) + m * 16 + (kc << 2);
#pragma unroll
            for (int j = 0; j < 4; ++j) {
                float v = acc[m][n][j] + bv;
                if (MODE == 1) v = fmaxf(v, 0.f);
                Cz[(rbase + j) * (size_t)ldc + col] = (h16)v;
            }
        }
    }
}

// ---------------------------------------------------------------- attention, one block per (b,h)
__global__ __launch_bounds__(256) void k_attn_h(const h16* __restrict__ qkv,
                                                h16* __restrict__ att) {
    __shared__ float q[32][65], k[32][65], v[32][65];
    __shared__ float sc[32][33];
    int b = blockIdx.x >> 3, h = blockIdx.x & 7;
    int t = threadIdx.x;
    const h16* base = qkv + (size_t)b * 32 * 1536 + h * 64;
    for (int i = t; i < 2048; i += 256) {
        int s = i >> 6, d = i & 63;
        size_t ro = (size_t)s * 1536 + d;
        q[s][d] = (float)base[ro];
        k[s][d] = (float)base[ro + 512];
        v[s][d] = (float)base[ro + 1024];
    }
    __syncthreads();
    {
        int r = t >> 3, c0 = (t & 7) << 2;
        float s0 = 0.f, s1 = 0.f, s2 = 0.f, s3 = 0.f;
#pragma unroll 8
        for (int d = 0; d < 64; ++d) {
            float qv = q[r][d];
            s0 += qv * k[c0 + 0][d];
            s1 += qv * k[c0 + 1][d];
            s2 += qv * k[c0 + 2][d];
            s3 += qv * k[c0 + 3][d];
        }
        sc[r][c0 + 0] = s0 * 0.125f;
        sc[r][c0 + 1] = s1 * 0.125f;
        sc[r][c0 + 2] = s2 * 0.125f;
        sc[r][c0 + 3] = s3 * 0.125f;
    }
    __syncthreads();
    {   // wave-parallel softmax: 8 lanes per row
        int r = t >> 3, c0 = (t & 7) << 2;
        float a0 = sc[r][c0], a1 = sc[r][c0 + 1], a2 = sc[r][c0 + 2], a3 = sc[r][c0 + 3];
        float mx = fmaxf(fmaxf(a0, a1), fmaxf(a2, a3));
        mx = fmaxf(mx, __shfl_xor(mx, 1));
        mx = fmaxf(mx, __shfl_xor(mx, 2));
        mx = fmaxf(mx, __shfl_xor(mx, 4));
        float e0 = expf(a0 - mx), e1 = expf(a1 - mx), e2 = expf(a2 - mx), e3 = expf(a3 - mx);
        float sm = e0 + e1 + e2 + e3;
        sm += __shfl_xor(sm, 1);
        sm += __shfl_xor(sm, 2);
        sm += __shfl_xor(sm, 4);
        float inv = 1.f / sm;
        sc[r][c0] = e0 * inv; sc[r][c0 + 1] = e1 * inv; sc[r][c0 + 2] = e2 * inv; sc[r][c0 + 3] = e3 * inv;
    }
    __syncthreads();
    for (int i = t; i < 2048; i += 256) {
        int s = i >> 6, d = i & 63;
        float acc = 0.f;
#pragma unroll 8
        for (int c = 0; c < 32; ++c) acc += sc[s][c] * v[c][d];
        att[((size_t)b * 32 + s) * DM + h * 64 + d] = (h16)acc;
    }
}

// ---------------------------------------------------------------- x = LN(x + p0 + p1 + bias)*w + b
__global__ __launch_bounds__(256) void k_addln_red(h16* __restrict__ x,
                                                   const h16* __restrict__ p0,
                                                   const h16* __restrict__ p1,
                                                   const float* __restrict__ bias,
                                                   const float* __restrict__ w,
                                                   const float* __restrict__ b) {
    size_t row = blockIdx.x;
    int t = threadIdx.x;
    size_t o0 = row * DM + t, o1 = o0 + 256;
    float v0 = (float)x[o0] + (float)p0[o0] + (float)p1[o0] + bias[t];
    float v1 = (float)x[o1] + (float)p0[o1] + (float)p1[o1] + bias[t + 256];
    float s = v0 + v1;
#pragma unroll
    for (int o = 32; o; o >>= 1) s += __shfl_xor(s, o);
    __shared__ float ss[4], qs[4];
    if ((t & 63) == 0) ss[t >> 6] = s;
    __syncthreads();
    float mean = (ss[0] + ss[1] + ss[2] + ss[3]) * (1.f / 512.f);
    float d0 = v0 - mean, d1 = v1 - mean;
    float qv = d0 * d0 + d1 * d1;
#pragma unroll
    for (int o = 32; o; o >>= 1) qv += __shfl_xor(qv, o);
    if ((t & 63) == 0) qs[t >> 6] = qv;
    __syncthreads();
    float var = (qs[0] + qs[1] + qs[2] + qs[3]) * (1.f / 512.f);
    float inv = 1.f / sqrtf(var + 1e-5f);
    x[o0] = (h16)(d0 * inv * w[t] + b[t]);
    x[o1] = (h16)(d1 * inv * w[t + 256] + b[t + 256]);
}

// ---------------------------------------------------------------- l2 rows: f32 in -> f16 out
__global__ __launch_bounds__(256) void k_l2rows_h(const float* __restrict__ in,
                                                  h16* __restrict__ outp) {
    size_t row = blockIdx.x;
    int t = threadIdx.x;
    float v0 = in[row * DM + t], v1 = in[row * DM + t + 256];
    float q = v0 * v0 + v1 * v1;
#pragma unroll
    for (int o = 32; o; o >>= 1) q += __shfl_xor(q, o);
    __shared__ float qs[4];
    if ((t & 63) == 0) qs[t >> 6] = q;
    __syncthreads();
    float n = sqrtf(qs[0] + qs[1] + qs[2] + qs[3]);
    float sc = 1.f / fmaxf(n, 1e-12f);
    outp[row * DM + t]       = (h16)(v0 * sc);
    outp[row * DM + t + 256] = (h16)(v1 * sc);
}

// ---------------------------------------------------------------- TOK rows (l2'd frames + video tokens)
__global__ __launch_bounds__(256) void k_build_tok_h(const float* __restrict__ frames,
                                                     const h16* __restrict__ X,
                                                     h16* __restrict__ TOK) {
    int rid = blockIdx.x;
    int j = rid / NTOK_V, tt = rid % NTOK_V;
    int t = threadIdx.x;
    float v0, v1;
    if (tt < 30) {
        const float* src = frames + ((size_t)j * 30 + tt) * DM;
        v0 = src[t]; v1 = src[t + 256];
    } else {
        const h16* src = X + ((size_t)j * 32 + (tt - 30)) * DM;
        v0 = (float)src[t]; v1 = (float)src[t + 256];
    }
    float q = v0 * v0 + v1 * v1;
#pragma unroll
    for (int o = 32; o; o >>= 1) q += __shfl_xor(q, o);
    __shared__ float qs[4];
    if ((t & 63) == 0) qs[t >> 6] = q;
    __syncthreads();
    float n = sqrtf(qs[0] + qs[1] + qs[2] + qs[3]);
    float sc = 1.f / fmaxf(n, 1e-12f);
    TOK[(size_t)rid * DM + t]       = (h16)(v0 * sc);
    TOK[(size_t)rid * DM + t + 256] = (h16)(v1 * sc);
}

// ---------------------------------------------------------------- max-reduce dots -> sims
__global__ __launch_bounds__(256) void k_sim_h(const h16* __restrict__ dots,
                                               float* __restrict__ out) {
    int i = blockIdx.x;
    int j = threadIdx.x;
    const h16* p = dots + (size_t)i * 15872 + (size_t)j * NTOK_V;
    float mf = -1e30f, mv = -1e30f;
#pragma unroll
    for (int tt = 0; tt < 30; ++tt) mf = fmaxf(mf, (float)p[tt]);
#pragma unroll
    for (int tt = 30; tt < 62; ++tt) mv = fmaxf(mv, (float)p[tt]);
    int o = i * 256 + j;
    out[o]          = mf + mv;
    out[65536 + o]  = mf;
    out[131072 + o] = mv;
}

// ---------------------------------------------------------------- launcher
extern "C" void kernel_launch(void* const* d_in, const int* in_sizes, int n_in,
                              void* d_out, int out_size, void* d_ws, size_t ws_size,
                              hipStream_t stream) {
    const float* text   = (const float*)d_in[0];
    const float* frames = (const float*)d_in[1];
    const float* expt   = (const float*)d_in[2];
    const float* Wqkv   = (const float*)d_in[3];
    const float* bqkv   = (const float*)d_in[4];
    const float* Wo     = (const float*)d_in[5];
    const float* bo     = (const float*)d_in[6];
    const float* ln1w   = (const float*)d_in[7];
    const float* ln1b   = (const float*)d_in[8];
    const float* W1     = (const float*)d_in[9];
    const float* b1     = (const float*)d_in[10];
    const float* W2     = (const float*)d_in[11];
    const float* b2     = (const float*)d_in[12];
    const float* ln2w   = (const float*)d_in[13];
    const float* ln2b   = (const float*)d_in[14];
    float* out = (float*)d_out;

    char* wsb = (char*)d_ws;
    const size_t MB = 1024 * 1024;
    h16* Xh    = (h16*)(wsb);              // 8 MB   [8192,512]
    h16* P0    = (h16*)(wsb + 8 * MB);     // 8 MB   split-K partial 0
    h16* P1    = (h16*)(wsb + 16 * MB);    // 8 MB   split-K partial 1 (= P0 + 8192*512)
    h16* ATTh  = (h16*)(wsb + 24 * MB);    // 8 MB   [8192,512]
    h16* FFh   = (h16*)(wsb + 32 * MB);    // 32 MB  [8192,2048] (also QKV [8192,1536])
    h16* TOKh  = (h16*)(wsb + 32 * MB);    // alias FF: 15.5 MB [15872,512] (post-transformer)
    h16* DOTSh = (h16*)(wsb + 48 * MB);    // alias FF tail: 7.75 MB [256,15872]
    h16* Wh    = (h16*)(wsb + 64 * MB);    // 25 MB  all weights fp16
    h16* QHATh = (h16*)(wsb + 90 * MB);    // 0.25 MB [256,512]

    h16* Whqkv = Wh;                       // 4*1536*512
    h16* Who   = Whqkv + 3145728;          // 4*512*512
    h16* Wh1   = Who + 1048576;            // 4*2048*512
    h16* Wh2   = Wh1 + 4194304;            // 4*2048*512

    k_cvt<<<1536, 256, 0, stream>>>(Wqkv, Whqkv, 393216);
    k_cvt<<<512,  256, 0, stream>>>(Wo,   Who,   131072);
    k_cvt<<<2048, 256, 0, stream>>>(W1,   Wh1,   524288);
    k_cvt<<<2048, 256, 0, stream>>>(W2,   Wh2,   524288);
    k_concat_h<<<8192, 256, 0, stream>>>(frames, expt, Xh);

    for (int l = 0; l < 4; ++l) {
        const h16* Wqkv_l = Whqkv + (size_t)l * 786432;
        const h16* Wo_l   = Who   + (size_t)l * 262144;
        const h16* W1_l   = Wh1   + (size_t)l * 1048576;
        const h16* W2_l   = Wh2   + (size_t)l * 1048576;

        k_g8<0><<<dim3(6, 32, 1), 512, 0, stream>>>(
            Xh, 512, Wqkv_l, 512, bqkv + (size_t)l * 1536, FFh, 1536, 8192, 1536, 512);
        k_attn_h<<<2048, 256, 0, stream>>>(FFh, ATTh);
        k_hgemm<3><<<dim3(4, 64, 2), 512, 0, stream>>>(
            ATTh, 512, Wo_l, 512, nullptr, P0, 512, 8192, 512, 256);
        k_addln_red<<<8192, 256, 0, stream>>>(Xh, P0, P1, bo + (size_t)l * 512,
                                              ln1w + (size_t)l * 512, ln1b + (size_t)l * 512);
        k_g8<1><<<dim3(8, 32, 1), 512, 0, stream>>>(
            Xh, 512, W1_l, 512, b1 + (size_t)l * 2048, FFh, 2048, 8192, 2048, 512);
        k_hgemm<3><<<dim3(4, 64, 2), 512, 0, stream>>>(
            FFh, 2048, W2_l, 2048, nullptr, P0, 512, 8192, 512, 1024);
        k_addln_red<<<8192, 256, 0, stream>>>(Xh, P0, P1, b2 + (size_t)l * 512,
                                              ln2w + (size_t)l * 512, ln2b + (size_t)l * 512);
    }

    k_l2rows_h<<<256, 256, 0, stream>>>(text, QHATh);
    k_build_tok_h<<<256 * NTOK_V, 256, 0, stream>>>(frames, Xh, TOKh);
    k_hgemm<2><<<dim3(124, 2, 1), 512, 0, stream>>>(
        QHATh, 512, TOKh, 512, nullptr, DOTSh, 15872, 256, 15872, 512);
    k_sim_h<<<256, 256, 0, stream>>>(DOTSh, out);
}

// Round 9
// 644.021 us; speedup vs baseline: 1.5754x; 1.0484x over previous
//
#include <hip/hip_runtime.h>
#include <math.h>

#define DM 512
#define NTOK_V 62

typedef _Float16 h16;
typedef __attribute__((ext_vector_type(8))) _Float16 h16x8;
typedef __attribute__((ext_vector_type(4))) float f32x4;

__device__ __forceinline__ void ldsload16(const void* g, void* l) {
    __builtin_amdgcn_global_load_lds(
        (const __attribute__((address_space(1))) unsigned int*)g,
        (__attribute__((address_space(3))) unsigned int*)l, 16, 0, 0);
}

// ---------------------------------------------------------------- fp32 -> fp16 convert
__global__ __launch_bounds__(256) void k_cvt(const float* __restrict__ in,
                                             h16* __restrict__ outp, int n8) {
    int i = blockIdx.x * 256 + threadIdx.x;
    if (i >= n8) return;
    float4 a = ((const float4*)in)[i * 2];
    float4 b = ((const float4*)in)[i * 2 + 1];
    h16x8 h;
    h[0] = (h16)a.x; h[1] = (h16)a.y; h[2] = (h16)a.z; h[3] = (h16)a.w;
    h[4] = (h16)b.x; h[5] = (h16)b.y; h[6] = (h16)b.z; h[7] = (h16)b.w;
    ((h16x8*)outp)[i] = h;
}

// ---------------------------------------------------------------- concat -> fp16 X
__global__ __launch_bounds__(256) void k_concat_h(const float* __restrict__ frames,
                                                  const float* __restrict__ expt,
                                                  h16* __restrict__ X) {
    int row = blockIdx.x;
    int b = row >> 5, s = row & 31;
    int t = threadIdx.x;
    const float* src = (s < 30) ? (frames + ((size_t)(b * 30 + s)) * DM)
                                : (expt + (size_t)(s - 30) * DM);
    X[(size_t)row * DM + t]       = (h16)src[t];
    X[(size_t)row * DM + t + 256] = (h16)src[t + 256];
}

// ---------------------------------------------------------------- 8-phase 256x256 MFMA GEMM
// C = A @ B^T. 512 thr = 8 waves (2M x 4N), wave = 128x64 out (acc 8x4).
// BK=64 K-tiles, 2x64KB LDS double-buffer, 4 phases/tile, vmcnt(2) only at
// tile boundary. Fragment-native LDS layout (conflict-free, no swizzle).
// Epilogue R9: m-outer / row / n-inner store order so each 128B line of C
// (one row x 64-col wave block) is written in 4 back-to-back 32B stores ->
// L2 assembles full lines, no partial-line eviction (R8: 2.47x write amp).
// MODE: 0 = +bias, 1 = +bias+relu
template<int MODE>
__global__ __launch_bounds__(512, 2) void k_g8(
        const h16* __restrict__ A, int lda,
        const h16* __restrict__ B, int ldb,
        const float* __restrict__ bias,
        h16* __restrict__ C, int ldc,
        int M, int N, int Keff) {
    __shared__ char smem[131072];              // 2 bufs x (A 2x16KB + B 2x16KB)
    const int t = threadIdx.x;
    const int w = t >> 6, lane = t & 63;
    const int wr = w >> 2, wc = w & 3;         // wave grid 2 x 4
    const int kc = lane >> 4, rr = lane & 15;
    const size_t row0 = (size_t)blockIdx.y * 256;
    const size_t col0 = (size_t)blockIdx.x * 256;

    const h16* gA = A + (row0 + (w << 4) + rr) * (size_t)lda + (kc << 3);
    const h16* gB = B + (col0 + (w << 4) + rr) * (size_t)ldb + (kc << 3);

    f32x4 acc[8][4];
#pragma unroll
    for (int m = 0; m < 8; ++m)
#pragma unroll
        for (int n = 0; n < 4; ++n) acc[m][n] = (f32x4){0.f, 0.f, 0.f, 0.f};

    const int nt = Keff >> 6;                  // K-tiles (8 for K=512)

#define SB0 __builtin_amdgcn_sched_barrier(0);
#define STG_A(bs, h, jt) { char* d_ = smem + (bs)*65536 + (h)*16384 + (w << 10) + (lane << 4); \
        const h16* s_ = gA + (size_t)((h)*128) * lda + (size_t)(jt)*64; \
        ldsload16(s_, d_); ldsload16(s_ + 32, d_ + 8192); }
#define STG_B(bs, h, jt) { char* d_ = smem + (bs)*65536 + 32768 + (h)*16384 + (w << 10) + (lane << 4); \
        const h16* s_ = gB + (size_t)((h)*128) * ldb + (size_t)(jt)*64; \
        ldsload16(s_, d_); ldsload16(s_ + 32, d_ + 8192); }
#define MFMA16(mp, AF) { \
        __builtin_amdgcn_s_setprio(1); \
        _Pragma("unroll") for (int i = 0; i < 2; ++i) \
        _Pragma("unroll") for (int n = 0; n < 4; ++n) \
        _Pragma("unroll") for (int kk = 0; kk < 2; ++kk) \
            acc[(mp)*2 + i][n] = __builtin_amdgcn_mfma_f32_16x16x32_f16(AF[i][kk], bf[n][kk], acc[(mp)*2 + i][n], 0, 0, 0); \
        __builtin_amdgcn_s_setprio(0); SB0 }

    STG_A(0, 0, 0) STG_A(0, 1, 0) STG_B(0, 0, 0) STG_B(0, 1, 0)

    int cur = 0;
    for (int j = 0; j < nt; ++j) {
        const int nxt = cur ^ 1;
        // ---- phase 0 (tile boundary)
        if (j + 1 < nt) {
            STG_A(nxt, 0, j + 1)
            asm volatile("s_waitcnt vmcnt(2)" ::: "memory");
        } else {
            asm volatile("s_waitcnt vmcnt(0)" ::: "memory");
        }
        SB0
        __builtin_amdgcn_s_barrier();
        SB0
        const char* Ab = smem + cur * 65536 + wr * 16384;
        const char* Bb = smem + cur * 65536 + 32768 + (wc >> 1) * 16384;
        h16x8 bf[4][2];
#pragma unroll
        for (int n = 0; n < 4; ++n)
#pragma unroll
            for (int kk = 0; kk < 2; ++kk)
                bf[n][kk] = *(const h16x8*)(Bb + kk * 8192 + (((wc & 1) << 2) + n) * 1024 + (lane << 4));
        h16x8 a0[2][2];
#pragma unroll
        for (int i = 0; i < 2; ++i)
#pragma unroll
            for (int kk = 0; kk < 2; ++kk)
                a0[i][kk] = *(const h16x8*)(Ab + kk * 8192 + (0 + i) * 1024 + (lane << 4));
        asm volatile("s_waitcnt lgkmcnt(0)" ::: "memory");
        SB0
        MFMA16(0, a0)
        // ---- phase 1
        h16x8 a1[2][2];
#pragma unroll
        for (int i = 0; i < 2; ++i)
#pragma unroll
            for (int kk = 0; kk < 2; ++kk)
                a1[i][kk] = *(const h16x8*)(Ab + kk * 8192 + (2 + i) * 1024 + (lane << 4));
        if (j + 1 < nt) STG_A(nxt, 1, j + 1)
        asm volatile("s_waitcnt lgkmcnt(0)" ::: "memory");
        SB0
        __builtin_amdgcn_s_barrier();
        SB0
        MFMA16(1, a1)
        // ---- phase 2
        h16x8 a2[2][2];
#pragma unroll
        for (int i = 0; i < 2; ++i)
#pragma unroll
            for (int kk = 0; kk < 2; ++kk)
                a2[i][kk] = *(const h16x8*)(Ab + kk * 8192 + (4 + i) * 1024 + (lane << 4));
        if (j + 1 < nt) STG_B(nxt, 0, j + 1)
        asm volatile("s_waitcnt lgkmcnt(0)" ::: "memory");
        SB0
        __builtin_amdgcn_s_barrier();
        SB0
        MFMA16(2, a2)
        // ---- phase 3
        h16x8 a3[2][2];
#pragma unroll
        for (int i = 0; i < 2; ++i)
#pragma unroll
            for (int kk = 0; kk < 2; ++kk)
                a3[i][kk] = *(const h16x8*)(Ab + kk * 8192 + (6 + i) * 1024 + (lane << 4));
        if (j + 1 < nt) STG_B(nxt, 1, j + 1)
        asm volatile("s_waitcnt lgkmcnt(0)" ::: "memory");
        SB0
        __builtin_amdgcn_s_barrier();
        SB0
        MFMA16(3, a3)
        cur = nxt;
    }
#undef MFMA16
#undef STG_A
#undef STG_B
#undef SB0

    // epilogue (R9): line-coherent store order — for each row, the 4 n-segments
    // (16 lanes x 32B each, together one 128B line per 16-lane group) issue
    // back-to-back; bias preloaded per-n.
    float bv[4];
#pragma unroll
    for (int n = 0; n < 4; ++n)
        bv[n] = bias ? bias[col0 + (wc << 6) + n * 16 + rr] : 0.f;
#pragma unroll
    for (int m = 0; m < 8; ++m) {
        size_t rbase = row0 + (wr << 7) + m * 16 + (kc << 2);
#pragma unroll
        for (int jj = 0; jj < 4; ++jj) {
            h16* rowp = C + (rbase + jj) * (size_t)ldc + col0 + (wc << 6) + rr;
#pragma unroll
            for (int n = 0; n < 4; ++n) {
                float v = acc[m][n][jj] + bv[n];
                if (MODE == 1) v = fmaxf(v, 0.f);
                rowp[n * 16] = (h16)v;
            }
        }
    }
}

// ---------------------------------------------------------------- 128x128 2-phase GEMM (R7, proven)
// MODE: 0 = +bias, 1 = +bias+relu, 2 = plain, 3 = split-K partial (out at z*M*N)
template<int MODE>
__global__ __launch_bounds__(512, 4) void k_hgemm(
        const h16* __restrict__ A, int lda,
        const h16* __restrict__ B, int ldb,
        const float* __restrict__ bias,
        h16* __restrict__ C, int ldc,
        int M, int N, int Keff) {
    __shared__ char smem[49152];               // 3 slots x (A 8KB + B 8KB)
    const int t = threadIdx.x;
    const int w = t >> 6, lane = t & 63;
    const int wr = w >> 2, wc = w & 3;         // wave grid 2 x 4
    const int kc = lane >> 4, rr = lane & 15;
    const size_t row0 = (size_t)blockIdx.y * 128;
    const size_t col0 = (size_t)blockIdx.x * 128;
    const int z = blockIdx.z;

    const h16* gA = A + (size_t)z * Keff + (row0 + (w << 4) + rr) * (size_t)lda + (kc << 3);
    const h16* gB = B + (size_t)z * Keff + (col0 + (w << 4) + rr) * (size_t)ldb + (kc << 3);
    h16* Cz = C + (MODE == 3 ? (size_t)z * (size_t)M * N : (size_t)0);

    f32x4 acc[4][2];
#pragma unroll
    for (int m = 0; m < 4; ++m)
#pragma unroll
        for (int n = 0; n < 2; ++n) acc[m][n] = (f32x4){0.f, 0.f, 0.f, 0.f};

    const int nt = Keff >> 5;

#define SB0 __builtin_amdgcn_sched_barrier(0);
#define STAGE(step, slot) { char* sA_ = smem + ((slot) << 14) + (w << 10); \
        ldsload16(gA + (size_t)(step) * 32, sA_); \
        ldsload16(gB + (size_t)(step) * 32, sA_ + 8192); }
#define KSTEP(WAITLIT, slotR, DOSTAGE, stepW, slotW) { \
        asm volatile("s_waitcnt vmcnt(" WAITLIT ")" ::: "memory"); \
        SB0 \
        __builtin_amdgcn_s_barrier(); \
        SB0 \
        const char* bA = smem + ((slotR) << 14); \
        const char* bB = bA + 8192; \
        h16x8 af[4], bf[2]; \
        _Pragma("unroll") for (int m = 0; m < 4; ++m) \
            af[m] = *(const h16x8*)(bA + ((wr << 2) + m) * 1024 + lane * 16); \
        _Pragma("unroll") for (int n = 0; n < 2; ++n) \
            bf[n] = *(const h16x8*)(bB + ((wc << 1) + n) * 1024 + lane * 16); \
        asm volatile("s_waitcnt lgkmcnt(0)" ::: "memory"); \
        SB0 \
        if (DOSTAGE) STAGE(stepW, slotW) \
        __builtin_amdgcn_s_setprio(1); \
        _Pragma("unroll") for (int m = 0; m < 4; ++m) \
        _Pragma("unroll") for (int n = 0; n < 2; ++n) \
            acc[m][n] = __builtin_amdgcn_mfma_f32_16x16x32_f16(af[m], bf[n], acc[m][n], 0, 0, 0); \
        __builtin_amdgcn_s_setprio(0); \
        SB0 }

    STAGE(0, 0) STAGE(1, 1)
    int slotR = 0, slotW = 2;
    int it = 0;
    for (; it < nt - 2; ++it) {
        KSTEP("2", slotR, 1, it + 2, slotW)
        slotR = (slotR == 2) ? 0 : slotR + 1;
        slotW = (slotW == 2) ? 0 : slotW + 1;
    }
    KSTEP("2", slotR, 0, 0, 0)
    slotR = (slotR == 2) ? 0 : slotR + 1;
    KSTEP("0", slotR, 0, 0, 0)
#undef KSTEP
#undef STAGE
#undef SB0

#pragma unroll
    for (int n = 0; n < 2; ++n) {
        size_t col = col0 + (wc << 5) + n * 16 + rr;
        float bv = (MODE == 0 || MODE == 1) ? bias[col] : 0.f;
#pragma unroll
        for (int m = 0; m < 4; ++m) {
            size_t rbase = row0 + (wr << 6) + m * 16 + (kc << 2);
#pragma unroll
            for (int j = 0; j < 4; ++j) {
                float v = acc[m][n][j] + bv;
                if (MODE == 1) v = fmaxf(v, 0.f);
                Cz[(rbase + j) * (size_t)ldc + col] = (h16)v;
            }
        }
    }
}

// ---------------------------------------------------------------- attention, one block per (b,h)
__global__ __launch_bounds__(256) void k_attn_h(const h16* __restrict__ qkv,
                                                h16* __restrict__ att) {
    __shared__ float q[32][65], k[32][65], v[32][65];
    __shared__ float sc[32][33];
    int b = blockIdx.x >> 3, h = blockIdx.x & 7;
    int t = threadIdx.x;
    const h16* base = qkv + (size_t)b * 32 * 1536 + h * 64;
    for (int i = t; i < 2048; i += 256) {
        int s = i >> 6, d = i & 63;
        size_t ro = (size_t)s * 1536 + d;
        q[s][d] = (float)base[ro];
        k[s][d] = (float)base[ro + 512];
        v[s][d] = (float)base[ro + 1024];
    }
    __syncthreads();
    {
        int r = t >> 3, c0 = (t & 7) << 2;
        float s0 = 0.f, s1 = 0.f, s2 = 0.f, s3 = 0.f;
#pragma unroll 8
        for (int d = 0; d < 64; ++d) {
            float qv = q[r][d];
            s0 += qv * k[c0 + 0][d];
            s1 += qv * k[c0 + 1][d];
            s2 += qv * k[c0 + 2][d];
            s3 += qv * k[c0 + 3][d];
        }
        sc[r][c0 + 0] = s0 * 0.125f;
        sc[r][c0 + 1] = s1 * 0.125f;
        sc[r][c0 + 2] = s2 * 0.125f;
        sc[r][c0 + 3] = s3 * 0.125f;
    }
    __syncthreads();
    {   // wave-parallel softmax: 8 lanes per row
        int r = t >> 3, c0 = (t & 7) << 2;
        float a0 = sc[r][c0], a1 = sc[r][c0 + 1], a2 = sc[r][c0 + 2], a3 = sc[r][c0 + 3];
        float mx = fmaxf(fmaxf(a0, a1), fmaxf(a2, a3));
        mx = fmaxf(mx, __shfl_xor(mx, 1));
        mx = fmaxf(mx, __shfl_xor(mx, 2));
        mx = fmaxf(mx, __shfl_xor(mx, 4));
        float e0 = expf(a0 - mx), e1 = expf(a1 - mx), e2 = expf(a2 - mx), e3 = expf(a3 - mx);
        float sm = e0 + e1 + e2 + e3;
        sm += __shfl_xor(sm, 1);
        sm += __shfl_xor(sm, 2);
        sm += __shfl_xor(sm, 4);
        float inv = 1.f / sm;
        sc[r][c0] = e0 * inv; sc[r][c0 + 1] = e1 * inv; sc[r][c0 + 2] = e2 * inv; sc[r][c0 + 3] = e3 * inv;
    }
    __syncthreads();
    for (int i = t; i < 2048; i += 256) {
        int s = i >> 6, d = i & 63;
        float acc = 0.f;
#pragma unroll 8
        for (int c = 0; c < 32; ++c) acc += sc[s][c] * v[c][d];
        att[((size_t)b * 32 + s) * DM + h * 64 + d] = (h16)acc;
    }
}

// ---------------------------------------------------------------- x = LN(x + p0 + p1 + bias)*w + b
__global__ __launch_bounds__(256) void k_addln_red(h16* __restrict__ x,
                                                   const h16* __restrict__ p0,
                                                   const h16* __restrict__ p1,
                                                   const float* __restrict__ bias,
                                                   const float* __restrict__ w,
                                                   const float* __restrict__ b) {
    size_t row = blockIdx.x;
    int t = threadIdx.x;
    size_t o0 = row * DM + t, o1 = o0 + 256;
    float v0 = (float)x[o0] + (float)p0[o0] + (float)p1[o0] + bias[t];
    float v1 = (float)x[o1] + (float)p0[o1] + (float)p1[o1] + bias[t + 256];
    float s = v0 + v1;
#pragma unroll
    for (int o = 32; o; o >>= 1) s += __shfl_xor(s, o);
    __shared__ float ss[4], qs[4];
    if ((t & 63) == 0) ss[t >> 6] = s;
    __syncthreads();
    float mean = (ss[0] + ss[1] + ss[2] + ss[3]) * (1.f / 512.f);
    float d0 = v0 - mean, d1 = v1 - mean;
    float qv = d0 * d0 + d1 * d1;
#pragma unroll
    for (int o = 32; o; o >>= 1) qv += __shfl_xor(qv, o);
    if ((t & 63) == 0) qs[t >> 6] = qv;
    __syncthreads();
    float var = (qs[0] + qs[1] + qs[2] + qs[3]) * (1.f / 512.f);
    float inv = 1.f / sqrtf(var + 1e-5f);
    x[o0] = (h16)(d0 * inv * w[t] + b[t]);
    x[o1] = (h16)(d1 * inv * w[t + 256] + b[t + 256]);
}

// ---------------------------------------------------------------- l2 rows: f32 in -> f16 out
__global__ __launch_bounds__(256) void k_l2rows_h(const float* __restrict__ in,
                                                  h16* __restrict__ outp) {
    size_t row = blockIdx.x;
    int t = threadIdx.x;
    float v0 = in[row * DM + t], v1 = in[row * DM + t + 256];
    float q = v0 * v0 + v1 * v1;
#pragma unroll
    for (int o = 32; o; o >>= 1) q += __shfl_xor(q, o);
    __shared__ float qs[4];
    if ((t & 63) == 0) qs[t >> 6] = q;
    __syncthreads();
    float n = sqrtf(qs[0] + qs[1] + qs[2] + qs[3]);
    float sc = 1.f / fmaxf(n, 1e-12f);
    outp[row * DM + t]       = (h16)(v0 * sc);
    outp[row * DM + t + 256] = (h16)(v1 * sc);
}

// ---------------------------------------------------------------- TOK rows (l2'd frames + video tokens)
__global__ __launch_bounds__(256) void k_build_tok_h(const float* __restrict__ frames,
                                                     const h16* __restrict__ X,
                                                     h16* __restrict__ TOK) {
    int rid = blockIdx.x;
    int j = rid / NTOK_V, tt = rid % NTOK_V;
    int t = threadIdx.x;
    float v0, v1;
    if (tt < 30) {
        const float* src = frames + ((size_t)j * 30 + tt) * DM;
        v0 = src[t]; v1 = src[t + 256];
    } else {
        const h16* src = X + ((size_t)j * 32 + (tt - 30)) * DM;
        v0 = (float)src[t]; v1 = (float)src[t + 256];
    }
    float q = v0 * v0 + v1 * v1;
#pragma unroll
    for (int o = 32; o; o >>= 1) q += __shfl_xor(q, o);
    __shared__ float qs[4];
    if ((t & 63) == 0) qs[t >> 6] = q;
    __syncthreads();
    float n = sqrtf(qs[0] + qs[1] + qs[2] + qs[3]);
    float sc = 1.f / fmaxf(n, 1e-12f);
    TOK[(size_t)rid * DM + t]       = (h16)(v0 * sc);
    TOK[(size_t)rid * DM + t + 256] = (h16)(v1 * sc);
}

// ---------------------------------------------------------------- max-reduce dots -> sims
__global__ __launch_bounds__(256) void k_sim_h(const h16* __restrict__ dots,
                                               float* __restrict__ out) {
    int i = blockIdx.x;
    int j = threadIdx.x;
    const h16* p = dots + (size_t)i * 15872 + (size_t)j * NTOK_V;
    float mf = -1e30f, mv = -1e30f;
#pragma unroll
    for (int tt = 0; tt < 30; ++tt) mf = fmaxf(mf, (float)p[tt]);
#pragma unroll
    for (int tt = 30; tt < 62; ++tt) mv = fmaxf(mv, (float)p[tt]);
    int o = i * 256 + j;
    out[o]          = mf + mv;
    out[65536 + o]  = mf;
    out[131072 + o] = mv;
}

// ---------------------------------------------------------------- launcher
extern "C" void kernel_launch(void* const* d_in, const int* in_sizes, int n_in,
                              void* d_out, int out_size, void* d_ws, size_t ws_size,
                              hipStream_t stream) {
    const float* text   = (const float*)d_in[0];
    const float* frames = (const float*)d_in[1];
    const float* expt   = (const float*)d_in[2];
    const float* Wqkv   = (const float*)d_in[3];
    const float* bqkv   = (const float*)d_in[4];
    const float* Wo     = (const float*)d_in[5];
    const float* bo     = (const float*)d_in[6];
    const float* ln1w   = (const float*)d_in[7];
    const float* ln1b   = (const float*)d_in[8];
    const float* W1     = (const float*)d_in[9];
    const float* b1     = (const float*)d_in[10];
    const float* W2     = (const float*)d_in[11];
    const float* b2     = (const float*)d_in[12];
    const float* ln2w   = (const float*)d_in[13];
    const float* ln2b   = (const float*)d_in[14];
    float* out = (float*)d_out;

    char* wsb = (char*)d_ws;
    const size_t MB = 1024 * 1024;
    h16* Xh    = (h16*)(wsb);              // 8 MB   [8192,512]
    h16* P0    = (h16*)(wsb + 8 * MB);     // 8 MB   split-K partial 0
    h16* P1    = (h16*)(wsb + 16 * MB);    // 8 MB   split-K partial 1 (= P0 + 8192*512)
    h16* ATTh  = (h16*)(wsb + 24 * MB);    // 8 MB   [8192,512]
    h16* FFh   = (h16*)(wsb + 32 * MB);    // 32 MB  [8192,2048] (also QKV [8192,1536])
    h16* TOKh  = (h16*)(wsb + 32 * MB);    // alias FF: 15.5 MB [15872,512] (post-transformer)
    h16* DOTSh = (h16*)(wsb + 48 * MB);    // alias FF tail: 7.75 MB [256,15872]
    h16* Wh    = (h16*)(wsb + 64 * MB);    // 25 MB  all weights fp16
    h16* QHATh = (h16*)(wsb + 90 * MB);    // 0.25 MB [256,512]

    h16* Whqkv = Wh;                       // 4*1536*512
    h16* Who   = Whqkv + 3145728;          // 4*512*512
    h16* Wh1   = Who + 1048576;            // 4*2048*512
    h16* Wh2   = Wh1 + 4194304;            // 4*2048*512

    k_cvt<<<1536, 256, 0, stream>>>(Wqkv, Whqkv, 393216);
    k_cvt<<<512,  256, 0, stream>>>(Wo,   Who,   131072);
    k_cvt<<<2048, 256, 0, stream>>>(W1,   Wh1,   524288);
    k_cvt<<<2048, 256, 0, stream>>>(W2,   Wh2,   524288);
    k_concat_h<<<8192, 256, 0, stream>>>(frames, expt, Xh);

    for (int l = 0; l < 4; ++l) {
        const h16* Wqkv_l = Whqkv + (size_t)l * 786432;
        const h16* Wo_l   = Who   + (size_t)l * 262144;
        const h16* W1_l   = Wh1   + (size_t)l * 1048576;
        const h16* W2_l   = Wh2   + (size_t)l * 1048576;

        k_g8<0><<<dim3(6, 32, 1), 512, 0, stream>>>(
            Xh, 512, Wqkv_l, 512, bqkv + (size_t)l * 1536, FFh, 1536, 8192, 1536, 512);
        k_attn_h<<<2048, 256, 0, stream>>>(FFh, ATTh);
        k_hgemm<3><<<dim3(4, 64, 2), 512, 0, stream>>>(
            ATTh, 512, Wo_l, 512, nullptr, P0, 512, 8192, 512, 256);
        k_addln_red<<<8192, 256, 0, stream>>>(Xh, P0, P1, bo + (size_t)l * 512,
                                              ln1w + (size_t)l * 512, ln1b + (size_t)l * 512);
        k_g8<1><<<dim3(8, 32, 1), 512, 0, stream>>>(
            Xh, 512, W1_l, 512, b1 + (size_t)l * 2048, FFh, 2048, 8192, 2048, 512);
        k_hgemm<3><<<dim3(4, 64, 2), 512, 0, stream>>>(
            FFh, 2048, W2_l, 2048, nullptr, P0, 512, 8192, 512, 1024);
        k_addln_red<<<8192, 256, 0, stream>>>(Xh, P0, P1, b2 + (size_t)l * 512,
                                              ln2w + (size_t)l * 512, ln2b + (size_t)l * 512);
    }

    k_l2rows_h<<<256, 256, 0, stream>>>(text, QHATh);
    k_build_tok_h<<<256 * NTOK_V, 256, 0, stream>>>(frames, Xh, TOKh);
    k_hgemm<2><<<dim3(124, 2, 1), 512, 0, stream>>>(
        QHATh, 512, TOKh, 512, nullptr, DOTSh, 15872, 256, 15872, 512);
    k_sim_h<<<256, 256, 0, stream>>>(DOTSh, out);
}

// Round 10
// 631.730 us; speedup vs baseline: 1.6060x; 1.0195x over previous
//
#include <hip/hip_runtime.h>
#include <math.h>

#define DM 512
#define NTOK_V 62

typedef _Float16 h16;
typedef __attribute__((ext_vector_type(8))) _Float16 h16x8;
typedef __attribute__((ext_vector_type(4))) float f32x4;

__device__ __forceinline__ void ldsload16(const void* g, void* l) {
    __builtin_amdgcn_global_load_lds(
        (const __attribute__((address_space(1))) unsigned int*)g,
        (__attribute__((address_space(3))) unsigned int*)l, 16, 0, 0);
}

// XCD-chunked bijective blockIdx swizzle (T1, m157 form; requires nwg%8==0).
// HW dispatches consecutive linear ids round-robin across 8 XCDs; this remap
// gives each XCD a CONTIGUOUS chunk of logical tiles -> shared A-panels/weights
// stay in that XCD's L2 instead of being re-fetched by all 8.
__device__ __forceinline__ void xcd_swz(int& bx, int& by) {
    const int gx = gridDim.x, gy = gridDim.y;
    const int lin = blockIdx.x + gx * blockIdx.y;
    const int cpx = (gx * gy) >> 3;
    const int wg = (lin & 7) * cpx + (lin >> 3);
    bx = wg % gx;
    by = wg / gx;
}

// ---------------------------------------------------------------- fp32 -> fp16 convert
__global__ __launch_bounds__(256) void k_cvt(const float* __restrict__ in,
                                             h16* __restrict__ outp, int n8) {
    int i = blockIdx.x * 256 + threadIdx.x;
    if (i >= n8) return;
    float4 a = ((const float4*)in)[i * 2];
    float4 b = ((const float4*)in)[i * 2 + 1];
    h16x8 h;
    h[0] = (h16)a.x; h[1] = (h16)a.y; h[2] = (h16)a.z; h[3] = (h16)a.w;
    h[4] = (h16)b.x; h[5] = (h16)b.y; h[6] = (h16)b.z; h[7] = (h16)b.w;
    ((h16x8*)outp)[i] = h;
}

// ---------------------------------------------------------------- concat -> fp16 X
__global__ __launch_bounds__(256) void k_concat_h(const float* __restrict__ frames,
                                                  const float* __restrict__ expt,
                                                  h16* __restrict__ X) {
    int row = blockIdx.x;
    int b = row >> 5, s = row & 31;
    int t = threadIdx.x;
    const float* src = (s < 30) ? (frames + ((size_t)(b * 30 + s)) * DM)
                                : (expt + (size_t)(s - 30) * DM);
    X[(size_t)row * DM + t]       = (h16)src[t];
    X[(size_t)row * DM + t + 256] = (h16)src[t + 256];
}

// ---------------------------------------------------------------- 8-phase 256x256 MFMA GEMM
// C = A @ B^T. 512 thr = 8 waves (2M x 4N), wave = 128x64 out (acc 8x4).
// BK=64 K-tiles, 2x64KB LDS double-buffer, 4 phases/tile, vmcnt(2) only at
// tile boundary. Fragment-native LDS layout (conflict-free, no swizzle).
// Line-coherent epilogue (R9). XCD-chunked block swizzle (R10).
// MODE: 0 = +bias, 1 = +bias+relu
template<int MODE>
__global__ __launch_bounds__(512, 2) void k_g8(
        const h16* __restrict__ A, int lda,
        const h16* __restrict__ B, int ldb,
        const float* __restrict__ bias,
        h16* __restrict__ C, int ldc,
        int M, int N, int Keff) {
    __shared__ char smem[131072];              // 2 bufs x (A 2x16KB + B 2x16KB)
    const int t = threadIdx.x;
    const int w = t >> 6, lane = t & 63;
    const int wr = w >> 2, wc = w & 3;         // wave grid 2 x 4
    const int kc = lane >> 4, rr = lane & 15;
    int bx, by;
    xcd_swz(bx, by);
    const size_t row0 = (size_t)by * 256;
    const size_t col0 = (size_t)bx * 256;

    const h16* gA = A + (row0 + (w << 4) + rr) * (size_t)lda + (kc << 3);
    const h16* gB = B + (col0 + (w << 4) + rr) * (size_t)ldb + (kc << 3);

    f32x4 acc[8][4];
#pragma unroll
    for (int m = 0; m < 8; ++m)
#pragma unroll
        for (int n = 0; n < 4; ++n) acc[m][n] = (f32x4){0.f, 0.f, 0.f, 0.f};

    const int nt = Keff >> 6;                  // K-tiles (8 for K=512)

#define SB0 __builtin_amdgcn_sched_barrier(0);
#define STG_A(bs, h, jt) { char* d_ = smem + (bs)*65536 + (h)*16384 + (w << 10) + (lane << 4); \
        const h16* s_ = gA + (size_t)((h)*128) * lda + (size_t)(jt)*64; \
        ldsload16(s_, d_); ldsload16(s_ + 32, d_ + 8192); }
#define STG_B(bs, h, jt) { char* d_ = smem + (bs)*65536 + 32768 + (h)*16384 + (w << 10) + (lane << 4); \
        const h16* s_ = gB + (size_t)((h)*128) * ldb + (size_t)(jt)*64; \
        ldsload16(s_, d_); ldsload16(s_ + 32, d_ + 8192); }
#define MFMA16(mp, AF) { \
        __builtin_amdgcn_s_setprio(1); \
        _Pragma("unroll") for (int i = 0; i < 2; ++i) \
        _Pragma("unroll") for (int n = 0; n < 4; ++n) \
        _Pragma("unroll") for (int kk = 0; kk < 2; ++kk) \
            acc[(mp)*2 + i][n] = __builtin_amdgcn_mfma_f32_16x16x32_f16(AF[i][kk], bf[n][kk], acc[(mp)*2 + i][n], 0, 0, 0); \
        __builtin_amdgcn_s_setprio(0); SB0 }

    STG_A(0, 0, 0) STG_A(0, 1, 0) STG_B(0, 0, 0) STG_B(0, 1, 0)

    int cur = 0;
    for (int j = 0; j < nt; ++j) {
        const int nxt = cur ^ 1;
        // ---- phase 0 (tile boundary)
        if (j + 1 < nt) {
            STG_A(nxt, 0, j + 1)
            asm volatile("s_waitcnt vmcnt(2)" ::: "memory");
        } else {
            asm volatile("s_waitcnt vmcnt(0)" ::: "memory");
        }
        SB0
        __builtin_amdgcn_s_barrier();
        SB0
        const char* Ab = smem + cur * 65536 + wr * 16384;
        const char* Bb = smem + cur * 65536 + 32768 + (wc >> 1) * 16384;
        h16x8 bf[4][2];
#pragma unroll
        for (int n = 0; n < 4; ++n)
#pragma unroll
            for (int kk = 0; kk < 2; ++kk)
                bf[n][kk] = *(const h16x8*)(Bb + kk * 8192 + (((wc & 1) << 2) + n) * 1024 + (lane << 4));
        h16x8 a0[2][2];
#pragma unroll
        for (int i = 0; i < 2; ++i)
#pragma unroll
            for (int kk = 0; kk < 2; ++kk)
                a0[i][kk] = *(const h16x8*)(Ab + kk * 8192 + (0 + i) * 1024 + (lane << 4));
        asm volatile("s_waitcnt lgkmcnt(0)" ::: "memory");
        SB0
        MFMA16(0, a0)
        // ---- phase 1
        h16x8 a1[2][2];
#pragma unroll
        for (int i = 0; i < 2; ++i)
#pragma unroll
            for (int kk = 0; kk < 2; ++kk)
                a1[i][kk] = *(const h16x8*)(Ab + kk * 8192 + (2 + i) * 1024 + (lane << 4));
        if (j + 1 < nt) STG_A(nxt, 1, j + 1)
        asm volatile("s_waitcnt lgkmcnt(0)" ::: "memory");
        SB0
        __builtin_amdgcn_s_barrier();
        SB0
        MFMA16(1, a1)
        // ---- phase 2
        h16x8 a2[2][2];
#pragma unroll
        for (int i = 0; i < 2; ++i)
#pragma unroll
            for (int kk = 0; kk < 2; ++kk)
                a2[i][kk] = *(const h16x8*)(Ab + kk * 8192 + (4 + i) * 1024 + (lane << 4));
        if (j + 1 < nt) STG_B(nxt, 0, j + 1)
        asm volatile("s_waitcnt lgkmcnt(0)" ::: "memory");
        SB0
        __builtin_amdgcn_s_barrier();
        SB0
        MFMA16(2, a2)
        // ---- phase 3
        h16x8 a3[2][2];
#pragma unroll
        for (int i = 0; i < 2; ++i)
#pragma unroll
            for (int kk = 0; kk < 2; ++kk)
                a3[i][kk] = *(const h16x8*)(Ab + kk * 8192 + (6 + i) * 1024 + (lane << 4));
        if (j + 1 < nt) STG_B(nxt, 1, j + 1)
        asm volatile("s_waitcnt lgkmcnt(0)" ::: "memory");
        SB0
        __builtin_amdgcn_s_barrier();
        SB0
        MFMA16(3, a3)
        cur = nxt;
    }
#undef MFMA16
#undef STG_A
#undef STG_B
#undef SB0

    // epilogue: line-coherent store order (R9-proven)
    float bv[4];
#pragma unroll
    for (int n = 0; n < 4; ++n)
        bv[n] = bias ? bias[col0 + (wc << 6) + n * 16 + rr] : 0.f;
#pragma unroll
    for (int m = 0; m < 8; ++m) {
        size_t rbase = row0 + (wr << 7) + m * 16 + (kc << 2);
#pragma unroll
        for (int jj = 0; jj < 4; ++jj) {
            h16* rowp = C + (rbase + jj) * (size_t)ldc + col0 + (wc << 6) + rr;
#pragma unroll
            for (int n = 0; n < 4; ++n) {
                float v = acc[m][n][jj] + bv[n];
                if (MODE == 1) v = fmaxf(v, 0.f);
                rowp[n * 16] = (h16)v;
            }
        }
    }
}

// ---------------------------------------------------------------- 128x128 2-phase GEMM (R7, proven)
// MODE: 0 = +bias, 1 = +bias+relu, 2 = plain, 3 = split-K partial (out at z*M*N)
template<int MODE>
__global__ __launch_bounds__(512, 4) void k_hgemm(
        const h16* __restrict__ A, int lda,
        const h16* __restrict__ B, int ldb,
        const float* __restrict__ bias,
        h16* __restrict__ C, int ldc,
        int M, int N, int Keff) {
    __shared__ char smem[49152];               // 3 slots x (A 8KB + B 8KB)
    const int t = threadIdx.x;
    const int w = t >> 6, lane = t & 63;
    const int wr = w >> 2, wc = w & 3;         // wave grid 2 x 4
    const int kc = lane >> 4, rr = lane & 15;
    int bx, by;
    xcd_swz(bx, by);
    const size_t row0 = (size_t)by * 128;
    const size_t col0 = (size_t)bx * 128;
    const int z = blockIdx.z;

    const h16* gA = A + (size_t)z * Keff + (row0 + (w << 4) + rr) * (size_t)lda + (kc << 3);
    const h16* gB = B + (size_t)z * Keff + (col0 + (w << 4) + rr) * (size_t)ldb + (kc << 3);
    h16* Cz = C + (MODE == 3 ? (size_t)z * (size_t)M * N : (size_t)0);

    f32x4 acc[4][2];
#pragma unroll
    for (int m = 0; m < 4; ++m)
#pragma unroll
        for (int n = 0; n < 2; ++n) acc[m][n] = (f32x4){0.f, 0.f, 0.f, 0.f};

    const int nt = Keff >> 5;

#define SB0 __builtin_amdgcn_sched_barrier(0);
#define STAGE(step, slot) { char* sA_ = smem + ((slot) << 14) + (w << 10); \
        ldsload16(gA + (size_t)(step) * 32, sA_); \
        ldsload16(gB + (size_t)(step) * 32, sA_ + 8192); }
#define KSTEP(WAITLIT, slotR, DOSTAGE, stepW, slotW) { \
        asm volatile("s_waitcnt vmcnt(" WAITLIT ")" ::: "memory"); \
        SB0 \
        __builtin_amdgcn_s_barrier(); \
        SB0 \
        const char* bA = smem + ((slotR) << 14); \
        const char* bB = bA + 8192; \
        h16x8 af[4], bf[2]; \
        _Pragma("unroll") for (int m = 0; m < 4; ++m) \
            af[m] = *(const h16x8*)(bA + ((wr << 2) + m) * 1024 + lane * 16); \
        _Pragma("unroll") for (int n = 0; n < 2; ++n) \
            bf[n] = *(const h16x8*)(bB + ((wc << 1) + n) * 1024 + lane * 16); \
        asm volatile("s_waitcnt lgkmcnt(0)" ::: "memory"); \
        SB0 \
        if (DOSTAGE) STAGE(stepW, slotW) \
        __builtin_amdgcn_s_setprio(1); \
        _Pragma("unroll") for (int m = 0; m < 4; ++m) \
        _Pragma("unroll") for (int n = 0; n < 2; ++n) \
            acc[m][n] = __builtin_amdgcn_mfma_f32_16x16x32_f16(af[m], bf[n], acc[m][n], 0, 0, 0); \
        __builtin_amdgcn_s_setprio(0); \
        SB0 }

    STAGE(0, 0) STAGE(1, 1)
    int slotR = 0, slotW = 2;
    int it = 0;
    for (; it < nt - 2; ++it) {
        KSTEP("2", slotR, 1, it + 2, slotW)
        slotR = (slotR == 2) ? 0 : slotR + 1;
        slotW = (slotW == 2) ? 0 : slotW + 1;
    }
    KSTEP("2", slotR, 0, 0, 0)
    slotR = (slotR == 2) ? 0 : slotR + 1;
    KSTEP("0", slotR, 0, 0, 0)
#undef KSTEP
#undef STAGE
#undef SB0

#pragma unroll
    for (int n = 0; n < 2; ++n) {
        size_t col = col0 + (wc << 5) + n * 16 + rr;
        float bv = (MODE == 0 || MODE == 1) ? bias[col] : 0.f;
#pragma unroll
        for (int m = 0; m < 4; ++m) {
            size_t rbase = row0 + (wr << 6) + m * 16 + (kc << 2);
#pragma unroll
            for (int j = 0; j < 4; ++j) {
                float v = acc[m][n][j] + bv;
                if (MODE == 1) v = fmaxf(v, 0.f);
                Cz[(rbase + j) * (size_t)ldc + col] = (h16)v;
            }
        }
    }
}

// ---------------------------------------------------------------- attention, one block per (b,h)
__global__ __launch_bounds__(256) void k_attn_h(const h16* __restrict__ qkv,
                                                h16* __restrict__ att) {
    __shared__ float q[32][65], k[32][65], v[32][65];
    __shared__ float sc[32][33];
    int b = blockIdx.x >> 3, h = blockIdx.x & 7;
    int t = threadIdx.x;
    const h16* base = qkv + (size_t)b * 32 * 1536 + h * 64;
    for (int i = t; i < 2048; i += 256) {
        int s = i >> 6, d = i & 63;
        size_t ro = (size_t)s * 1536 + d;
        q[s][d] = (float)base[ro];
        k[s][d] = (float)base[ro + 512];
        v[s][d] = (float)base[ro + 1024];
    }
    __syncthreads();
    {
        int r = t >> 3, c0 = (t & 7) << 2;
        float s0 = 0.f, s1 = 0.f, s2 = 0.f, s3 = 0.f;
#pragma unroll 8
        for (int d = 0; d < 64; ++d) {
            float qv = q[r][d];
            s0 += qv * k[c0 + 0][d];
            s1 += qv * k[c0 + 1][d];
            s2 += qv * k[c0 + 2][d];
            s3 += qv * k[c0 + 3][d];
        }
        sc[r][c0 + 0] = s0 * 0.125f;
        sc[r][c0 + 1] = s1 * 0.125f;
        sc[r][c0 + 2] = s2 * 0.125f;
        sc[r][c0 + 3] = s3 * 0.125f;
    }
    __syncthreads();
    {   // wave-parallel softmax: 8 lanes per row
        int r = t >> 3, c0 = (t & 7) << 2;
        float a0 = sc[r][c0], a1 = sc[r][c0 + 1], a2 = sc[r][c0 + 2], a3 = sc[r][c0 + 3];
        float mx = fmaxf(fmaxf(a0, a1), fmaxf(a2, a3));
        mx = fmaxf(mx, __shfl_xor(mx, 1));
        mx = fmaxf(mx, __shfl_xor(mx, 2));
        mx = fmaxf(mx, __shfl_xor(mx, 4));
        float e0 = expf(a0 - mx), e1 = expf(a1 - mx), e2 = expf(a2 - mx), e3 = expf(a3 - mx);
        float sm = e0 + e1 + e2 + e3;
        sm += __shfl_xor(sm, 1);
        sm += __shfl_xor(sm, 2);
        sm += __shfl_xor(sm, 4);
        float inv = 1.f / sm;
        sc[r][c0] = e0 * inv; sc[r][c0 + 1] = e1 * inv; sc[r][c0 + 2] = e2 * inv; sc[r][c0 + 3] = e3 * inv;
    }
    __syncthreads();
    for (int i = t; i < 2048; i += 256) {
        int s = i >> 6, d = i & 63;
        float acc = 0.f;
#pragma unroll 8
        for (int c = 0; c < 32; ++c) acc += sc[s][c] * v[c][d];
        att[((size_t)b * 32 + s) * DM + h * 64 + d] = (h16)acc;
    }
}

// ---------------------------------------------------------------- x = LN(x + p0 + p1 + bias)*w + b
__global__ __launch_bounds__(256) void k_addln_red(h16* __restrict__ x,
                                                   const h16* __restrict__ p0,
                                                   const h16* __restrict__ p1,
                                                   const float* __restrict__ bias,
                                                   const float* __restrict__ w,
                                                   const float* __restrict__ b) {
    size_t row = blockIdx.x;
    int t = threadIdx.x;
    size_t o0 = row * DM + t, o1 = o0 + 256;
    float v0 = (float)x[o0] + (float)p0[o0] + (float)p1[o0] + bias[t];
    float v1 = (float)x[o1] + (float)p0[o1] + (float)p1[o1] + bias[t + 256];
    float s = v0 + v1;
#pragma unroll
    for (int o = 32; o; o >>= 1) s += __shfl_xor(s, o);
    __shared__ float ss[4], qs[4];
    if ((t & 63) == 0) ss[t >> 6] = s;
    __syncthreads();
    float mean = (ss[0] + ss[1] + ss[2] + ss[3]) * (1.f / 512.f);
    float d0 = v0 - mean, d1 = v1 - mean;
    float qv = d0 * d0 + d1 * d1;
#pragma unroll
    for (int o = 32; o; o >>= 1) qv += __shfl_xor(qv, o);
    if ((t & 63) == 0) qs[t >> 6] = qv;
    __syncthreads();
    float var = (qs[0] + qs[1] + qs[2] + qs[3]) * (1.f / 512.f);
    float inv = 1.f / sqrtf(var + 1e-5f);
    x[o0] = (h16)(d0 * inv * w[t] + b[t]);
    x[o1] = (h16)(d1 * inv * w[t + 256] + b[t + 256]);
}

// ---------------------------------------------------------------- l2 rows: f32 in -> f16 out
__global__ __launch_bounds__(256) void k_l2rows_h(const float* __restrict__ in,
                                                  h16* __restrict__ outp) {
    size_t row = blockIdx.x;
    int t = threadIdx.x;
    float v0 = in[row * DM + t], v1 = in[row * DM + t + 256];
    float q = v0 * v0 + v1 * v1;
#pragma unroll
    for (int o = 32; o; o >>= 1) q += __shfl_xor(q, o);
    __shared__ float qs[4];
    if ((t & 63) == 0) qs[t >> 6] = q;
    __syncthreads();
    float n = sqrtf(qs[0] + qs[1] + qs[2] + qs[3]);
    float sc = 1.f / fmaxf(n, 1e-12f);
    outp[row * DM + t]       = (h16)(v0 * sc);
    outp[row * DM + t + 256] = (h16)(v1 * sc);
}

// ---------------------------------------------------------------- TOK rows (l2'd frames + video tokens)
__global__ __launch_bounds__(256) void k_build_tok_h(const float* __restrict__ frames,
                                                     const h16* __restrict__ X,
                                                     h16* __restrict__ TOK) {
    int rid = blockIdx.x;
    int j = rid / NTOK_V, tt = rid % NTOK_V;
    int t = threadIdx.x;
    float v0, v1;
    if (tt < 30) {
        const float* src = frames + ((size_t)j * 30 + tt) * DM;
        v0 = src[t]; v1 = src[t + 256];
    } else {
        const h16* src = X + ((size_t)j * 32 + (tt - 30)) * DM;
        v0 = (float)src[t]; v1 = (float)src[t + 256];
    }
    float q = v0 * v0 + v1 * v1;
#pragma unroll
    for (int o = 32; o; o >>= 1) q += __shfl_xor(q, o);
    __shared__ float qs[4];
    if ((t & 63) == 0) qs[t >> 6] = q;
    __syncthreads();
    float n = sqrtf(qs[0] + qs[1] + qs[2] + qs[3]);
    float sc = 1.f / fmaxf(n, 1e-12f);
    TOK[(size_t)rid * DM + t]       = (h16)(v0 * sc);
    TOK[(size_t)rid * DM + t + 256] = (h16)(v1 * sc);
}

// ---------------------------------------------------------------- max-reduce dots -> sims
__global__ __launch_bounds__(256) void k_sim_h(const h16* __restrict__ dots,
                                               float* __restrict__ out) {
    int i = blockIdx.x;
    int j = threadIdx.x;
    const h16* p = dots + (size_t)i * 15872 + (size_t)j * NTOK_V;
    float mf = -1e30f, mv = -1e30f;
#pragma unroll
    for (int tt = 0; tt < 30; ++tt) mf = fmaxf(mf, (float)p[tt]);
#pragma unroll
    for (int tt = 30; tt < 62; ++tt) mv = fmaxf(mv, (float)p[tt]);
    int o = i * 256 + j;
    out[o]          = mf + mv;
    out[65536 + o]  = mf;
    out[131072 + o] = mv;
}

// ---------------------------------------------------------------- launcher
extern "C" void kernel_launch(void* const* d_in, const int* in_sizes, int n_in,
                              void* d_out, int out_size, void* d_ws, size_t ws_size,
                              hipStream_t stream) {
    const float* text   = (const float*)d_in[0];
    const float* frames = (const float*)d_in[1];
    const float* expt   = (const float*)d_in[2];
    const float* Wqkv   = (const float*)d_in[3];
    const float* bqkv   = (const float*)d_in[4];
    const float* Wo     = (const float*)d_in[5];
    const float* bo     = (const float*)d_in[6];
    const float* ln1w   = (const float*)d_in[7];
    const float* ln1b   = (const float*)d_in[8];
    const float* W1     = (const float*)d_in[9];
    const float* b1     = (const float*)d_in[10];
    const float* W2     = (const float*)d_in[11];
    const float* b2     = (const float*)d_in[12];
    const float* ln2w   = (const float*)d_in[13];
    const float* ln2b   = (const float*)d_in[14];
    float* out = (float*)d_out;

    char* wsb = (char*)d_ws;
    const size_t MB = 1024 * 1024;
    h16* Xh    = (h16*)(wsb);              // 8 MB   [8192,512]
    h16* P0    = (h16*)(wsb + 8 * MB);     // 8 MB   split-K partial 0
    h16* P1    = (h16*)(wsb + 16 * MB);    // 8 MB   split-K partial 1 (= P0 + 8192*512)
    h16* ATTh  = (h16*)(wsb + 24 * MB);    // 8 MB   [8192,512]
    h16* FFh   = (h16*)(wsb + 32 * MB);    // 32 MB  [8192,2048] (also QKV [8192,1536])
    h16* TOKh  = (h16*)(wsb + 32 * MB);    // alias FF: 15.5 MB [15872,512] (post-transformer)
    h16* DOTSh = (h16*)(wsb + 48 * MB);    // alias FF tail: 7.75 MB [256,15872]
    h16* Wh    = (h16*)(wsb + 64 * MB);    // 25 MB  all weights fp16
    h16* QHATh = (h16*)(wsb + 90 * MB);    // 0.25 MB [256,512]

    h16* Whqkv = Wh;                       // 4*1536*512
    h16* Who   = Whqkv + 3145728;          // 4*512*512
    h16* Wh1   = Who + 1048576;            // 4*2048*512
    h16* Wh2   = Wh1 + 4194304;            // 4*2048*512

    k_cvt<<<1536, 256, 0, stream>>>(Wqkv, Whqkv, 393216);
    k_cvt<<<512,  256, 0, stream>>>(Wo,   Who,   131072);
    k_cvt<<<2048, 256, 0, stream>>>(W1,   Wh1,   524288);
    k_cvt<<<2048, 256, 0, stream>>>(W2,   Wh2,   524288);
    k_concat_h<<<8192, 256, 0, stream>>>(frames, expt, Xh);

    for (int l = 0; l < 4; ++l) {
        const h16* Wqkv_l = Whqkv + (size_t)l * 786432;
        const h16* Wo_l   = Who   + (size_t)l * 262144;
        const h16* W1_l   = Wh1   + (size_t)l * 1048576;
        const h16* W2_l   = Wh2   + (size_t)l * 1048576;

        k_g8<0><<<dim3(6, 32, 1), 512, 0, stream>>>(
            Xh, 512, Wqkv_l, 512, bqkv + (size_t)l * 1536, FFh, 1536, 8192, 1536, 512);
        k_attn_h<<<2048, 256, 0, stream>>>(FFh, ATTh);
        k_hgemm<3><<<dim3(4, 64, 2), 512, 0, stream>>>(
            ATTh, 512, Wo_l, 512, nullptr, P0, 512, 8192, 512, 256);
        k_addln_red<<<8192, 256, 0, stream>>>(Xh, P0, P1, bo + (size_t)l * 512,
                                              ln1w + (size_t)l * 512, ln1b + (size_t)l * 512);
        k_g8<1><<<dim3(8, 32, 1), 512, 0, stream>>>(
            Xh, 512, W1_l, 512, b1 + (size_t)l * 2048, FFh, 2048, 8192, 2048, 512);
        k_hgemm<3><<<dim3(4, 64, 2), 512, 0, stream>>>(
            FFh, 2048, W2_l, 2048, nullptr, P0, 512, 8192, 512, 1024);
        k_addln_red<<<8192, 256, 0, stream>>>(Xh, P0, P1, b2 + (size_t)l * 512,
                                              ln2w + (size_t)l * 512, ln2b + (size_t)l * 512);
    }

    k_l2rows_h<<<256, 256, 0, stream>>>(text, QHATh);
    k_build_tok_h<<<256 * NTOK_V, 256, 0, stream>>>(frames, Xh, TOKh);
    k_hgemm<2><<<dim3(124, 2, 1), 512, 0, stream>>>(
        QHATh, 512, TOKh, 512, nullptr, DOTSh, 15872, 256, 15872, 512);
    k_sim_h<<<256, 256, 0, stream>>>(DOTSh, out);
}

// Round 11
// 628.223 us; speedup vs baseline: 1.6150x; 1.0056x over previous
//
#include <hip/hip_runtime.h>
#include <math.h>

#define DM 512
#define NTOK_V 62

typedef _Float16 h16;
typedef __attribute__((ext_vector_type(8))) _Float16 h16x8;
typedef __attribute__((ext_vector_type(4))) float f32x4;

__device__ __forceinline__ void ldsload16(const void* g, void* l) {
    __builtin_amdgcn_global_load_lds(
        (const __attribute__((address_space(1))) unsigned int*)g,
        (__attribute__((address_space(3))) unsigned int*)l, 16, 0, 0);
}

// XCD-chunked bijective blockIdx swizzle (T1; requires nwg%8==0)
__device__ __forceinline__ void xcd_swz(int& bx, int& by) {
    const int gx = gridDim.x, gy = gridDim.y;
    const int lin = blockIdx.x + gx * blockIdx.y;
    const int cpx = (gx * gy) >> 3;
    const int wg = (lin & 7) * cpx + (lin >> 3);
    bx = wg % gx;
    by = wg / gx;
}

// ---------------------------------------------------------------- fp32 -> fp16 convert
__global__ __launch_bounds__(256) void k_cvt(const float* __restrict__ in,
                                             h16* __restrict__ outp, int n8) {
    int i = blockIdx.x * 256 + threadIdx.x;
    if (i >= n8) return;
    float4 a = ((const float4*)in)[i * 2];
    float4 b = ((const float4*)in)[i * 2 + 1];
    h16x8 h;
    h[0] = (h16)a.x; h[1] = (h16)a.y; h[2] = (h16)a.z; h[3] = (h16)a.w;
    h[4] = (h16)b.x; h[5] = (h16)b.y; h[6] = (h16)b.z; h[7] = (h16)b.w;
    ((h16x8*)outp)[i] = h;
}

// ---------------------------------------------------------------- concat -> fp16 X
__global__ __launch_bounds__(256) void k_concat_h(const float* __restrict__ frames,
                                                  const float* __restrict__ expt,
                                                  h16* __restrict__ X) {
    int row = blockIdx.x;
    int b = row >> 5, s = row & 31;
    int t = threadIdx.x;
    const float* src = (s < 30) ? (frames + ((size_t)(b * 30 + s)) * DM)
                                : (expt + (size_t)(s - 30) * DM);
    X[(size_t)row * DM + t]       = (h16)src[t];
    X[(size_t)row * DM + t + 256] = (h16)src[t + 256];
}

// ---------------------------------------------------------------- 8-phase 256x256 MFMA GEMM (R9/R10-proven)
template<int MODE>   // 0 = +bias, 1 = +bias+relu
__global__ __launch_bounds__(512, 2) void k_g8(
        const h16* __restrict__ A, int lda,
        const h16* __restrict__ B, int ldb,
        const float* __restrict__ bias,
        h16* __restrict__ C, int ldc,
        int M, int N, int Keff) {
    __shared__ char smem[131072];
    const int t = threadIdx.x;
    const int w = t >> 6, lane = t & 63;
    const int wr = w >> 2, wc = w & 3;
    const int kc = lane >> 4, rr = lane & 15;
    int bx, by;
    xcd_swz(bx, by);
    const size_t row0 = (size_t)by * 256;
    const size_t col0 = (size_t)bx * 256;

    const h16* gA = A + (row0 + (w << 4) + rr) * (size_t)lda + (kc << 3);
    const h16* gB = B + (col0 + (w << 4) + rr) * (size_t)ldb + (kc << 3);

    f32x4 acc[8][4];
#pragma unroll
    for (int m = 0; m < 8; ++m)
#pragma unroll
        for (int n = 0; n < 4; ++n) acc[m][n] = (f32x4){0.f, 0.f, 0.f, 0.f};

    const int nt = Keff >> 6;

#define SB0 __builtin_amdgcn_sched_barrier(0);
#define STG_A(bs, h, jt) { char* d_ = smem + (bs)*65536 + (h)*16384 + (w << 10) + (lane << 4); \
        const h16* s_ = gA + (size_t)((h)*128) * lda + (size_t)(jt)*64; \
        ldsload16(s_, d_); ldsload16(s_ + 32, d_ + 8192); }
#define STG_B(bs, h, jt) { char* d_ = smem + (bs)*65536 + 32768 + (h)*16384 + (w << 10) + (lane << 4); \
        const h16* s_ = gB + (size_t)((h)*128) * ldb + (size_t)(jt)*64; \
        ldsload16(s_, d_); ldsload16(s_ + 32, d_ + 8192); }
#define MFMA16(mp, AF) { \
        __builtin_amdgcn_s_setprio(1); \
        _Pragma("unroll") for (int i = 0; i < 2; ++i) \
        _Pragma("unroll") for (int n = 0; n < 4; ++n) \
        _Pragma("unroll") for (int kk = 0; kk < 2; ++kk) \
            acc[(mp)*2 + i][n] = __builtin_amdgcn_mfma_f32_16x16x32_f16(AF[i][kk], bf[n][kk], acc[(mp)*2 + i][n], 0, 0, 0); \
        __builtin_amdgcn_s_setprio(0); SB0 }

    STG_A(0, 0, 0) STG_A(0, 1, 0) STG_B(0, 0, 0) STG_B(0, 1, 0)

    int cur = 0;
    for (int j = 0; j < nt; ++j) {
        const int nxt = cur ^ 1;
        if (j + 1 < nt) {
            STG_A(nxt, 0, j + 1)
            asm volatile("s_waitcnt vmcnt(2)" ::: "memory");
        } else {
            asm volatile("s_waitcnt vmcnt(0)" ::: "memory");
        }
        SB0
        __builtin_amdgcn_s_barrier();
        SB0
        const char* Ab = smem + cur * 65536 + wr * 16384;
        const char* Bb = smem + cur * 65536 + 32768 + (wc >> 1) * 16384;
        h16x8 bf[4][2];
#pragma unroll
        for (int n = 0; n < 4; ++n)
#pragma unroll
            for (int kk = 0; kk < 2; ++kk)
                bf[n][kk] = *(const h16x8*)(Bb + kk * 8192 + (((wc & 1) << 2) + n) * 1024 + (lane << 4));
        h16x8 a0[2][2];
#pragma unroll
        for (int i = 0; i < 2; ++i)
#pragma unroll
            for (int kk = 0; kk < 2; ++kk)
                a0[i][kk] = *(const h16x8*)(Ab + kk * 8192 + (0 + i) * 1024 + (lane << 4));
        asm volatile("s_waitcnt lgkmcnt(0)" ::: "memory");
        SB0
        MFMA16(0, a0)
        h16x8 a1[2][2];
#pragma unroll
        for (int i = 0; i < 2; ++i)
#pragma unroll
            for (int kk = 0; kk < 2; ++kk)
                a1[i][kk] = *(const h16x8*)(Ab + kk * 8192 + (2 + i) * 1024 + (lane << 4));
        if (j + 1 < nt) STG_A(nxt, 1, j + 1)
        asm volatile("s_waitcnt lgkmcnt(0)" ::: "memory");
        SB0
        __builtin_amdgcn_s_barrier();
        SB0
        MFMA16(1, a1)
        h16x8 a2[2][2];
#pragma unroll
        for (int i = 0; i < 2; ++i)
#pragma unroll
            for (int kk = 0; kk < 2; ++kk)
                a2[i][kk] = *(const h16x8*)(Ab + kk * 8192 + (4 + i) * 1024 + (lane << 4));
        if (j + 1 < nt) STG_B(nxt, 0, j + 1)
        asm volatile("s_waitcnt lgkmcnt(0)" ::: "memory");
        SB0
        __builtin_amdgcn_s_barrier();
        SB0
        MFMA16(2, a2)
        h16x8 a3[2][2];
#pragma unroll
        for (int i = 0; i < 2; ++i)
#pragma unroll
            for (int kk = 0; kk < 2; ++kk)
                a3[i][kk] = *(const h16x8*)(Ab + kk * 8192 + (6 + i) * 1024 + (lane << 4));
        if (j + 1 < nt) STG_B(nxt, 1, j + 1)
        asm volatile("s_waitcnt lgkmcnt(0)" ::: "memory");
        SB0
        __builtin_amdgcn_s_barrier();
        SB0
        MFMA16(3, a3)
        cur = nxt;
    }
#undef MFMA16
#undef STG_A
#undef STG_B
#undef SB0

    float bv[4];
#pragma unroll
    for (int n = 0; n < 4; ++n)
        bv[n] = bias ? bias[col0 + (wc << 6) + n * 16 + rr] : 0.f;
#pragma unroll
    for (int m = 0; m < 8; ++m) {
        size_t rbase = row0 + (wr << 7) + m * 16 + (kc << 2);
#pragma unroll
        for (int jj = 0; jj < 4; ++jj) {
            h16* rowp = C + (rbase + jj) * (size_t)ldc + col0 + (wc << 6) + rr;
#pragma unroll
            for (int n = 0; n < 4; ++n) {
                float v = acc[m][n][jj] + bv[n];
                if (MODE == 1) v = fmaxf(v, 0.f);
                rowp[n * 16] = (h16)v;
            }
        }
    }
}

// ---------------------------------------------------------------- 128x128 2-phase GEMM (R7-proven)
template<int MODE>   // 2 = plain, 3 = split-K partial
__global__ __launch_bounds__(512, 4) void k_hgemm(
        const h16* __restrict__ A, int lda,
        const h16* __restrict__ B, int ldb,
        const float* __restrict__ bias,
        h16* __restrict__ C, int ldc,
        int M, int N, int Keff) {
    __shared__ char smem[49152];
    const int t = threadIdx.x;
    const int w = t >> 6, lane = t & 63;
    const int wr = w >> 2, wc = w & 3;
    const int kc = lane >> 4, rr = lane & 15;
    int bx, by;
    xcd_swz(bx, by);
    const size_t row0 = (size_t)by * 128;
    const size_t col0 = (size_t)bx * 128;
    const int z = blockIdx.z;

    const h16* gA = A + (size_t)z * Keff + (row0 + (w << 4) + rr) * (size_t)lda + (kc << 3);
    const h16* gB = B + (size_t)z * Keff + (col0 + (w << 4) + rr) * (size_t)ldb + (kc << 3);
    h16* Cz = C + (MODE == 3 ? (size_t)z * (size_t)M * N : (size_t)0);

    f32x4 acc[4][2];
#pragma unroll
    for (int m = 0; m < 4; ++m)
#pragma unroll
        for (int n = 0; n < 2; ++n) acc[m][n] = (f32x4){0.f, 0.f, 0.f, 0.f};

    const int nt = Keff >> 5;

#define SB0 __builtin_amdgcn_sched_barrier(0);
#define STAGE(step, slot) { char* sA_ = smem + ((slot) << 14) + (w << 10); \
        ldsload16(gA + (size_t)(step) * 32, sA_); \
        ldsload16(gB + (size_t)(step) * 32, sA_ + 8192); }
#define KSTEP(WAITLIT, slotR, DOSTAGE, stepW, slotW) { \
        asm volatile("s_waitcnt vmcnt(" WAITLIT ")" ::: "memory"); \
        SB0 \
        __builtin_amdgcn_s_barrier(); \
        SB0 \
        const char* bA = smem + ((slotR) << 14); \
        const char* bB = bA + 8192; \
        h16x8 af[4], bf[2]; \
        _Pragma("unroll") for (int m = 0; m < 4; ++m) \
            af[m] = *(const h16x8*)(bA + ((wr << 2) + m) * 1024 + lane * 16); \
        _Pragma("unroll") for (int n = 0; n < 2; ++n) \
            bf[n] = *(const h16x8*)(bB + ((wc << 1) + n) * 1024 + lane * 16); \
        asm volatile("s_waitcnt lgkmcnt(0)" ::: "memory"); \
        SB0 \
        if (DOSTAGE) STAGE(stepW, slotW) \
        __builtin_amdgcn_s_setprio(1); \
        _Pragma("unroll") for (int m = 0; m < 4; ++m) \
        _Pragma("unroll") for (int n = 0; n < 2; ++n) \
            acc[m][n] = __builtin_amdgcn_mfma_f32_16x16x32_f16(af[m], bf[n], acc[m][n], 0, 0, 0); \
        __builtin_amdgcn_s_setprio(0); \
        SB0 }

    STAGE(0, 0) STAGE(1, 1)
    int slotR = 0, slotW = 2;
    int it = 0;
    for (; it < nt - 2; ++it) {
        KSTEP("2", slotR, 1, it + 2, slotW)
        slotR = (slotR == 2) ? 0 : slotR + 1;
        slotW = (slotW == 2) ? 0 : slotW + 1;
    }
    KSTEP("2", slotR, 0, 0, 0)
    slotR = (slotR == 2) ? 0 : slotR + 1;
    KSTEP("0", slotR, 0, 0, 0)
#undef KSTEP
#undef STAGE
#undef SB0

#pragma unroll
    for (int n = 0; n < 2; ++n) {
        size_t col = col0 + (wc << 5) + n * 16 + rr;
        float bv = (MODE == 0 || MODE == 1) ? bias[col] : 0.f;
#pragma unroll
        for (int m = 0; m < 4; ++m) {
            size_t rbase = row0 + (wr << 6) + m * 16 + (kc << 2);
#pragma unroll
            for (int j = 0; j < 4; ++j) {
                float v = acc[m][n][j] + bv;
                if (MODE == 1) v = fmaxf(v, 0.f);
                Cz[(rbase + j) * (size_t)ldc + col] = (h16)v;
            }
        }
    }
}

// ---------------------------------------------------------------- fused O-proj + residual + LN (R11)
// One block per 32 rows (video). 512 thr = 8 waves; wave w owns cols w*64..+63
// of all 32 rows. A (ATT 32x512) fully pre-staged fragment-native (32KB);
// W_o streamed via 3-slot ring (3x32KB), BK=32, counted vmcnt(4)/tail 0,
// one barrier per step (R6-proven WAR-safe). Epilogue: acc+bias -> LDS f32
// [32][516] -> per-row 16-lane shfl reduce -> x = LN(x + proj)*w + b in place.
__global__ __launch_bounds__(512, 2) void k_attproj(
        const h16* __restrict__ ATT,
        const h16* __restrict__ Bw,      // W_o fp16 [512,512]
        const float* __restrict__ bo,
        h16* __restrict__ X,             // residual in, LN out (in place)
        const float* __restrict__ lw,
        const float* __restrict__ lb) {
    __shared__ char smem[131072];        // A 32KB @0 | ring 3x32KB @32768
    const int t = threadIdx.x;
    const int w = t >> 6, lane = t & 63;
    const int kc = lane >> 4, rr = lane & 15;
    const size_t row0 = (size_t)blockIdx.x * 32;
    const h16* Ain = ATT + row0 * DM;

    f32x4 acc[2][4];
#pragma unroll
    for (int m = 0; m < 2; ++m)
#pragma unroll
        for (int n = 0; n < 4; ++n) acc[m][n] = (f32x4){0.f, 0.f, 0.f, 0.f};

#define SB0 __builtin_amdgcn_sched_barrier(0);
#define STGB(js, sl) { _Pragma("unroll") for (int u = 0; u < 4; ++u) { \
        const h16* s_ = Bw + (size_t)((((u << 3) + w) << 4) + rr) * DM + (js) * 32 + (kc << 3); \
        ldsload16(s_, smem + 32768 + (sl) * 32768 + ((((u << 3) + w) << 10)) + (lane << 4)); } }

    // prologue: A full (4 loads/thread) + B step0 + B step1
#pragma unroll
    for (int u = 0; u < 4; ++u) {
        int sidx = (u << 2) + (w >> 1);
        const h16* s_ = Ain + (size_t)(((w & 1) << 4) + rr) * DM + sidx * 32 + (kc << 3);
        ldsload16(s_, smem + (sidx << 11) + ((w & 1) << 10) + (lane << 4));
    }
    STGB(0, 0) STGB(1, 1)

    int slotR = 0, slotW = 2;
    for (int s = 0; s < 15; ++s) {
        asm volatile("s_waitcnt vmcnt(4)" ::: "memory");
        SB0
        __builtin_amdgcn_s_barrier();
        SB0
        h16x8 af[2], bf[4];
#pragma unroll
        for (int m = 0; m < 2; ++m)
            af[m] = *(const h16x8*)(smem + (s << 11) + (m << 10) + (lane << 4));
#pragma unroll
        for (int n = 0; n < 4; ++n)
            bf[n] = *(const h16x8*)(smem + 32768 + slotR * 32768 + (((w << 2) + n) << 10) + (lane << 4));
        asm volatile("s_waitcnt lgkmcnt(0)" ::: "memory");
        SB0
        if (s + 2 < 16) STGB(s + 2, slotW)
        __builtin_amdgcn_s_setprio(1);
#pragma unroll
        for (int m = 0; m < 2; ++m)
#pragma unroll
            for (int n = 0; n < 4; ++n)
                acc[m][n] = __builtin_amdgcn_mfma_f32_16x16x32_f16(af[m], bf[n], acc[m][n], 0, 0, 0);
        __builtin_amdgcn_s_setprio(0);
        SB0
        slotR = (slotR == 2) ? 0 : slotR + 1;
        slotW = (slotW == 2) ? 0 : slotW + 1;
    }
    {   // s = 15 (drain)
        asm volatile("s_waitcnt vmcnt(0)" ::: "memory");
        SB0
        __builtin_amdgcn_s_barrier();
        SB0
        h16x8 af[2], bf[4];
#pragma unroll
        for (int m = 0; m < 2; ++m)
            af[m] = *(const h16x8*)(smem + (15 << 11) + (m << 10) + (lane << 4));
#pragma unroll
        for (int n = 0; n < 4; ++n)
            bf[n] = *(const h16x8*)(smem + 32768 + slotR * 32768 + (((w << 2) + n) << 10) + (lane << 4));
        asm volatile("s_waitcnt lgkmcnt(0)" ::: "memory");
        SB0
#pragma unroll
        for (int m = 0; m < 2; ++m)
#pragma unroll
            for (int n = 0; n < 4; ++n)
                acc[m][n] = __builtin_amdgcn_mfma_f32_16x16x32_f16(af[m], bf[n], acc[m][n], 0, 0, 0);
    }
#undef STGB
#undef SB0
    __syncthreads();                     // all reads done -> LDS reusable

    // proj + bias -> LDS f32 [32][516]
    float* outl = (float*)smem;
    float bv[4];
#pragma unroll
    for (int n = 0; n < 4; ++n)
        bv[n] = bo[(w << 6) + n * 16 + rr];
#pragma unroll
    for (int m = 0; m < 2; ++m)
#pragma unroll
        for (int n = 0; n < 4; ++n)
#pragma unroll
            for (int j = 0; j < 4; ++j) {
                int r = m * 16 + (lane >> 4) * 4 + j;
                int c = (w << 6) + n * 16 + rr;
                outl[r * 516 + c] = acc[m][n][j] + bv[n];
            }
    __syncthreads();

    // LN: thread t -> row r = t>>4, cols l + 16*i (l = t&15, i = 0..31)
    {
        const int r = t >> 4, l = t & 15;
        const size_t grow = (row0 + r) * (size_t)DM;
        float v[32];
        float sum = 0.f, sq = 0.f;
#pragma unroll
        for (int i = 0; i < 32; ++i) {
            int col = l + (i << 4);
            float vv = outl[r * 516 + col] + (float)X[grow + col];
            v[i] = vv;
            sum += vv;
            sq += vv * vv;
        }
#pragma unroll
        for (int o = 8; o; o >>= 1) {
            sum += __shfl_xor(sum, o);
            sq  += __shfl_xor(sq, o);
        }
        float mean = sum * (1.f / 512.f);
        float var = sq * (1.f / 512.f) - mean * mean;
        float inv = 1.f / sqrtf(var + 1e-5f);
#pragma unroll
        for (int i = 0; i < 32; ++i) {
            int col = l + (i << 4);
            X[grow + col] = (h16)((v[i] - mean) * inv * lw[col] + lb[col]);
        }
    }
}

// ---------------------------------------------------------------- attention, one block per (b,h)
__global__ __launch_bounds__(256) void k_attn_h(const h16* __restrict__ qkv,
                                                h16* __restrict__ att) {
    __shared__ float q[32][65], k[32][65], v[32][65];
    __shared__ float sc[32][33];
    int b = blockIdx.x >> 3, h = blockIdx.x & 7;
    int t = threadIdx.x;
    const h16* base = qkv + (size_t)b * 32 * 1536 + h * 64;
    for (int i = t; i < 2048; i += 256) {
        int s = i >> 6, d = i & 63;
        size_t ro = (size_t)s * 1536 + d;
        q[s][d] = (float)base[ro];
        k[s][d] = (float)base[ro + 512];
        v[s][d] = (float)base[ro + 1024];
    }
    __syncthreads();
    {
        int r = t >> 3, c0 = (t & 7) << 2;
        float s0 = 0.f, s1 = 0.f, s2 = 0.f, s3 = 0.f;
#pragma unroll 8
        for (int d = 0; d < 64; ++d) {
            float qv = q[r][d];
            s0 += qv * k[c0 + 0][d];
            s1 += qv * k[c0 + 1][d];
            s2 += qv * k[c0 + 2][d];
            s3 += qv * k[c0 + 3][d];
        }
        sc[r][c0 + 0] = s0 * 0.125f;
        sc[r][c0 + 1] = s1 * 0.125f;
        sc[r][c0 + 2] = s2 * 0.125f;
        sc[r][c0 + 3] = s3 * 0.125f;
    }
    __syncthreads();
    {
        int r = t >> 3, c0 = (t & 7) << 2;
        float a0 = sc[r][c0], a1 = sc[r][c0 + 1], a2 = sc[r][c0 + 2], a3 = sc[r][c0 + 3];
        float mx = fmaxf(fmaxf(a0, a1), fmaxf(a2, a3));
        mx = fmaxf(mx, __shfl_xor(mx, 1));
        mx = fmaxf(mx, __shfl_xor(mx, 2));
        mx = fmaxf(mx, __shfl_xor(mx, 4));
        float e0 = expf(a0 - mx), e1 = expf(a1 - mx), e2 = expf(a2 - mx), e3 = expf(a3 - mx);
        float sm = e0 + e1 + e2 + e3;
        sm += __shfl_xor(sm, 1);
        sm += __shfl_xor(sm, 2);
        sm += __shfl_xor(sm, 4);
        float inv = 1.f / sm;
        sc[r][c0] = e0 * inv; sc[r][c0 + 1] = e1 * inv; sc[r][c0 + 2] = e2 * inv; sc[r][c0 + 3] = e3 * inv;
    }
    __syncthreads();
    for (int i = t; i < 2048; i += 256) {
        int s = i >> 6, d = i & 63;
        float acc = 0.f;
#pragma unroll 8
        for (int c = 0; c < 32; ++c) acc += sc[s][c] * v[c][d];
        att[((size_t)b * 32 + s) * DM + h * 64 + d] = (h16)acc;
    }
}

// ---------------------------------------------------------------- x = LN(x + p0 + p1 + bias)*w + b
__global__ __launch_bounds__(256) void k_addln_red(h16* __restrict__ x,
                                                   const h16* __restrict__ p0,
                                                   const h16* __restrict__ p1,
                                                   const float* __restrict__ bias,
                                                   const float* __restrict__ w,
                                                   const float* __restrict__ b) {
    size_t row = blockIdx.x;
    int t = threadIdx.x;
    size_t o0 = row * DM + t, o1 = o0 + 256;
    float v0 = (float)x[o0] + (float)p0[o0] + (float)p1[o0] + bias[t];
    float v1 = (float)x[o1] + (float)p0[o1] + (float)p1[o1] + bias[t + 256];
    float s = v0 + v1;
#pragma unroll
    for (int o = 32; o; o >>= 1) s += __shfl_xor(s, o);
    __shared__ float ss[4], qs[4];
    if ((t & 63) == 0) ss[t >> 6] = s;
    __syncthreads();
    float mean = (ss[0] + ss[1] + ss[2] + ss[3]) * (1.f / 512.f);
    float d0 = v0 - mean, d1 = v1 - mean;
    float qv = d0 * d0 + d1 * d1;
#pragma unroll
    for (int o = 32; o; o >>= 1) qv += __shfl_xor(qv, o);
    if ((t & 63) == 0) qs[t >> 6] = qv;
    __syncthreads();
    float var = (qs[0] + qs[1] + qs[2] + qs[3]) * (1.f / 512.f);
    float inv = 1.f / sqrtf(var + 1e-5f);
    x[o0] = (h16)(d0 * inv * w[t] + b[t]);
    x[o1] = (h16)(d1 * inv * w[t + 256] + b[t + 256]);
}

// ---------------------------------------------------------------- l2 rows: f32 in -> f16 out
__global__ __launch_bounds__(256) void k_l2rows_h(const float* __restrict__ in,
                                                  h16* __restrict__ outp) {
    size_t row = blockIdx.x;
    int t = threadIdx.x;
    float v0 = in[row * DM + t], v1 = in[row * DM + t + 256];
    float q = v0 * v0 + v1 * v1;
#pragma unroll
    for (int o = 32; o; o >>= 1) q += __shfl_xor(q, o);
    __shared__ float qs[4];
    if ((t & 63) == 0) qs[t >> 6] = q;
    __syncthreads();
    float n = sqrtf(qs[0] + qs[1] + qs[2] + qs[3]);
    float sc = 1.f / fmaxf(n, 1e-12f);
    outp[row * DM + t]       = (h16)(v0 * sc);
    outp[row * DM + t + 256] = (h16)(v1 * sc);
}

// ---------------------------------------------------------------- TOK rows (l2'd frames + video tokens)
__global__ __launch_bounds__(256) void k_build_tok_h(const float* __restrict__ frames,
                                                     const h16* __restrict__ X,
                                                     h16* __restrict__ TOK) {
    int rid = blockIdx.x;
    int j = rid / NTOK_V, tt = rid % NTOK_V;
    int t = threadIdx.x;
    float v0, v1;
    if (tt < 30) {
        const float* src = frames + ((size_t)j * 30 + tt) * DM;
        v0 = src[t]; v1 = src[t + 256];
    } else {
        const h16* src = X + ((size_t)j * 32 + (tt - 30)) * DM;
        v0 = (float)src[t]; v1 = (float)src[t + 256];
    }
    float q = v0 * v0 + v1 * v1;
#pragma unroll
    for (int o = 32; o; o >>= 1) q += __shfl_xor(q, o);
    __shared__ float qs[4];
    if ((t & 63) == 0) qs[t >> 6] = q;
    __syncthreads();
    float n = sqrtf(qs[0] + qs[1] + qs[2] + qs[3]);
    float sc = 1.f / fmaxf(n, 1e-12f);
    TOK[(size_t)rid * DM + t]       = (h16)(v0 * sc);
    TOK[(size_t)rid * DM + t + 256] = (h16)(v1 * sc);
}

// ---------------------------------------------------------------- max-reduce dots -> sims
__global__ __launch_bounds__(256) void k_sim_h(const h16* __restrict__ dots,
                                               float* __restrict__ out) {
    int i = blockIdx.x;
    int j = threadIdx.x;
    const h16* p = dots + (size_t)i * 15872 + (size_t)j * NTOK_V;
    float mf = -1e30f, mv = -1e30f;
#pragma unroll
    for (int tt = 0; tt < 30; ++tt) mf = fmaxf(mf, (float)p[tt]);
#pragma unroll
    for (int tt = 30; tt < 62; ++tt) mv = fmaxf(mv, (float)p[tt]);
    int o = i * 256 + j;
    out[o]          = mf + mv;
    out[65536 + o]  = mf;
    out[131072 + o] = mv;
}

// ---------------------------------------------------------------- launcher
extern "C" void kernel_launch(void* const* d_in, const int* in_sizes, int n_in,
                              void* d_out, int out_size, void* d_ws, size_t ws_size,
                              hipStream_t stream) {
    const float* text   = (const float*)d_in[0];
    const float* frames = (const float*)d_in[1];
    const float* expt   = (const float*)d_in[2];
    const float* Wqkv   = (const float*)d_in[3];
    const float* bqkv   = (const float*)d_in[4];
    const float* Wo     = (const float*)d_in[5];
    const float* bo     = (const float*)d_in[6];
    const float* ln1w   = (const float*)d_in[7];
    const float* ln1b   = (const float*)d_in[8];
    const float* W1     = (const float*)d_in[9];
    const float* b1     = (const float*)d_in[10];
    const float* W2     = (const float*)d_in[11];
    const float* b2     = (const float*)d_in[12];
    const float* ln2w   = (const float*)d_in[13];
    const float* ln2b   = (const float*)d_in[14];
    float* out = (float*)d_out;

    char* wsb = (char*)d_ws;
    const size_t MB = 1024 * 1024;
    h16* Xh    = (h16*)(wsb);              // 8 MB   [8192,512]
    h16* P0    = (h16*)(wsb + 8 * MB);     // 8 MB   split-K partial 0 (FF2)
    h16* P1    = (h16*)(wsb + 16 * MB);    // 8 MB   split-K partial 1
    h16* ATTh  = (h16*)(wsb + 24 * MB);    // 8 MB   [8192,512]
    h16* FFh   = (h16*)(wsb + 32 * MB);    // 32 MB  [8192,2048] (also QKV [8192,1536])
    h16* TOKh  = (h16*)(wsb + 32 * MB);    // alias FF: 15.5 MB (post-transformer)
    h16* DOTSh = (h16*)(wsb + 48 * MB);    // alias FF tail: 7.75 MB
    h16* Wh    = (h16*)(wsb + 64 * MB);    // 25 MB  all weights fp16
    h16* QHATh = (h16*)(wsb + 90 * MB);    // 0.25 MB

    h16* Whqkv = Wh;                       // 4*1536*512
    h16* Who   = Whqkv + 3145728;          // 4*512*512
    h16* Wh1   = Who + 1048576;            // 4*2048*512
    h16* Wh2   = Wh1 + 4194304;            // 4*2048*512

    k_cvt<<<1536, 256, 0, stream>>>(Wqkv, Whqkv, 393216);
    k_cvt<<<512,  256, 0, stream>>>(Wo,   Who,   131072);
    k_cvt<<<2048, 256, 0, stream>>>(W1,   Wh1,   524288);
    k_cvt<<<2048, 256, 0, stream>>>(W2,   Wh2,   524288);
    k_concat_h<<<8192, 256, 0, stream>>>(frames, expt, Xh);

    for (int l = 0; l < 4; ++l) {
        const h16* Wqkv_l = Whqkv + (size_t)l * 786432;
        const h16* Wo_l   = Who   + (size_t)l * 262144;
        const h16* W1_l   = Wh1   + (size_t)l * 1048576;
        const h16* W2_l   = Wh2   + (size_t)l * 1048576;

        k_g8<0><<<dim3(6, 32, 1), 512, 0, stream>>>(
            Xh, 512, Wqkv_l, 512, bqkv + (size_t)l * 1536, FFh, 1536, 8192, 1536, 512);
        k_attn_h<<<2048, 256, 0, stream>>>(FFh, ATTh);
        k_attproj<<<256, 512, 0, stream>>>(ATTh, Wo_l, bo + (size_t)l * 512, Xh,
                                           ln1w + (size_t)l * 512, ln1b + (size_t)l * 512);
        k_g8<1><<<dim3(8, 32, 1), 512, 0, stream>>>(
            Xh, 512, W1_l, 512, b1 + (size_t)l * 2048, FFh, 2048, 8192, 2048, 512);
        k_hgemm<3><<<dim3(4, 64, 2), 512, 0, stream>>>(
            FFh, 2048, W2_l, 2048, nullptr, P0, 512, 8192, 512, 1024);
        k_addln_red<<<8192, 256, 0, stream>>>(Xh, P0, P1, b2 + (size_t)l * 512,
                                              ln2w + (size_t)l * 512, ln2b + (size_t)l * 512);
    }

    k_l2rows_h<<<256, 256, 0, stream>>>(text, QHATh);
    k_build_tok_h<<<256 * NTOK_V, 256, 0, stream>>>(frames, Xh, TOKh);
    k_hgemm<2><<<dim3(124, 2, 1), 512, 0, stream>>>(
        QHATh, 512, TOKh, 512, nullptr, DOTSh, 15872, 256, 15872, 512);
    k_sim_h<<<256, 256, 0, stream>>>(DOTSh, out);
}

// Round 12
// 609.842 us; speedup vs baseline: 1.6637x; 1.0301x over previous
//
#include <hip/hip_runtime.h>
#include <math.h>

#define DM 512
#define NTOK_V 62

typedef _Float16 h16;
typedef __attribute__((ext_vector_type(8))) _Float16 h16x8;
typedef __attribute__((ext_vector_type(4))) float f32x4;

__device__ __forceinline__ void ldsload16(const void* g, void* l) {
    __builtin_amdgcn_global_load_lds(
        (const __attribute__((address_space(1))) unsigned int*)g,
        (__attribute__((address_space(3))) unsigned int*)l, 16, 0, 0);
}

// XCD-chunked bijective blockIdx swizzle (T1; requires nwg%8==0 per z-plane)
__device__ __forceinline__ void xcd_swz(int& bx, int& by) {
    const int gx = gridDim.x, gy = gridDim.y;
    const int lin = blockIdx.x + gx * blockIdx.y;
    const int cpx = (gx * gy) >> 3;
    const int wg = (lin & 7) * cpx + (lin >> 3);
    bx = wg % gx;
    by = wg / gx;
}

// ---------------------------------------------------------------- fp32 -> fp16 convert
__global__ __launch_bounds__(256) void k_cvt(const float* __restrict__ in,
                                             h16* __restrict__ outp, int n8) {
    int i = blockIdx.x * 256 + threadIdx.x;
    if (i >= n8) return;
    float4 a = ((const float4*)in)[i * 2];
    float4 b = ((const float4*)in)[i * 2 + 1];
    h16x8 h;
    h[0] = (h16)a.x; h[1] = (h16)a.y; h[2] = (h16)a.z; h[3] = (h16)a.w;
    h[4] = (h16)b.x; h[5] = (h16)b.y; h[6] = (h16)b.z; h[7] = (h16)b.w;
    ((h16x8*)outp)[i] = h;
}

// ---------------------------------------------------------------- concat -> fp16 X
__global__ __launch_bounds__(256) void k_concat_h(const float* __restrict__ frames,
                                                  const float* __restrict__ expt,
                                                  h16* __restrict__ X) {
    int row = blockIdx.x;
    int b = row >> 5, s = row & 31;
    int t = threadIdx.x;
    const float* src = (s < 30) ? (frames + ((size_t)(b * 30 + s)) * DM)
                                : (expt + (size_t)(s - 30) * DM);
    X[(size_t)row * DM + t]       = (h16)src[t];
    X[(size_t)row * DM + t + 256] = (h16)src[t + 256];
}

// ---------------------------------------------------------------- 8-phase 256x256 MFMA GEMM (R9/R10-proven)
template<int MODE>   // 0 = +bias, 1 = +bias+relu
__global__ __launch_bounds__(512, 2) void k_g8(
        const h16* __restrict__ A, int lda,
        const h16* __restrict__ B, int ldb,
        const float* __restrict__ bias,
        h16* __restrict__ C, int ldc,
        int M, int N, int Keff) {
    __shared__ char smem[131072];
    const int t = threadIdx.x;
    const int w = t >> 6, lane = t & 63;
    const int wr = w >> 2, wc = w & 3;
    const int kc = lane >> 4, rr = lane & 15;
    int bx, by;
    xcd_swz(bx, by);
    const size_t row0 = (size_t)by * 256;
    const size_t col0 = (size_t)bx * 256;

    const h16* gA = A + (row0 + (w << 4) + rr) * (size_t)lda + (kc << 3);
    const h16* gB = B + (col0 + (w << 4) + rr) * (size_t)ldb + (kc << 3);

    f32x4 acc[8][4];
#pragma unroll
    for (int m = 0; m < 8; ++m)
#pragma unroll
        for (int n = 0; n < 4; ++n) acc[m][n] = (f32x4){0.f, 0.f, 0.f, 0.f};

    const int nt = Keff >> 6;

#define SB0 __builtin_amdgcn_sched_barrier(0);
#define STG_A(bs, h, jt) { char* d_ = smem + (bs)*65536 + (h)*16384 + (w << 10) + (lane << 4); \
        const h16* s_ = gA + (size_t)((h)*128) * lda + (size_t)(jt)*64; \
        ldsload16(s_, d_); ldsload16(s_ + 32, d_ + 8192); }
#define STG_B(bs, h, jt) { char* d_ = smem + (bs)*65536 + 32768 + (h)*16384 + (w << 10) + (lane << 4); \
        const h16* s_ = gB + (size_t)((h)*128) * ldb + (size_t)(jt)*64; \
        ldsload16(s_, d_); ldsload16(s_ + 32, d_ + 8192); }
#define MFMA16(mp, AF) { \
        __builtin_amdgcn_s_setprio(1); \
        _Pragma("unroll") for (int i = 0; i < 2; ++i) \
        _Pragma("unroll") for (int n = 0; n < 4; ++n) \
        _Pragma("unroll") for (int kk = 0; kk < 2; ++kk) \
            acc[(mp)*2 + i][n] = __builtin_amdgcn_mfma_f32_16x16x32_f16(AF[i][kk], bf[n][kk], acc[(mp)*2 + i][n], 0, 0, 0); \
        __builtin_amdgcn_s_setprio(0); SB0 }

    STG_A(0, 0, 0) STG_A(0, 1, 0) STG_B(0, 0, 0) STG_B(0, 1, 0)

    int cur = 0;
    for (int j = 0; j < nt; ++j) {
        const int nxt = cur ^ 1;
        if (j + 1 < nt) {
            STG_A(nxt, 0, j + 1)
            asm volatile("s_waitcnt vmcnt(2)" ::: "memory");
        } else {
            asm volatile("s_waitcnt vmcnt(0)" ::: "memory");
        }
        SB0
        __builtin_amdgcn_s_barrier();
        SB0
        const char* Ab = smem + cur * 65536 + wr * 16384;
        const char* Bb = smem + cur * 65536 + 32768 + (wc >> 1) * 16384;
        h16x8 bf[4][2];
#pragma unroll
        for (int n = 0; n < 4; ++n)
#pragma unroll
            for (int kk = 0; kk < 2; ++kk)
                bf[n][kk] = *(const h16x8*)(Bb + kk * 8192 + (((wc & 1) << 2) + n) * 1024 + (lane << 4));
        h16x8 a0[2][2];
#pragma unroll
        for (int i = 0; i < 2; ++i)
#pragma unroll
            for (int kk = 0; kk < 2; ++kk)
                a0[i][kk] = *(const h16x8*)(Ab + kk * 8192 + (0 + i) * 1024 + (lane << 4));
        asm volatile("s_waitcnt lgkmcnt(0)" ::: "memory");
        SB0
        MFMA16(0, a0)
        h16x8 a1[2][2];
#pragma unroll
        for (int i = 0; i < 2; ++i)
#pragma unroll
            for (int kk = 0; kk < 2; ++kk)
                a1[i][kk] = *(const h16x8*)(Ab + kk * 8192 + (2 + i) * 1024 + (lane << 4));
        if (j + 1 < nt) STG_A(nxt, 1, j + 1)
        asm volatile("s_waitcnt lgkmcnt(0)" ::: "memory");
        SB0
        __builtin_amdgcn_s_barrier();
        SB0
        MFMA16(1, a1)
        h16x8 a2[2][2];
#pragma unroll
        for (int i = 0; i < 2; ++i)
#pragma unroll
            for (int kk = 0; kk < 2; ++kk)
                a2[i][kk] = *(const h16x8*)(Ab + kk * 8192 + (4 + i) * 1024 + (lane << 4));
        if (j + 1 < nt) STG_B(nxt, 0, j + 1)
        asm volatile("s_waitcnt lgkmcnt(0)" ::: "memory");
        SB0
        __builtin_amdgcn_s_barrier();
        SB0
        MFMA16(2, a2)
        h16x8 a3[2][2];
#pragma unroll
        for (int i = 0; i < 2; ++i)
#pragma unroll
            for (int kk = 0; kk < 2; ++kk)
                a3[i][kk] = *(const h16x8*)(Ab + kk * 8192 + (6 + i) * 1024 + (lane << 4));
        if (j + 1 < nt) STG_B(nxt, 1, j + 1)
        asm volatile("s_waitcnt lgkmcnt(0)" ::: "memory");
        SB0
        __builtin_amdgcn_s_barrier();
        SB0
        MFMA16(3, a3)
        cur = nxt;
    }
#undef MFMA16
#undef STG_A
#undef STG_B
#undef SB0

    float bv[4];
#pragma unroll
    for (int n = 0; n < 4; ++n)
        bv[n] = bias ? bias[col0 + (wc << 6) + n * 16 + rr] : 0.f;
#pragma unroll
    for (int m = 0; m < 8; ++m) {
        size_t rbase = row0 + (wr << 7) + m * 16 + (kc << 2);
#pragma unroll
        for (int jj = 0; jj < 4; ++jj) {
            h16* rowp = C + (rbase + jj) * (size_t)ldc + col0 + (wc << 6) + rr;
#pragma unroll
            for (int n = 0; n < 4; ++n) {
                float v = acc[m][n][jj] + bv[n];
                if (MODE == 1) v = fmaxf(v, 0.f);
                rowp[n * 16] = (h16)v;
            }
        }
    }
}

// ---------------------------------------------------------------- 4-phase 256x128 split-K GEMM (R12)
// Same schedule family as k_g8 (BK=64, double-buffer, counted vmcnt(2) at tile
// boundary, lgkmcnt(0)+barrier phases) but BN=128 so N=512 grids reach 256
// blocks with split-K=2. 8 waves 4Mx2N, wave = 64x64 (acc 4x4). 3 staging
// chunks/tile (A-half, A-half, B) of 2 loads/thread -> boundary vmcnt(2)
// retires exactly the current tile's 6 older loads. Partial out at z*M*N.
__global__ __launch_bounds__(512, 2) void k_g8n(
        const h16* __restrict__ A, int lda,
        const h16* __restrict__ B, int ldb,
        h16* __restrict__ C, int ldc,
        int M, int N, int Keff) {
    __shared__ char smem[98304];               // 2 bufs x (A 2x16KB + B 16KB)
    const int t = threadIdx.x;
    const int w = t >> 6, lane = t & 63;
    const int wr = w >> 1, wc = w & 1;         // wave grid 4 x 2
    const int kc = lane >> 4, rr = lane & 15;
    int bx, by;
    xcd_swz(bx, by);
    const size_t row0 = (size_t)by * 256;
    const size_t col0 = (size_t)bx * 128;
    const int z = blockIdx.z;

    const h16* gA = A + (size_t)z * Keff + (row0 + (w << 4) + rr) * (size_t)lda + (kc << 3);
    const h16* gB = B + (size_t)z * Keff + (col0 + (w << 4) + rr) * (size_t)ldb + (kc << 3);
    h16* Cz = C + (size_t)z * (size_t)M * N;

    f32x4 acc[4][4];
#pragma unroll
    for (int m = 0; m < 4; ++m)
#pragma unroll
        for (int n = 0; n < 4; ++n) acc[m][n] = (f32x4){0.f, 0.f, 0.f, 0.f};

    const int nt = Keff >> 6;                  // K-tiles (16 for Keff=1024)

#define SB0 __builtin_amdgcn_sched_barrier(0);
#define STG_A(bs, h, jt) { char* d_ = smem + (bs)*49152 + (h)*16384 + (w << 10) + (lane << 4); \
        const h16* s_ = gA + (size_t)((h)*128) * lda + (size_t)(jt)*64; \
        ldsload16(s_, d_); ldsload16(s_ + 32, d_ + 8192); }
#define STG_B(bs, jt) { char* d_ = smem + (bs)*49152 + 32768 + (w << 10) + (lane << 4); \
        const h16* s_ = gB + (size_t)(jt)*64; \
        ldsload16(s_, d_); ldsload16(s_ + 32, d_ + 8192); }
#define MFMA8(mp, AF) { \
        __builtin_amdgcn_s_setprio(1); \
        _Pragma("unroll") for (int n = 0; n < 4; ++n) \
        _Pragma("unroll") for (int kk = 0; kk < 2; ++kk) \
            acc[mp][n] = __builtin_amdgcn_mfma_f32_16x16x32_f16(AF[kk], bf[n][kk], acc[mp][n], 0, 0, 0); \
        __builtin_amdgcn_s_setprio(0); SB0 }
#define LDA_FRAG(dst, mp) { int g_ = (wr << 2) + (mp); \
        const char* p_ = smem + cur * 49152 + ((g_ >> 3) << 14) + ((g_ & 7) << 10) + (lane << 4); \
        _Pragma("unroll") for (int kk = 0; kk < 2; ++kk) \
            dst[kk] = *(const h16x8*)(p_ + kk * 8192); }

    STG_A(0, 0, 0) STG_A(0, 1, 0) STG_B(0, 0)

    int cur = 0;
    for (int j = 0; j < nt; ++j) {
        const int nxt = cur ^ 1;
        // ---- phase 0 (tile boundary)
        if (j + 1 < nt) {
            STG_A(nxt, 0, j + 1)
            asm volatile("s_waitcnt vmcnt(2)" ::: "memory");
        } else {
            asm volatile("s_waitcnt vmcnt(0)" ::: "memory");
        }
        SB0
        __builtin_amdgcn_s_barrier();
        SB0
        const char* Bb = smem + cur * 49152 + 32768;
        h16x8 bf[4][2];
#pragma unroll
        for (int n = 0; n < 4; ++n)
#pragma unroll
            for (int kk = 0; kk < 2; ++kk)
                bf[n][kk] = *(const h16x8*)(Bb + kk * 8192 + (((wc << 2) + n) << 10) + (lane << 4));
        h16x8 a0[2];
        LDA_FRAG(a0, 0)
        asm volatile("s_waitcnt lgkmcnt(0)" ::: "memory");
        SB0
        MFMA8(0, a0)
        // ---- phase 1
        h16x8 a1[2];
        LDA_FRAG(a1, 1)
        if (j + 1 < nt) STG_A(nxt, 1, j + 1)
        asm volatile("s_waitcnt lgkmcnt(0)" ::: "memory");
        SB0
        __builtin_amdgcn_s_barrier();
        SB0
        MFMA8(1, a1)
        // ---- phase 2
        h16x8 a2[2];
        LDA_FRAG(a2, 2)
        if (j + 1 < nt) STG_B(nxt, j + 1)
        asm volatile("s_waitcnt lgkmcnt(0)" ::: "memory");
        SB0
        __builtin_amdgcn_s_barrier();
        SB0
        MFMA8(2, a2)
        // ---- phase 3
        h16x8 a3[2];
        LDA_FRAG(a3, 3)
        asm volatile("s_waitcnt lgkmcnt(0)" ::: "memory");
        SB0
        __builtin_amdgcn_s_barrier();
        SB0
        MFMA8(3, a3)
        cur = nxt;
    }
#undef LDA_FRAG
#undef MFMA8
#undef STG_A
#undef STG_B
#undef SB0

    // line-coherent epilogue (R9 pattern)
#pragma unroll
    for (int m = 0; m < 4; ++m) {
        size_t rbase = row0 + (wr << 6) + m * 16 + (kc << 2);
#pragma unroll
        for (int jj = 0; jj < 4; ++jj) {
            h16* rowp = Cz + (rbase + jj) * (size_t)ldc + col0 + (wc << 6) + rr;
#pragma unroll
            for (int n = 0; n < 4; ++n)
                rowp[n * 16] = (h16)acc[m][n][jj];
        }
    }
}

// ---------------------------------------------------------------- 128x128 2-phase GEMM (R7-proven; DOTS)
template<int MODE>   // 2 = plain
__global__ __launch_bounds__(512, 4) void k_hgemm(
        const h16* __restrict__ A, int lda,
        const h16* __restrict__ B, int ldb,
        const float* __restrict__ bias,
        h16* __restrict__ C, int ldc,
        int M, int N, int Keff) {
    __shared__ char smem[49152];
    const int t = threadIdx.x;
    const int w = t >> 6, lane = t & 63;
    const int wr = w >> 2, wc = w & 3;
    const int kc = lane >> 4, rr = lane & 15;
    int bx, by;
    xcd_swz(bx, by);
    const size_t row0 = (size_t)by * 128;
    const size_t col0 = (size_t)bx * 128;

    const h16* gA = A + (row0 + (w << 4) + rr) * (size_t)lda + (kc << 3);
    const h16* gB = B + (col0 + (w << 4) + rr) * (size_t)ldb + (kc << 3);

    f32x4 acc[4][2];
#pragma unroll
    for (int m = 0; m < 4; ++m)
#pragma unroll
        for (int n = 0; n < 2; ++n) acc[m][n] = (f32x4){0.f, 0.f, 0.f, 0.f};

    const int nt = Keff >> 5;

#define SB0 __builtin_amdgcn_sched_barrier(0);
#define STAGE(step, slot) { char* sA_ = smem + ((slot) << 14) + (w << 10); \
        ldsload16(gA + (size_t)(step) * 32, sA_); \
        ldsload16(gB + (size_t)(step) * 32, sA_ + 8192); }
#define KSTEP(WAITLIT, slotR, DOSTAGE, stepW, slotW) { \
        asm volatile("s_waitcnt vmcnt(" WAITLIT ")" ::: "memory"); \
        SB0 \
        __builtin_amdgcn_s_barrier(); \
        SB0 \
        const char* bA = smem + ((slotR) << 14); \
        const char* bB = bA + 8192; \
        h16x8 af[4], bf[2]; \
        _Pragma("unroll") for (int m = 0; m < 4; ++m) \
            af[m] = *(const h16x8*)(bA + ((wr << 2) + m) * 1024 + lane * 16); \
        _Pragma("unroll") for (int n = 0; n < 2; ++n) \
            bf[n] = *(const h16x8*)(bB + ((wc << 1) + n) * 1024 + lane * 16); \
        asm volatile("s_waitcnt lgkmcnt(0)" ::: "memory"); \
        SB0 \
        if (DOSTAGE) STAGE(stepW, slotW) \
        __builtin_amdgcn_s_setprio(1); \
        _Pragma("unroll") for (int m = 0; m < 4; ++m) \
        _Pragma("unroll") for (int n = 0; n < 2; ++n) \
            acc[m][n] = __builtin_amdgcn_mfma_f32_16x16x32_f16(af[m], bf[n], acc[m][n], 0, 0, 0); \
        __builtin_amdgcn_s_setprio(0); \
        SB0 }

    STAGE(0, 0) STAGE(1, 1)
    int slotR = 0, slotW = 2;
    int it = 0;
    for (; it < nt - 2; ++it) {
        KSTEP("2", slotR, 1, it + 2, slotW)
        slotR = (slotR == 2) ? 0 : slotR + 1;
        slotW = (slotW == 2) ? 0 : slotW + 1;
    }
    KSTEP("2", slotR, 0, 0, 0)
    slotR = (slotR == 2) ? 0 : slotR + 1;
    KSTEP("0", slotR, 0, 0, 0)
#undef KSTEP
#undef STAGE
#undef SB0

#pragma unroll
    for (int n = 0; n < 2; ++n) {
        size_t col = col0 + (wc << 5) + n * 16 + rr;
#pragma unroll
        for (int m = 0; m < 4; ++m) {
            size_t rbase = row0 + (wr << 6) + m * 16 + (kc << 2);
#pragma unroll
            for (int j = 0; j < 4; ++j)
                C[(rbase + j) * (size_t)ldc + col] = (h16)acc[m][n][j];
        }
    }
}

// ---------------------------------------------------------------- fused O-proj + residual + LN (R11-proven)
__global__ __launch_bounds__(512, 2) void k_attproj(
        const h16* __restrict__ ATT,
        const h16* __restrict__ Bw,
        const float* __restrict__ bo,
        h16* __restrict__ X,
        const float* __restrict__ lw,
        const float* __restrict__ lb) {
    __shared__ char smem[131072];
    const int t = threadIdx.x;
    const int w = t >> 6, lane = t & 63;
    const int kc = lane >> 4, rr = lane & 15;
    const size_t row0 = (size_t)blockIdx.x * 32;
    const h16* Ain = ATT + row0 * DM;

    f32x4 acc[2][4];
#pragma unroll
    for (int m = 0; m < 2; ++m)
#pragma unroll
        for (int n = 0; n < 4; ++n) acc[m][n] = (f32x4){0.f, 0.f, 0.f, 0.f};

#define SB0 __builtin_amdgcn_sched_barrier(0);
#define STGB(js, sl) { _Pragma("unroll") for (int u = 0; u < 4; ++u) { \
        const h16* s_ = Bw + (size_t)((((u << 3) + w) << 4) + rr) * DM + (js) * 32 + (kc << 3); \
        ldsload16(s_, smem + 32768 + (sl) * 32768 + ((((u << 3) + w) << 10)) + (lane << 4)); } }

#pragma unroll
    for (int u = 0; u < 4; ++u) {
        int sidx = (u << 2) + (w >> 1);
        const h16* s_ = Ain + (size_t)(((w & 1) << 4) + rr) * DM + sidx * 32 + (kc << 3);
        ldsload16(s_, smem + (sidx << 11) + ((w & 1) << 10) + (lane << 4));
    }
    STGB(0, 0) STGB(1, 1)

    int slotR = 0, slotW = 2;
    for (int s = 0; s < 15; ++s) {
        asm volatile("s_waitcnt vmcnt(4)" ::: "memory");
        SB0
        __builtin_amdgcn_s_barrier();
        SB0
        h16x8 af[2], bf[4];
#pragma unroll
        for (int m = 0; m < 2; ++m)
            af[m] = *(const h16x8*)(smem + (s << 11) + (m << 10) + (lane << 4));
#pragma unroll
        for (int n = 0; n < 4; ++n)
            bf[n] = *(const h16x8*)(smem + 32768 + slotR * 32768 + (((w << 2) + n) << 10) + (lane << 4));
        asm volatile("s_waitcnt lgkmcnt(0)" ::: "memory");
        SB0
        if (s + 2 < 16) STGB(s + 2, slotW)
        __builtin_amdgcn_s_setprio(1);
#pragma unroll
        for (int m = 0; m < 2; ++m)
#pragma unroll
            for (int n = 0; n < 4; ++n)
                acc[m][n] = __builtin_amdgcn_mfma_f32_16x16x32_f16(af[m], bf[n], acc[m][n], 0, 0, 0);
        __builtin_amdgcn_s_setprio(0);
        SB0
        slotR = (slotR == 2) ? 0 : slotR + 1;
        slotW = (slotW == 2) ? 0 : slotW + 1;
    }
    {
        asm volatile("s_waitcnt vmcnt(0)" ::: "memory");
        SB0
        __builtin_amdgcn_s_barrier();
        SB0
        h16x8 af[2], bf[4];
#pragma unroll
        for (int m = 0; m < 2; ++m)
            af[m] = *(const h16x8*)(smem + (15 << 11) + (m << 10) + (lane << 4));
#pragma unroll
        for (int n = 0; n < 4; ++n)
            bf[n] = *(const h16x8*)(smem + 32768 + slotR * 32768 + (((w << 2) + n) << 10) + (lane << 4));
        asm volatile("s_waitcnt lgkmcnt(0)" ::: "memory");
        SB0
#pragma unroll
        for (int m = 0; m < 2; ++m)
#pragma unroll
            for (int n = 0; n < 4; ++n)
                acc[m][n] = __builtin_amdgcn_mfma_f32_16x16x32_f16(af[m], bf[n], acc[m][n], 0, 0, 0);
    }
#undef STGB
#undef SB0
    __syncthreads();

    float* outl = (float*)smem;
    float bv[4];
#pragma unroll
    for (int n = 0; n < 4; ++n)
        bv[n] = bo[(w << 6) + n * 16 + rr];
#pragma unroll
    for (int m = 0; m < 2; ++m)
#pragma unroll
        for (int n = 0; n < 4; ++n)
#pragma unroll
            for (int j = 0; j < 4; ++j) {
                int r = m * 16 + (lane >> 4) * 4 + j;
                int c = (w << 6) + n * 16 + rr;
                outl[r * 516 + c] = acc[m][n][j] + bv[n];
            }
    __syncthreads();

    {
        const int r = t >> 4, l = t & 15;
        const size_t grow = (row0 + r) * (size_t)DM;
        float v[32];
        float sum = 0.f, sq = 0.f;
#pragma unroll
        for (int i = 0; i < 32; ++i) {
            int col = l + (i << 4);
            float vv = outl[r * 516 + col] + (float)X[grow + col];
            v[i] = vv;
            sum += vv;
            sq += vv * vv;
        }
#pragma unroll
        for (int o = 8; o; o >>= 1) {
            sum += __shfl_xor(sum, o);
            sq  += __shfl_xor(sq, o);
        }
        float mean = sum * (1.f / 512.f);
        float var = sq * (1.f / 512.f) - mean * mean;
        float inv = 1.f / sqrtf(var + 1e-5f);
#pragma unroll
        for (int i = 0; i < 32; ++i) {
            int col = l + (i << 4);
            X[grow + col] = (h16)((v[i] - mean) * inv * lw[col] + lb[col]);
        }
    }
}

// ---------------------------------------------------------------- attention, one block per (b,h)
__global__ __launch_bounds__(256) void k_attn_h(const h16* __restrict__ qkv,
                                                h16* __restrict__ att) {
    __shared__ float q[32][65], k[32][65], v[32][65];
    __shared__ float sc[32][33];
    int b = blockIdx.x >> 3, h = blockIdx.x & 7;
    int t = threadIdx.x;
    const h16* base = qkv + (size_t)b * 32 * 1536 + h * 64;
    for (int i = t; i < 2048; i += 256) {
        int s = i >> 6, d = i & 63;
        size_t ro = (size_t)s * 1536 + d;
        q[s][d] = (float)base[ro];
        k[s][d] = (float)base[ro + 512];
        v[s][d] = (float)base[ro + 1024];
    }
    __syncthreads();
    {
        int r = t >> 3, c0 = (t & 7) << 2;
        float s0 = 0.f, s1 = 0.f, s2 = 0.f, s3 = 0.f;
#pragma unroll 8
        for (int d = 0; d < 64; ++d) {
            float qv = q[r][d];
            s0 += qv * k[c0 + 0][d];
            s1 += qv * k[c0 + 1][d];
            s2 += qv * k[c0 + 2][d];
            s3 += qv * k[c0 + 3][d];
        }
        sc[r][c0 + 0] = s0 * 0.125f;
        sc[r][c0 + 1] = s1 * 0.125f;
        sc[r][c0 + 2] = s2 * 0.125f;
        sc[r][c0 + 3] = s3 * 0.125f;
    }
    __syncthreads();
    {
        int r = t >> 3, c0 = (t & 7) << 2;
        float a0 = sc[r][c0], a1 = sc[r][c0 + 1], a2 = sc[r][c0 + 2], a3 = sc[r][c0 + 3];
        float mx = fmaxf(fmaxf(a0, a1), fmaxf(a2, a3));
        mx = fmaxf(mx, __shfl_xor(mx, 1));
        mx = fmaxf(mx, __shfl_xor(mx, 2));
        mx = fmaxf(mx, __shfl_xor(mx, 4));
        float e0 = expf(a0 - mx), e1 = expf(a1 - mx), e2 = expf(a2 - mx), e3 = expf(a3 - mx);
        float sm = e0 + e1 + e2 + e3;
        sm += __shfl_xor(sm, 1);
        sm += __shfl_xor(sm, 2);
        sm += __shfl_xor(sm, 4);
        float inv = 1.f / sm;
        sc[r][c0] = e0 * inv; sc[r][c0 + 1] = e1 * inv; sc[r][c0 + 2] = e2 * inv; sc[r][c0 + 3] = e3 * inv;
    }
    __syncthreads();
    for (int i = t; i < 2048; i += 256) {
        int s = i >> 6, d = i & 63;
        float acc = 0.f;
#pragma unroll 8
        for (int c = 0; c < 32; ++c) acc += sc[s][c] * v[c][d];
        att[((size_t)b * 32 + s) * DM + h * 64 + d] = (h16)acc;
    }
}

// ---------------------------------------------------------------- x = LN(x + p0 + p1 + bias)*w + b
__global__ __launch_bounds__(256) void k_addln_red(h16* __restrict__ x,
                                                   const h16* __restrict__ p0,
                                                   const h16* __restrict__ p1,
                                                   const float* __restrict__ bias,
                                                   const float* __restrict__ w,
                                                   const float* __restrict__ b) {
    size_t row = blockIdx.x;
    int t = threadIdx.x;
    size_t o0 = row * DM + t, o1 = o0 + 256;
    float v0 = (float)x[o0] + (float)p0[o0] + (float)p1[o0] + bias[t];
    float v1 = (float)x[o1] + (float)p0[o1] + (float)p1[o1] + bias[t + 256];
    float s = v0 + v1;
#pragma unroll
    for (int o = 32; o; o >>= 1) s += __shfl_xor(s, o);
    __shared__ float ss[4], qs[4];
    if ((t & 63) == 0) ss[t >> 6] = s;
    __syncthreads();
    float mean = (ss[0] + ss[1] + ss[2] + ss[3]) * (1.f / 512.f);
    float d0 = v0 - mean, d1 = v1 - mean;
    float qv = d0 * d0 + d1 * d1;
#pragma unroll
    for (int o = 32; o; o >>= 1) qv += __shfl_xor(qv, o);
    if ((t & 63) == 0) qs[t >> 6] = qv;
    __syncthreads();
    float var = (qs[0] + qs[1] + qs[2] + qs[3]) * (1.f / 512.f);
    float inv = 1.f / sqrtf(var + 1e-5f);
    x[o0] = (h16)(d0 * inv * w[t] + b[t]);
    x[o1] = (h16)(d1 * inv * w[t + 256] + b[t + 256]);
}

// ---------------------------------------------------------------- l2 rows: f32 in -> f16 out
__global__ __launch_bounds__(256) void k_l2rows_h(const float* __restrict__ in,
                                                  h16* __restrict__ outp) {
    size_t row = blockIdx.x;
    int t = threadIdx.x;
    float v0 = in[row * DM + t], v1 = in[row * DM + t + 256];
    float q = v0 * v0 + v1 * v1;
#pragma unroll
    for (int o = 32; o; o >>= 1) q += __shfl_xor(q, o);
    __shared__ float qs[4];
    if ((t & 63) == 0) qs[t >> 6] = q;
    __syncthreads();
    float n = sqrtf(qs[0] + qs[1] + qs[2] + qs[3]);
    float sc = 1.f / fmaxf(n, 1e-12f);
    outp[row * DM + t]       = (h16)(v0 * sc);
    outp[row * DM + t + 256] = (h16)(v1 * sc);
}

// ---------------------------------------------------------------- TOK rows (l2'd frames + video tokens)
__global__ __launch_bounds__(256) void k_build_tok_h(const float* __restrict__ frames,
                                                     const h16* __restrict__ X,
                                                     h16* __restrict__ TOK) {
    int rid = blockIdx.x;
    int j = rid / NTOK_V, tt = rid % NTOK_V;
    int t = threadIdx.x;
    float v0, v1;
    if (tt < 30) {
        const float* src = frames + ((size_t)j * 30 + tt) * DM;
        v0 = src[t]; v1 = src[t + 256];
    } else {
        const h16* src = X + ((size_t)j * 32 + (tt - 30)) * DM;
        v0 = (float)src[t]; v1 = (float)src[t + 256];
    }
    float q = v0 * v0 + v1 * v1;
#pragma unroll
    for (int o = 32; o; o >>= 1) q += __shfl_xor(q, o);
    __shared__ float qs[4];
    if ((t & 63) == 0) qs[t >> 6] = q;
    __syncthreads();
    float n = sqrtf(qs[0] + qs[1] + qs[2] + qs[3]);
    float sc = 1.f / fmaxf(n, 1e-12f);
    TOK[(size_t)rid * DM + t]       = (h16)(v0 * sc);
    TOK[(size_t)rid * DM + t + 256] = (h16)(v1 * sc);
}

// ---------------------------------------------------------------- max-reduce dots -> sims
__global__ __launch_bounds__(256) void k_sim_h(const h16* __restrict__ dots,
                                               float* __restrict__ out) {
    int i = blockIdx.x;
    int j = threadIdx.x;
    const h16* p = dots + (size_t)i * 15872 + (size_t)j * NTOK_V;
    float mf = -1e30f, mv = -1e30f;
#pragma unroll
    for (int tt = 0; tt < 30; ++tt) mf = fmaxf(mf, (float)p[tt]);
#pragma unroll
    for (int tt = 30; tt < 62; ++tt) mv = fmaxf(mv, (float)p[tt]);
    int o = i * 256 + j;
    out[o]          = mf + mv;
    out[65536 + o]  = mf;
    out[131072 + o] = mv;
}

// ---------------------------------------------------------------- launcher
extern "C" void kernel_launch(void* const* d_in, const int* in_sizes, int n_in,
                              void* d_out, int out_size, void* d_ws, size_t ws_size,
                              hipStream_t stream) {
    const float* text   = (const float*)d_in[0];
    const float* frames = (const float*)d_in[1];
    const float* expt   = (const float*)d_in[2];
    const float* Wqkv   = (const float*)d_in[3];
    const float* bqkv   = (const float*)d_in[4];
    const float* Wo     = (const float*)d_in[5];
    const float* bo     = (const float*)d_in[6];
    const float* ln1w   = (const float*)d_in[7];
    const float* ln1b   = (const float*)d_in[8];
    const float* W1     = (const float*)d_in[9];
    const float* b1     = (const float*)d_in[10];
    const float* W2     = (const float*)d_in[11];
    const float* b2     = (const float*)d_in[12];
    const float* ln2w   = (const float*)d_in[13];
    const float* ln2b   = (const float*)d_in[14];
    float* out = (float*)d_out;

    char* wsb = (char*)d_ws;
    const size_t MB = 1024 * 1024;
    h16* Xh    = (h16*)(wsb);              // 8 MB   [8192,512]
    h16* P0    = (h16*)(wsb + 8 * MB);     // 8 MB   split-K partial 0 (FF2)
    h16* P1    = (h16*)(wsb + 16 * MB);    // 8 MB   split-K partial 1
    h16* ATTh  = (h16*)(wsb + 24 * MB);    // 8 MB   [8192,512]
    h16* FFh   = (h16*)(wsb + 32 * MB);    // 32 MB  [8192,2048] (also QKV [8192,1536])
    h16* TOKh  = (h16*)(wsb + 32 * MB);    // alias FF (post-transformer)
    h16* DOTSh = (h16*)(wsb + 48 * MB);    // alias FF tail
    h16* Wh    = (h16*)(wsb + 64 * MB);    // 25 MB  all weights fp16
    h16* QHATh = (h16*)(wsb + 90 * MB);    // 0.25 MB

    h16* Whqkv = Wh;                       // 4*1536*512
    h16* Who   = Whqkv + 3145728;          // 4*512*512
    h16* Wh1   = Who + 1048576;            // 4*2048*512
    h16* Wh2   = Wh1 + 4194304;            // 4*2048*512

    k_cvt<<<1536, 256, 0, stream>>>(Wqkv, Whqkv, 393216);
    k_cvt<<<512,  256, 0, stream>>>(Wo,   Who,   131072);
    k_cvt<<<2048, 256, 0, stream>>>(W1,   Wh1,   524288);
    k_cvt<<<2048, 256, 0, stream>>>(W2,   Wh2,   524288);
    k_concat_h<<<8192, 256, 0, stream>>>(frames, expt, Xh);

    for (int l = 0; l < 4; ++l) {
        const h16* Wqkv_l = Whqkv + (size_t)l * 786432;
        const h16* Wo_l   = Who   + (size_t)l * 262144;
        const h16* W1_l   = Wh1   + (size_t)l * 1048576;
        const h16* W2_l   = Wh2   + (size_t)l * 1048576;

        k_g8<0><<<dim3(6, 32, 1), 512, 0, stream>>>(
            Xh, 512, Wqkv_l, 512, bqkv + (size_t)l * 1536, FFh, 1536, 8192, 1536, 512);
        k_attn_h<<<2048, 256, 0, stream>>>(FFh, ATTh);
        k_attproj<<<256, 512, 0, stream>>>(ATTh, Wo_l, bo + (size_t)l * 512, Xh,
                                           ln1w + (size_t)l * 512, ln1b + (size_t)l * 512);
        k_g8<1><<<dim3(8, 32, 1), 512, 0, stream>>>(
            Xh, 512, W1_l, 512, b1 + (size_t)l * 2048, FFh, 2048, 8192, 2048, 512);
        k_g8n<<<dim3(4, 32, 2), 512, 0, stream>>>(
            FFh, 2048, W2_l, 2048, P0, 512, 8192, 512, 1024);
        k_addln_red<<<8192, 256, 0, stream>>>(Xh, P0, P1, b2 + (size_t)l * 512,
                                              ln2w + (size_t)l * 512, ln2b + (size_t)l * 512);
    }

    k_l2rows_h<<<256, 256, 0, stream>>>(text, QHATh);
    k_build_tok_h<<<256 * NTOK_V, 256, 0, stream>>>(frames, Xh, TOKh);
    k_hgemm<2><<<dim3(124, 2, 1), 512, 0, stream>>>(
        QHATh, 512, TOKh, 512, nullptr, DOTSh, 15872, 256, 15872, 512);
    k_sim_h<<<256, 256, 0, stream>>>(DOTSh, out);
}

// Round 13
// 515.971 us; speedup vs baseline: 1.9663x; 1.1819x over previous
//
#include <hip/hip_runtime.h>
#include <math.h>

#define DM 512
#define NTOK_V 62

typedef _Float16 h16;
typedef __attribute__((ext_vector_type(8))) _Float16 h16x8;
typedef __attribute__((ext_vector_type(4))) float f32x4;

__device__ __forceinline__ void ldsload16(const void* g, void* l) {
    __builtin_amdgcn_global_load_lds(
        (const __attribute__((address_space(1))) unsigned int*)g,
        (__attribute__((address_space(3))) unsigned int*)l, 16, 0, 0);
}

// XCD-chunked bijective blockIdx swizzle (T1; requires nwg%8==0 per z-plane)
__device__ __forceinline__ void xcd_swz(int& bx, int& by) {
    const int gx = gridDim.x, gy = gridDim.y;
    const int lin = blockIdx.x + gx * blockIdx.y;
    const int cpx = (gx * gy) >> 3;
    const int wg = (lin & 7) * cpx + (lin >> 3);
    bx = wg % gx;
    by = wg / gx;
}

// ---------------------------------------------------------------- fp32 -> fp16 convert
__global__ __launch_bounds__(256) void k_cvt(const float* __restrict__ in,
                                             h16* __restrict__ outp, int n8) {
    int i = blockIdx.x * 256 + threadIdx.x;
    if (i >= n8) return;
    float4 a = ((const float4*)in)[i * 2];
    float4 b = ((const float4*)in)[i * 2 + 1];
    h16x8 h;
    h[0] = (h16)a.x; h[1] = (h16)a.y; h[2] = (h16)a.z; h[3] = (h16)a.w;
    h[4] = (h16)b.x; h[5] = (h16)b.y; h[6] = (h16)b.z; h[7] = (h16)b.w;
    ((h16x8*)outp)[i] = h;
}

// ---------------------------------------------------------------- concat -> fp16 X
__global__ __launch_bounds__(256) void k_concat_h(const float* __restrict__ frames,
                                                  const float* __restrict__ expt,
                                                  h16* __restrict__ X) {
    int row = blockIdx.x;
    int b = row >> 5, s = row & 31;
    int t = threadIdx.x;
    const float* src = (s < 30) ? (frames + ((size_t)(b * 30 + s)) * DM)
                                : (expt + (size_t)(s - 30) * DM);
    X[(size_t)row * DM + t]       = (h16)src[t];
    X[(size_t)row * DM + t + 256] = (h16)src[t + 256];
}

// ---------------------------------------------------------------- 8-phase 256x256 MFMA GEMM (R9/R10-proven)
template<int MODE>   // 0 = +bias, 1 = +bias+relu
__global__ __launch_bounds__(512, 2) void k_g8(
        const h16* __restrict__ A, int lda,
        const h16* __restrict__ B, int ldb,
        const float* __restrict__ bias,
        h16* __restrict__ C, int ldc,
        int M, int N, int Keff) {
    __shared__ char smem[131072];
    const int t = threadIdx.x;
    const int w = t >> 6, lane = t & 63;
    const int wr = w >> 2, wc = w & 3;
    const int kc = lane >> 4, rr = lane & 15;
    int bx, by;
    xcd_swz(bx, by);
    const size_t row0 = (size_t)by * 256;
    const size_t col0 = (size_t)bx * 256;

    const h16* gA = A + (row0 + (w << 4) + rr) * (size_t)lda + (kc << 3);
    const h16* gB = B + (col0 + (w << 4) + rr) * (size_t)ldb + (kc << 3);

    f32x4 acc[8][4];
#pragma unroll
    for (int m = 0; m < 8; ++m)
#pragma unroll
        for (int n = 0; n < 4; ++n) acc[m][n] = (f32x4){0.f, 0.f, 0.f, 0.f};

    const int nt = Keff >> 6;

#define SB0 __builtin_amdgcn_sched_barrier(0);
#define STG_A(bs, h, jt) { char* d_ = smem + (bs)*65536 + (h)*16384 + (w << 10) + (lane << 4); \
        const h16* s_ = gA + (size_t)((h)*128) * lda + (size_t)(jt)*64; \
        ldsload16(s_, d_); ldsload16(s_ + 32, d_ + 8192); }
#define STG_B(bs, h, jt) { char* d_ = smem + (bs)*65536 + 32768 + (h)*16384 + (w << 10) + (lane << 4); \
        const h16* s_ = gB + (size_t)((h)*128) * ldb + (size_t)(jt)*64; \
        ldsload16(s_, d_); ldsload16(s_ + 32, d_ + 8192); }
#define MFMA16(mp, AF) { \
        __builtin_amdgcn_s_setprio(1); \
        _Pragma("unroll") for (int i = 0; i < 2; ++i) \
        _Pragma("unroll") for (int n = 0; n < 4; ++n) \
        _Pragma("unroll") for (int kk = 0; kk < 2; ++kk) \
            acc[(mp)*2 + i][n] = __builtin_amdgcn_mfma_f32_16x16x32_f16(AF[i][kk], bf[n][kk], acc[(mp)*2 + i][n], 0, 0, 0); \
        __builtin_amdgcn_s_setprio(0); SB0 }

    STG_A(0, 0, 0) STG_A(0, 1, 0) STG_B(0, 0, 0) STG_B(0, 1, 0)

    int cur = 0;
    for (int j = 0; j < nt; ++j) {
        const int nxt = cur ^ 1;
        if (j + 1 < nt) {
            STG_A(nxt, 0, j + 1)
            asm volatile("s_waitcnt vmcnt(2)" ::: "memory");
        } else {
            asm volatile("s_waitcnt vmcnt(0)" ::: "memory");
        }
        SB0
        __builtin_amdgcn_s_barrier();
        SB0
        const char* Ab = smem + cur * 65536 + wr * 16384;
        const char* Bb = smem + cur * 65536 + 32768 + (wc >> 1) * 16384;
        h16x8 bf[4][2];
#pragma unroll
        for (int n = 0; n < 4; ++n)
#pragma unroll
            for (int kk = 0; kk < 2; ++kk)
                bf[n][kk] = *(const h16x8*)(Bb + kk * 8192 + (((wc & 1) << 2) + n) * 1024 + (lane << 4));
        h16x8 a0[2][2];
#pragma unroll
        for (int i = 0; i < 2; ++i)
#pragma unroll
            for (int kk = 0; kk < 2; ++kk)
                a0[i][kk] = *(const h16x8*)(Ab + kk * 8192 + (0 + i) * 1024 + (lane << 4));
        asm volatile("s_waitcnt lgkmcnt(0)" ::: "memory");
        SB0
        MFMA16(0, a0)
        h16x8 a1[2][2];
#pragma unroll
        for (int i = 0; i < 2; ++i)
#pragma unroll
            for (int kk = 0; kk < 2; ++kk)
                a1[i][kk] = *(const h16x8*)(Ab + kk * 8192 + (2 + i) * 1024 + (lane << 4));
        if (j + 1 < nt) STG_A(nxt, 1, j + 1)
        asm volatile("s_waitcnt lgkmcnt(0)" ::: "memory");
        SB0
        __builtin_amdgcn_s_barrier();
        SB0
        MFMA16(1, a1)
        h16x8 a2[2][2];
#pragma unroll
        for (int i = 0; i < 2; ++i)
#pragma unroll
            for (int kk = 0; kk < 2; ++kk)
                a2[i][kk] = *(const h16x8*)(Ab + kk * 8192 + (4 + i) * 1024 + (lane << 4));
        if (j + 1 < nt) STG_B(nxt, 0, j + 1)
        asm volatile("s_waitcnt lgkmcnt(0)" ::: "memory");
        SB0
        __builtin_amdgcn_s_barrier();
        SB0
        MFMA16(2, a2)
        h16x8 a3[2][2];
#pragma unroll
        for (int i = 0; i < 2; ++i)
#pragma unroll
            for (int kk = 0; kk < 2; ++kk)
                a3[i][kk] = *(const h16x8*)(Ab + kk * 8192 + (6 + i) * 1024 + (lane << 4));
        if (j + 1 < nt) STG_B(nxt, 1, j + 1)
        asm volatile("s_waitcnt lgkmcnt(0)" ::: "memory");
        SB0
        __builtin_amdgcn_s_barrier();
        SB0
        MFMA16(3, a3)
        cur = nxt;
    }
#undef MFMA16
#undef STG_A
#undef STG_B
#undef SB0

    float bv[4];
#pragma unroll
    for (int n = 0; n < 4; ++n)
        bv[n] = bias ? bias[col0 + (wc << 6) + n * 16 + rr] : 0.f;
#pragma unroll
    for (int m = 0; m < 8; ++m) {
        size_t rbase = row0 + (wr << 7) + m * 16 + (kc << 2);
#pragma unroll
        for (int jj = 0; jj < 4; ++jj) {
            h16* rowp = C + (rbase + jj) * (size_t)ldc + col0 + (wc << 6) + rr;
#pragma unroll
            for (int n = 0; n < 4; ++n) {
                float v = acc[m][n][jj] + bv[n];
                if (MODE == 1) v = fmaxf(v, 0.f);
                rowp[n * 16] = (h16)v;
            }
        }
    }
}

// ---------------------------------------------------------------- 4-phase 256x128 split-K GEMM (R12-proven)
__global__ __launch_bounds__(512, 2) void k_g8n(
        const h16* __restrict__ A, int lda,
        const h16* __restrict__ B, int ldb,
        h16* __restrict__ C, int ldc,
        int M, int N, int Keff) {
    __shared__ char smem[98304];
    const int t = threadIdx.x;
    const int w = t >> 6, lane = t & 63;
    const int wr = w >> 1, wc = w & 1;
    const int kc = lane >> 4, rr = lane & 15;
    int bx, by;
    xcd_swz(bx, by);
    const size_t row0 = (size_t)by * 256;
    const size_t col0 = (size_t)bx * 128;
    const int z = blockIdx.z;

    const h16* gA = A + (size_t)z * Keff + (row0 + (w << 4) + rr) * (size_t)lda + (kc << 3);
    const h16* gB = B + (size_t)z * Keff + (col0 + (w << 4) + rr) * (size_t)ldb + (kc << 3);
    h16* Cz = C + (size_t)z * (size_t)M * N;

    f32x4 acc[4][4];
#pragma unroll
    for (int m = 0; m < 4; ++m)
#pragma unroll
        for (int n = 0; n < 4; ++n) acc[m][n] = (f32x4){0.f, 0.f, 0.f, 0.f};

    const int nt = Keff >> 6;

#define SB0 __builtin_amdgcn_sched_barrier(0);
#define STG_A(bs, h, jt) { char* d_ = smem + (bs)*49152 + (h)*16384 + (w << 10) + (lane << 4); \
        const h16* s_ = gA + (size_t)((h)*128) * lda + (size_t)(jt)*64; \
        ldsload16(s_, d_); ldsload16(s_ + 32, d_ + 8192); }
#define STG_B(bs, jt) { char* d_ = smem + (bs)*49152 + 32768 + (w << 10) + (lane << 4); \
        const h16* s_ = gB + (size_t)(jt)*64; \
        ldsload16(s_, d_); ldsload16(s_ + 32, d_ + 8192); }
#define MFMA8(mp, AF) { \
        __builtin_amdgcn_s_setprio(1); \
        _Pragma("unroll") for (int n = 0; n < 4; ++n) \
        _Pragma("unroll") for (int kk = 0; kk < 2; ++kk) \
            acc[mp][n] = __builtin_amdgcn_mfma_f32_16x16x32_f16(AF[kk], bf[n][kk], acc[mp][n], 0, 0, 0); \
        __builtin_amdgcn_s_setprio(0); SB0 }
#define LDA_FRAG(dst, mp) { int g_ = (wr << 2) + (mp); \
        const char* p_ = smem + cur * 49152 + ((g_ >> 3) << 14) + ((g_ & 7) << 10) + (lane << 4); \
        _Pragma("unroll") for (int kk = 0; kk < 2; ++kk) \
            dst[kk] = *(const h16x8*)(p_ + kk * 8192); }

    STG_A(0, 0, 0) STG_A(0, 1, 0) STG_B(0, 0)

    int cur = 0;
    for (int j = 0; j < nt; ++j) {
        const int nxt = cur ^ 1;
        if (j + 1 < nt) {
            STG_A(nxt, 0, j + 1)
            asm volatile("s_waitcnt vmcnt(2)" ::: "memory");
        } else {
            asm volatile("s_waitcnt vmcnt(0)" ::: "memory");
        }
        SB0
        __builtin_amdgcn_s_barrier();
        SB0
        const char* Bb = smem + cur * 49152 + 32768;
        h16x8 bf[4][2];
#pragma unroll
        for (int n = 0; n < 4; ++n)
#pragma unroll
            for (int kk = 0; kk < 2; ++kk)
                bf[n][kk] = *(const h16x8*)(Bb + kk * 8192 + (((wc << 2) + n) << 10) + (lane << 4));
        h16x8 a0[2];
        LDA_FRAG(a0, 0)
        asm volatile("s_waitcnt lgkmcnt(0)" ::: "memory");
        SB0
        MFMA8(0, a0)
        h16x8 a1[2];
        LDA_FRAG(a1, 1)
        if (j + 1 < nt) STG_A(nxt, 1, j + 1)
        asm volatile("s_waitcnt lgkmcnt(0)" ::: "memory");
        SB0
        __builtin_amdgcn_s_barrier();
        SB0
        MFMA8(1, a1)
        h16x8 a2[2];
        LDA_FRAG(a2, 2)
        if (j + 1 < nt) STG_B(nxt, j + 1)
        asm volatile("s_waitcnt lgkmcnt(0)" ::: "memory");
        SB0
        __builtin_amdgcn_s_barrier();
        SB0
        MFMA8(2, a2)
        h16x8 a3[2];
        LDA_FRAG(a3, 3)
        asm volatile("s_waitcnt lgkmcnt(0)" ::: "memory");
        SB0
        __builtin_amdgcn_s_barrier();
        SB0
        MFMA8(3, a3)
        cur = nxt;
    }
#undef LDA_FRAG
#undef MFMA8
#undef STG_A
#undef STG_B
#undef SB0

#pragma unroll
    for (int m = 0; m < 4; ++m) {
        size_t rbase = row0 + (wr << 6) + m * 16 + (kc << 2);
#pragma unroll
        for (int jj = 0; jj < 4; ++jj) {
            h16* rowp = Cz + (rbase + jj) * (size_t)ldc + col0 + (wc << 6) + rr;
#pragma unroll
            for (int n = 0; n < 4; ++n)
                rowp[n * 16] = (h16)acc[m][n][jj];
        }
    }
}

// ---------------------------------------------------------------- 128x128 2-phase GEMM (R7-proven; DOTS)
template<int MODE>
__global__ __launch_bounds__(512, 4) void k_hgemm(
        const h16* __restrict__ A, int lda,
        const h16* __restrict__ B, int ldb,
        const float* __restrict__ bias,
        h16* __restrict__ C, int ldc,
        int M, int N, int Keff) {
    __shared__ char smem[49152];
    const int t = threadIdx.x;
    const int w = t >> 6, lane = t & 63;
    const int wr = w >> 2, wc = w & 3;
    const int kc = lane >> 4, rr = lane & 15;
    int bx, by;
    xcd_swz(bx, by);
    const size_t row0 = (size_t)by * 128;
    const size_t col0 = (size_t)bx * 128;

    const h16* gA = A + (row0 + (w << 4) + rr) * (size_t)lda + (kc << 3);
    const h16* gB = B + (col0 + (w << 4) + rr) * (size_t)ldb + (kc << 3);

    f32x4 acc[4][2];
#pragma unroll
    for (int m = 0; m < 4; ++m)
#pragma unroll
        for (int n = 0; n < 2; ++n) acc[m][n] = (f32x4){0.f, 0.f, 0.f, 0.f};

    const int nt = Keff >> 5;

#define SB0 __builtin_amdgcn_sched_barrier(0);
#define STAGE(step, slot) { char* sA_ = smem + ((slot) << 14) + (w << 10); \
        ldsload16(gA + (size_t)(step) * 32, sA_); \
        ldsload16(gB + (size_t)(step) * 32, sA_ + 8192); }
#define KSTEP(WAITLIT, slotR, DOSTAGE, stepW, slotW) { \
        asm volatile("s_waitcnt vmcnt(" WAITLIT ")" ::: "memory"); \
        SB0 \
        __builtin_amdgcn_s_barrier(); \
        SB0 \
        const char* bA = smem + ((slotR) << 14); \
        const char* bB = bA + 8192; \
        h16x8 af[4], bf[2]; \
        _Pragma("unroll") for (int m = 0; m < 4; ++m) \
            af[m] = *(const h16x8*)(bA + ((wr << 2) + m) * 1024 + lane * 16); \
        _Pragma("unroll") for (int n = 0; n < 2; ++n) \
            bf[n] = *(const h16x8*)(bB + ((wc << 1) + n) * 1024 + lane * 16); \
        asm volatile("s_waitcnt lgkmcnt(0)" ::: "memory"); \
        SB0 \
        if (DOSTAGE) STAGE(stepW, slotW) \
        __builtin_amdgcn_s_setprio(1); \
        _Pragma("unroll") for (int m = 0; m < 4; ++m) \
        _Pragma("unroll") for (int n = 0; n < 2; ++n) \
            acc[m][n] = __builtin_amdgcn_mfma_f32_16x16x32_f16(af[m], bf[n], acc[m][n], 0, 0, 0); \
        __builtin_amdgcn_s_setprio(0); \
        SB0 }

    STAGE(0, 0) STAGE(1, 1)
    int slotR = 0, slotW = 2;
    int it = 0;
    for (; it < nt - 2; ++it) {
        KSTEP("2", slotR, 1, it + 2, slotW)
        slotR = (slotR == 2) ? 0 : slotR + 1;
        slotW = (slotW == 2) ? 0 : slotW + 1;
    }
    KSTEP("2", slotR, 0, 0, 0)
    slotR = (slotR == 2) ? 0 : slotR + 1;
    KSTEP("0", slotR, 0, 0, 0)
#undef KSTEP
#undef STAGE
#undef SB0

#pragma unroll
    for (int n = 0; n < 2; ++n) {
        size_t col = col0 + (wc << 5) + n * 16 + rr;
#pragma unroll
        for (int m = 0; m < 4; ++m) {
            size_t rbase = row0 + (wr << 6) + m * 16 + (kc << 2);
#pragma unroll
            for (int j = 0; j < 4; ++j)
                C[(rbase + j) * (size_t)ldc + col] = (h16)acc[m][n][j];
        }
    }
}

// ---------------------------------------------------------------- fused attention + O-proj + residual + LN (R13)
// Block per video (256 blocks, 8 waves = 8 heads). Attn phase is wave-private
// (no barriers): stage Q/K/V fragment-native, QK^T MFMA, in-register softmax,
// P->frag via wave-private LDS, PV MFMA with VT scalar-gathered fragments,
// O->fragment-native LDS. Then barrier + the R11-proven W_o ring loop + LN.
// LDS: ring 3x32KB @0 (attn: head h QKV @ h*12288) | O 32KB @98304
// (attn: P scratch @98304+h*2048, consumed before O writes - wave-private).
__global__ __launch_bounds__(512, 1) void k_fattn(
        const h16* __restrict__ QKV,   // [8192][1536]
        const h16* __restrict__ Wo,    // [512][512] fp16
        const float* __restrict__ bo,
        h16* __restrict__ X,           // residual in / LN out (in place)
        const float* __restrict__ lw,
        const float* __restrict__ lb) {
    __shared__ char smem[131072];
    const int t = threadIdx.x;
    const int w = t >> 6, lane = t & 63;   // wave = head
    const int rr = lane & 15, kc = lane >> 4;
    const size_t b = blockIdx.x;
    const size_t row0 = b * 32;
    const h16* qkv = QKV + row0 * 1536;

#define SB0 __builtin_amdgcn_sched_barrier(0);
    // ---- stage Q,K,V of head w (12 x 1KB wave-loads, fragment-native)
#pragma unroll
    for (int mat = 0; mat < 3; ++mat)
#pragma unroll
        for (int g = 0; g < 2; ++g)
#pragma unroll
            for (int q = 0; q < 2; ++q) {
                const h16* src = qkv + (size_t)(g * 16 + rr) * 1536 + mat * 512 + w * 64 + q * 32 + kc * 8;
                ldsload16(src, smem + w * 12288 + mat * 4096 + (g * 2 + q) * 1024 + lane * 16);
            }
    asm volatile("s_waitcnt vmcnt(4)" ::: "memory");   // Q,K landed (V in flight)
    SB0

    // ---- S = Q @ K^T  (8 mfma); C-layout: row=m*16+kc*4+j, col=n*16+rr
    const char* Qb = smem + w * 12288;
    const char* Kb = Qb + 4096;
    f32x4 s[2][2];
#pragma unroll
    for (int m = 0; m < 2; ++m)
#pragma unroll
        for (int n = 0; n < 2; ++n) s[m][n] = (f32x4){0.f, 0.f, 0.f, 0.f};
#pragma unroll
    for (int q = 0; q < 2; ++q) {
        h16x8 aq[2], bk[2];
#pragma unroll
        for (int m = 0; m < 2; ++m) aq[m] = *(const h16x8*)(Qb + (m * 2 + q) * 1024 + lane * 16);
#pragma unroll
        for (int n = 0; n < 2; ++n) bk[n] = *(const h16x8*)(Kb + (n * 2 + q) * 1024 + lane * 16);
#pragma unroll
        for (int m = 0; m < 2; ++m)
#pragma unroll
            for (int n = 0; n < 2; ++n)
                s[m][n] = __builtin_amdgcn_mfma_f32_16x16x32_f16(aq[m], bk[n], s[m][n], 0, 0, 0);
    }

    // ---- softmax over cols (reduce: 2 in-lane n-tiles + shfl over low 4 lane bits)
    float p[2][2][4];
#pragma unroll
    for (int m = 0; m < 2; ++m)
#pragma unroll
        for (int j = 0; j < 4; ++j) {
            float a0 = s[m][0][j] * 0.125f, a1 = s[m][1][j] * 0.125f;
            float mx = fmaxf(a0, a1);
            mx = fmaxf(mx, __shfl_xor(mx, 1));
            mx = fmaxf(mx, __shfl_xor(mx, 2));
            mx = fmaxf(mx, __shfl_xor(mx, 4));
            mx = fmaxf(mx, __shfl_xor(mx, 8));
            float e0 = expf(a0 - mx), e1 = expf(a1 - mx);
            float sm = e0 + e1;
            sm += __shfl_xor(sm, 1);
            sm += __shfl_xor(sm, 2);
            sm += __shfl_xor(sm, 4);
            sm += __shfl_xor(sm, 8);
            float inv = 1.f / sm;
            p[m][0][j] = e0 * inv;
            p[m][1][j] = e1 * inv;
        }

    // ---- P -> fragment-native (wave-private scratch @98304 + w*2048)
    char* Pb = smem + 98304 + w * 2048;
#pragma unroll
    for (int m = 0; m < 2; ++m)
#pragma unroll
        for (int n = 0; n < 2; ++n)
#pragma unroll
            for (int j = 0; j < 4; ++j)
                *(h16*)(Pb + m * 1024 + (kc * 4 + j + ((n * 2 + (rr >> 3)) & 3) * 16) * 16 + (lane & 7) * 2) = (h16)p[m][n][j];
    asm volatile("s_waitcnt lgkmcnt(0)" ::: "memory");
    SB0
    h16x8 ap[2];
#pragma unroll
    for (int m = 0; m < 2; ++m) ap[m] = *(const h16x8*)(Pb + m * 1024 + lane * 16);

    asm volatile("s_waitcnt vmcnt(0)" ::: "memory");   // V landed
    SB0

    // ---- PV: O = P @ V via VT fragments (bv[e] = V[kc*8+e][n*16+rr]); 8 mfma
    const char* Vb = Qb + 8192;
    f32x4 o[2][4];
#pragma unroll
    for (int m = 0; m < 2; ++m)
#pragma unroll
        for (int n = 0; n < 4; ++n) o[m][n] = (f32x4){0.f, 0.f, 0.f, 0.f};
#pragma unroll
    for (int n = 0; n < 4; ++n) {
        h16x8 bv;
#pragma unroll
        for (int e = 0; e < 8; ++e)
            bv[e] = *(const h16*)(Vb + ((kc >> 1) * 2 + (n >> 1)) * 1024
                                  + ((kc & 1) * 8 + e) * 16
                                  + ((n * 2 + (rr >> 3)) & 3) * 256 + (lane & 7) * 2);
#pragma unroll
        for (int m = 0; m < 2; ++m)
            o[m][n] = __builtin_amdgcn_mfma_f32_16x16x32_f16(ap[m], bv, o[m][n], 0, 0, 0);
    }

    // ---- O -> fragment-native A-matrix [32][512] @98304 (cols w*64..+63)
#pragma unroll
    for (int m = 0; m < 2; ++m)
#pragma unroll
        for (int n = 0; n < 4; ++n)
#pragma unroll
            for (int j = 0; j < 4; ++j)
                *(h16*)(smem + 98304 + (m * 16 + w * 2 + (n >> 1)) * 1024
                        + (kc * 4 + j + ((n & 1) * 2 + (rr >> 3)) * 16) * 16 + (lane & 7) * 2) = (h16)o[m][n][j];
    asm volatile("s_waitcnt lgkmcnt(0)" ::: "memory");
    SB0
    __builtin_amdgcn_s_barrier();
    SB0

    // ---- O-proj: stream Wo through 3-slot ring @0/32768/65536 (R11-proven loop)
    f32x4 acc[2][4];
#pragma unroll
    for (int m = 0; m < 2; ++m)
#pragma unroll
        for (int n = 0; n < 4; ++n) acc[m][n] = (f32x4){0.f, 0.f, 0.f, 0.f};

#define STGB(js, sl) { _Pragma("unroll") for (int u = 0; u < 4; ++u) { \
        const h16* s_ = Wo + (size_t)((((u << 3) + w) << 4) + rr) * DM + (js) * 32 + (kc << 3); \
        ldsload16(s_, smem + (sl) * 32768 + (((u << 3) + w) << 10) + (lane << 4)); } }

    STGB(0, 0) STGB(1, 1)
    int slotR = 0, slotW = 2;
    for (int sx = 0; sx < 15; ++sx) {
        asm volatile("s_waitcnt vmcnt(4)" ::: "memory");
        SB0
        __builtin_amdgcn_s_barrier();
        SB0
        h16x8 af[2], bf[4];
#pragma unroll
        for (int m = 0; m < 2; ++m)
            af[m] = *(const h16x8*)(smem + 98304 + (m * 16 + sx) * 1024 + (lane << 4));
#pragma unroll
        for (int n = 0; n < 4; ++n)
            bf[n] = *(const h16x8*)(smem + slotR * 32768 + (((w << 2) + n) << 10) + (lane << 4));
        asm volatile("s_waitcnt lgkmcnt(0)" ::: "memory");
        SB0
        if (sx + 2 < 16) STGB(sx + 2, slotW)
        __builtin_amdgcn_s_setprio(1);
#pragma unroll
        for (int m = 0; m < 2; ++m)
#pragma unroll
            for (int n = 0; n < 4; ++n)
                acc[m][n] = __builtin_amdgcn_mfma_f32_16x16x32_f16(af[m], bf[n], acc[m][n], 0, 0, 0);
        __builtin_amdgcn_s_setprio(0);
        SB0
        slotR = (slotR == 2) ? 0 : slotR + 1;
        slotW = (slotW == 2) ? 0 : slotW + 1;
    }
    {
        asm volatile("s_waitcnt vmcnt(0)" ::: "memory");
        SB0
        __builtin_amdgcn_s_barrier();
        SB0
        h16x8 af[2], bf[4];
#pragma unroll
        for (int m = 0; m < 2; ++m)
            af[m] = *(const h16x8*)(smem + 98304 + (m * 16 + 15) * 1024 + (lane << 4));
#pragma unroll
        for (int n = 0; n < 4; ++n)
            bf[n] = *(const h16x8*)(smem + slotR * 32768 + (((w << 2) + n) << 10) + (lane << 4));
        asm volatile("s_waitcnt lgkmcnt(0)" ::: "memory");
        SB0
#pragma unroll
        for (int m = 0; m < 2; ++m)
#pragma unroll
            for (int n = 0; n < 4; ++n)
                acc[m][n] = __builtin_amdgcn_mfma_f32_16x16x32_f16(af[m], bf[n], acc[m][n], 0, 0, 0);
    }
#undef STGB
#undef SB0
    __syncthreads();

    // ---- proj + bias -> LDS f32 [32][516], then residual + LN (R11-proven)
    float* outl = (float*)smem;
    float bvv[4];
#pragma unroll
    for (int n = 0; n < 4; ++n)
        bvv[n] = bo[(w << 6) + n * 16 + rr];
#pragma unroll
    for (int m = 0; m < 2; ++m)
#pragma unroll
        for (int n = 0; n < 4; ++n)
#pragma unroll
            for (int j = 0; j < 4; ++j) {
                int r = m * 16 + kc * 4 + j;
                int c = (w << 6) + n * 16 + rr;
                outl[r * 516 + c] = acc[m][n][j] + bvv[n];
            }
    __syncthreads();
    {
        const int r = t >> 4, l = t & 15;
        const size_t grow = (row0 + r) * (size_t)DM;
        float v[32];
        float sum = 0.f, sq = 0.f;
#pragma unroll
        for (int i = 0; i < 32; ++i) {
            int col = l + (i << 4);
            float vv = outl[r * 516 + col] + (float)X[grow + col];
            v[i] = vv;
            sum += vv;
            sq += vv * vv;
        }
#pragma unroll
        for (int o2 = 8; o2; o2 >>= 1) {
            sum += __shfl_xor(sum, o2);
            sq  += __shfl_xor(sq, o2);
        }
        float mean = sum * (1.f / 512.f);
        float var = sq * (1.f / 512.f) - mean * mean;
        float inv = 1.f / sqrtf(var + 1e-5f);
#pragma unroll
        for (int i = 0; i < 32; ++i) {
            int col = l + (i << 4);
            X[grow + col] = (h16)((v[i] - mean) * inv * lw[col] + lb[col]);
        }
    }
}

// ---------------------------------------------------------------- x = LN(x + p0 + p1 + bias)*w + b
__global__ __launch_bounds__(256) void k_addln_red(h16* __restrict__ x,
                                                   const h16* __restrict__ p0,
                                                   const h16* __restrict__ p1,
                                                   const float* __restrict__ bias,
                                                   const float* __restrict__ w,
                                                   const float* __restrict__ b) {
    size_t row = blockIdx.x;
    int t = threadIdx.x;
    size_t o0 = row * DM + t, o1 = o0 + 256;
    float v0 = (float)x[o0] + (float)p0[o0] + (float)p1[o0] + bias[t];
    float v1 = (float)x[o1] + (float)p0[o1] + (float)p1[o1] + bias[t + 256];
    float s = v0 + v1;
#pragma unroll
    for (int o = 32; o; o >>= 1) s += __shfl_xor(s, o);
    __shared__ float ss[4], qs[4];
    if ((t & 63) == 0) ss[t >> 6] = s;
    __syncthreads();
    float mean = (ss[0] + ss[1] + ss[2] + ss[3]) * (1.f / 512.f);
    float d0 = v0 - mean, d1 = v1 - mean;
    float qv = d0 * d0 + d1 * d1;
#pragma unroll
    for (int o = 32; o; o >>= 1) qv += __shfl_xor(qv, o);
    if ((t & 63) == 0) qs[t >> 6] = qv;
    __syncthreads();
    float var = (qs[0] + qs[1] + qs[2] + qs[3]) * (1.f / 512.f);
    float inv = 1.f / sqrtf(var + 1e-5f);
    x[o0] = (h16)(d0 * inv * w[t] + b[t]);
    x[o1] = (h16)(d1 * inv * w[t + 256] + b[t + 256]);
}

// ---------------------------------------------------------------- l2 rows: f32 in -> f16 out
__global__ __launch_bounds__(256) void k_l2rows_h(const float* __restrict__ in,
                                                  h16* __restrict__ outp) {
    size_t row = blockIdx.x;
    int t = threadIdx.x;
    float v0 = in[row * DM + t], v1 = in[row * DM + t + 256];
    float q = v0 * v0 + v1 * v1;
#pragma unroll
    for (int o = 32; o; o >>= 1) q += __shfl_xor(q, o);
    __shared__ float qs[4];
    if ((t & 63) == 0) qs[t >> 6] = q;
    __syncthreads();
    float n = sqrtf(qs[0] + qs[1] + qs[2] + qs[3]);
    float sc = 1.f / fmaxf(n, 1e-12f);
    outp[row * DM + t]       = (h16)(v0 * sc);
    outp[row * DM + t + 256] = (h16)(v1 * sc);
}

// ---------------------------------------------------------------- TOK rows (l2'd frames + video tokens)
__global__ __launch_bounds__(256) void k_build_tok_h(const float* __restrict__ frames,
                                                     const h16* __restrict__ X,
                                                     h16* __restrict__ TOK) {
    int rid = blockIdx.x;
    int j = rid / NTOK_V, tt = rid % NTOK_V;
    int t = threadIdx.x;
    float v0, v1;
    if (tt < 30) {
        const float* src = frames + ((size_t)j * 30 + tt) * DM;
        v0 = src[t]; v1 = src[t + 256];
    } else {
        const h16* src = X + ((size_t)j * 32 + (tt - 30)) * DM;
        v0 = (float)src[t]; v1 = (float)src[t + 256];
    }
    float q = v0 * v0 + v1 * v1;
#pragma unroll
    for (int o = 32; o; o >>= 1) q += __shfl_xor(q, o);
    __shared__ float qs[4];
    if ((t & 63) == 0) qs[t >> 6] = q;
    __syncthreads();
    float n = sqrtf(qs[0] + qs[1] + qs[2] + qs[3]);
    float sc = 1.f / fmaxf(n, 1e-12f);
    TOK[(size_t)rid * DM + t]       = (h16)(v0 * sc);
    TOK[(size_t)rid * DM + t + 256] = (h16)(v1 * sc);
}

// ---------------------------------------------------------------- max-reduce dots -> sims
__global__ __launch_bounds__(256) void k_sim_h(const h16* __restrict__ dots,
                                               float* __restrict__ out) {
    int i = blockIdx.x;
    int j = threadIdx.x;
    const h16* p = dots + (size_t)i * 15872 + (size_t)j * NTOK_V;
    float mf = -1e30f, mv = -1e30f;
#pragma unroll
    for (int tt = 0; tt < 30; ++tt) mf = fmaxf(mf, (float)p[tt]);
#pragma unroll
    for (int tt = 30; tt < 62; ++tt) mv = fmaxf(mv, (float)p[tt]);
    int o = i * 256 + j;
    out[o]          = mf + mv;
    out[65536 + o]  = mf;
    out[131072 + o] = mv;
}

// ---------------------------------------------------------------- launcher
extern "C" void kernel_launch(void* const* d_in, const int* in_sizes, int n_in,
                              void* d_out, int out_size, void* d_ws, size_t ws_size,
                              hipStream_t stream) {
    const float* text   = (const float*)d_in[0];
    const float* frames = (const float*)d_in[1];
    const float* expt   = (const float*)d_in[2];
    const float* Wqkv   = (const float*)d_in[3];
    const float* bqkv   = (const float*)d_in[4];
    const float* Wo     = (const float*)d_in[5];
    const float* bo     = (const float*)d_in[6];
    const float* ln1w   = (const float*)d_in[7];
    const float* ln1b   = (const float*)d_in[8];
    const float* W1     = (const float*)d_in[9];
    const float* b1     = (const float*)d_in[10];
    const float* W2     = (const float*)d_in[11];
    const float* b2     = (const float*)d_in[12];
    const float* ln2w   = (const float*)d_in[13];
    const float* ln2b   = (const float*)d_in[14];
    float* out = (float*)d_out;

    char* wsb = (char*)d_ws;
    const size_t MB = 1024 * 1024;
    h16* Xh    = (h16*)(wsb);              // 8 MB   [8192,512]
    h16* P0    = (h16*)(wsb + 8 * MB);     // 8 MB   split-K partial 0 (FF2)
    h16* P1    = (h16*)(wsb + 16 * MB);    // 8 MB   split-K partial 1
    h16* FFh   = (h16*)(wsb + 32 * MB);    // 32 MB  [8192,2048] (also QKV [8192,1536])
    h16* TOKh  = (h16*)(wsb + 32 * MB);    // alias FF (post-transformer)
    h16* DOTSh = (h16*)(wsb + 48 * MB);    // alias FF tail
    h16* Wh    = (h16*)(wsb + 64 * MB);    // 25 MB  all weights fp16
    h16* QHATh = (h16*)(wsb + 90 * MB);    // 0.25 MB

    h16* Whqkv = Wh;                       // 4*1536*512
    h16* Who   = Whqkv + 3145728;          // 4*512*512
    h16* Wh1   = Who + 1048576;            // 4*2048*512
    h16* Wh2   = Wh1 + 4194304;            // 4*2048*512

    k_cvt<<<1536, 256, 0, stream>>>(Wqkv, Whqkv, 393216);
    k_cvt<<<512,  256, 0, stream>>>(Wo,   Who,   131072);
    k_cvt<<<2048, 256, 0, stream>>>(W1,   Wh1,   524288);
    k_cvt<<<2048, 256, 0, stream>>>(W2,   Wh2,   524288);
    k_concat_h<<<8192, 256, 0, stream>>>(frames, expt, Xh);

    for (int l = 0; l < 4; ++l) {
        const h16* Wqkv_l = Whqkv + (size_t)l * 786432;
        const h16* Wo_l   = Who   + (size_t)l * 262144;
        const h16* W1_l   = Wh1   + (size_t)l * 1048576;
        const h16* W2_l   = Wh2   + (size_t)l * 1048576;

        k_g8<0><<<dim3(6, 32, 1), 512, 0, stream>>>(
            Xh, 512, Wqkv_l, 512, bqkv + (size_t)l * 1536, FFh, 1536, 8192, 1536, 512);
        k_fattn<<<256, 512, 0, stream>>>(FFh, Wo_l, bo + (size_t)l * 512, Xh,
                                         ln1w + (size_t)l * 512, ln1b + (size_t)l * 512);
        k_g8<1><<<dim3(8, 32, 1), 512, 0, stream>>>(
            Xh, 512, W1_l, 512, b1 + (size_t)l * 2048, FFh, 2048, 8192, 2048, 512);
        k_g8n<<<dim3(4, 32, 2), 512, 0, stream>>>(
            FFh, 2048, W2_l, 2048, P0, 512, 8192, 512, 1024);
        k_addln_red<<<8192, 256, 0, stream>>>(Xh, P0, P1, b2 + (size_t)l * 512,
                                              ln2w + (size_t)l * 512, ln2b + (size_t)l * 512);
    }

    k_l2rows_h<<<256, 256, 0, stream>>>(text, QHATh);
    k_build_tok_h<<<256 * NTOK_V, 256, 0, stream>>>(frames, Xh, TOKh);
    k_hgemm<2><<<dim3(124, 2, 1), 512, 0, stream>>>(
        QHATh, 512, TOKh, 512, nullptr, DOTSh, 15872, 256, 15872, 512);
    k_sim_h<<<256, 256, 0, stream>>>(DOTSh, out);
}